// Round 1
// 496.542 us; speedup vs baseline: 1.0100x; 1.0100x over previous
//
#include <hip/hip_runtime.h>
#include <cstdint>

#define Bc  2
#define Sc  2048
#define Dc  1024
#define Ec  1024
#define Hc  16
#define HDc 64
#define TTc (Bc*Sc)
#define TILE_R 128
#define NTILES 36
#define EPSc 1e-5f
#define LOG2E 1.44269504f
#define C2    (0.125f*LOG2E)

typedef unsigned short u16;
using bf8   = __attribute__((ext_vector_type(8))) short;
using f32x4 = __attribute__((ext_vector_type(4))) float;
#define MFMA(a,b,c) __builtin_amdgcn_mfma_f32_16x16x32_bf16(a,b,c,0,0,0)

static __device__ __forceinline__ u16 f2b(float f){
    return (u16)((__float_as_uint(f) + 0x8000u) >> 16);
}
static __device__ __forceinline__ float b2f(u16 s){
    return __uint_as_float(((unsigned)s) << 16);
}

// ---------------------------------------------------------------------------
// 1. modality-sorted token permutation, 128-padded segments per (b,m)
// ---------------------------------------------------------------------------
__global__ void k_perm(const int* __restrict__ mod, int* __restrict__ perm,
                       int* __restrict__ tmeta)
{
    __shared__ int cnt[4], segstart[4];
    int t = threadIdx.x;
    if (t < 4) cnt[t] = 0;
    __syncthreads();
    for (int i = t; i < TTc; i += 256){
        int b = i >> 11; int m = mod[i];
        atomicAdd(&cnt[b*2+m], 1);
    }
    __syncthreads();
    if (t == 0){
        int off = 0;
        for (int i = 0; i < 4; i++){
            segstart[i] = off;
            int pad = ((cnt[i] + TILE_R - 1)/TILE_R)*TILE_R;
            for (int tt = off/TILE_R; tt < (off+pad)/TILE_R; tt++) tmeta[tt] = i;
            off += pad;
        }
        for (int tt = off/TILE_R; tt < NTILES; tt++) tmeta[tt] = -1;
    }
    __syncthreads();
    if (t < 4) cnt[t] = 0;
    for (int i = t; i < NTILES*TILE_R; i += 256) perm[i] = -1;
    __syncthreads();
    for (int i = t; i < TTc; i += 256){
        int b = i >> 11, s = i & 2047; int m = mod[i];
        int r = atomicAdd(&cnt[b*2+m], 1);
        perm[segstart[b*2+m] + r] = s;
    }
}

// ---------------------------------------------------------------------------
// 2. fp32 -> bf16 elementwise (optionally scaled)
// ---------------------------------------------------------------------------
__global__ __launch_bounds__(256) void k_f2b(const float* __restrict__ src,
                                             u16* __restrict__ dst, int n)
{
    int i = (blockIdx.x*256 + threadIdx.x)*4;
    if (i >= n) return;
    float4 v = *(const float4*)&src[i];
    ushort4 o;
    o.x = f2b(v.x); o.y = f2b(v.y); o.z = f2b(v.z); o.w = f2b(v.w);
    *(ushort4*)&dst[i] = o;
}

__global__ __launch_bounds__(256) void k_f2bs(const float* __restrict__ src,
                                              u16* __restrict__ dst, int n, float sc)
{
    int i = (blockIdx.x*256 + threadIdx.x)*4;
    if (i >= n) return;
    float4 v = *(const float4*)&src[i];
    ushort4 o;
    o.x = f2b(v.x*sc); o.y = f2b(v.y*sc); o.z = f2b(v.z*sc); o.w = f2b(v.w*sc);
    *(ushort4*)&dst[i] = o;
}

// ---------------------------------------------------------------------------
// 3. transpose+convert all four weights in one launch; grid (32,32,8)
// ---------------------------------------------------------------------------
__global__ __launch_bounds__(256) void k_tcvt(
    const float* __restrict__ s0, const float* __restrict__ s1,
    const float* __restrict__ s2, const float* __restrict__ s3,
    u16* __restrict__ d0, u16* __restrict__ d1,
    u16* __restrict__ d2, u16* __restrict__ d3)
{
    int wsel = blockIdx.z >> 1, m = blockIdx.z & 1;
    const float* src = (wsel==0?s0:wsel==1?s1:wsel==2?s2:s3) + (size_t)m*1048576;
    u16*       dst = (wsel==0?d0:wsel==1?d1:wsel==2?d2:d3) + (size_t)m*1048576;
    __shared__ float sh[32][33];
    int t = threadIdx.x;
    int i0 = blockIdx.x*32, j0 = blockIdx.y*32;
    {
        int i = t >> 3, j4 = (t & 7)*4;
        *(float4*)&sh[i][j4] = *(const float4*)&src[(size_t)(i0+i)*1024 + j0 + j4];
    }
    __syncthreads();
    {
        int j = t >> 3, i4 = (t & 7)*4;
        ushort4 o;
        o.x = f2b(sh[i4+0][j]); o.y = f2b(sh[i4+1][j]);
        o.z = f2b(sh[i4+2][j]); o.w = f2b(sh[i4+3][j]);
        *(ushort4*)&dst[(size_t)(j0+j)*1024 + i0 + i4] = o;
    }
}

// ---------------------------------------------------------------------------
// 4. QKV projection, MFMA, with fused per-head RMSNorm for Q and K.
//    grid (8, NTILES, 3)
// ---------------------------------------------------------------------------
__global__ __launch_bounds__(256) void k_qkv(
    const u16* __restrict__ xb, const u16* __restrict__ wqT,
    const u16* __restrict__ wkT, const u16* __restrict__ wvT,
    const int* __restrict__ perm, const int* __restrict__ tmeta,
    const float* __restrict__ qnw, const float* __restrict__ knw,
    u16* __restrict__ qb, u16* __restrict__ kb, u16* __restrict__ vb)
{
    int meta = tmeta[blockIdx.y];
    if (meta < 0) return;
    int b = meta >> 1, m = meta & 1;
    const u16* W = (blockIdx.z==0 ? wqT : (blockIdx.z==1 ? wkT : wvT)) + (size_t)m*Ec*Dc;
    u16* outp    = (blockIdx.z==0 ? qb  : (blockIdx.z==1 ? kb  : vb));
    int c0 = blockIdx.x*128;
    int t = threadIdx.x, lane = t & 63, wv_ = t >> 6;
    int quad = lane >> 4, lc = lane & 15;

    __shared__ u16 at[128][72];
    __shared__ u16 bt[128][72];
    __shared__ int sperm[128];
    if (t < 128) sperm[t] = perm[blockIdx.y*128 + t];
    f32x4 acc[2][8];
    #pragma unroll
    for (int i=0;i<2;i++)
        #pragma unroll
        for (int j=0;j<8;j++) acc[i][j] = (f32x4){0.f,0.f,0.f,0.f};
    __syncthreads();

    int rr = t >> 1, hf = t & 1;
    for (int d0 = 0; d0 < Dc; d0 += 64){
        int s_ = sperm[rr];
        if (s_ >= 0){
            const u16* src = xb + ((size_t)(b*Sc + s_))*Dc + d0 + hf*32;
            *(uint4*)&at[rr][hf*32]      = *(const uint4*)(src);
            *(uint4*)&at[rr][hf*32 + 8]  = *(const uint4*)(src + 8);
            *(uint4*)&at[rr][hf*32 + 16] = *(const uint4*)(src + 16);
            *(uint4*)&at[rr][hf*32 + 24] = *(const uint4*)(src + 24);
        } else {
            uint4 z = make_uint4(0,0,0,0);
            *(uint4*)&at[rr][hf*32]      = z;
            *(uint4*)&at[rr][hf*32 + 8]  = z;
            *(uint4*)&at[rr][hf*32 + 16] = z;
            *(uint4*)&at[rr][hf*32 + 24] = z;
        }
        const u16* wsrc = W + (size_t)(c0 + rr)*Dc + d0 + hf*32;
        *(uint4*)&bt[rr][hf*32]      = *(const uint4*)(wsrc);
        *(uint4*)&bt[rr][hf*32 + 8]  = *(const uint4*)(wsrc + 8);
        *(uint4*)&bt[rr][hf*32 + 16] = *(const uint4*)(wsrc + 16);
        *(uint4*)&bt[rr][hf*32 + 24] = *(const uint4*)(wsrc + 24);
        __syncthreads();
        #pragma unroll
        for (int ks = 0; ks < 2; ks++){
            bf8 a0 = *(const bf8*)&at[wv_*32 + lc][ks*32 + quad*8];
            bf8 a1 = *(const bf8*)&at[wv_*32 + 16 + lc][ks*32 + quad*8];
            #pragma unroll
            for (int nb = 0; nb < 8; nb++){
                bf8 bb = *(const bf8*)&bt[nb*16 + lc][ks*32 + quad*8];
                acc[0][nb] = MFMA(a0, bb, acc[0][nb]);
                acc[1][nb] = MFMA(a1, bb, acc[1][nb]);
            }
        }
        __syncthreads();
    }

    if (blockIdx.z < 2){
        const float* nw = (blockIdx.z==0 ? qnw : knw) + m*HDc;
        float w0 = nw[lc], w1 = nw[16+lc], w2 = nw[32+lc], w3 = nw[48+lc];
        #pragma unroll
        for (int mb = 0; mb < 2; mb++){
            #pragma unroll
            for (int r = 0; r < 4; r++){
                #pragma unroll
                for (int g = 0; g < 2; g++){
                    float ss = 0.f;
                    #pragma unroll
                    for (int j = 0; j < 4; j++){
                        float v2 = acc[mb][g*4+j][r];
                        ss += v2*v2;
                    }
                    ss += __shfl_xor(ss, 1, 64);
                    ss += __shfl_xor(ss, 2, 64);
                    ss += __shfl_xor(ss, 4, 64);
                    ss += __shfl_xor(ss, 8, 64);
                    float rs = rsqrtf(ss*(1.f/64.f) + EPSc);
                    acc[mb][g*4+0][r] *= rs*w0;
                    acc[mb][g*4+1][r] *= rs*w1;
                    acc[mb][g*4+2][r] *= rs*w2;
                    acc[mb][g*4+3][r] *= rs*w3;
                }
            }
        }
    }

    int h0 = c0 >> 6;
    #pragma unroll
    for (int mb = 0; mb < 2; mb++){
        #pragma unroll
        for (int r = 0; r < 4; r++){
            int row = wv_*32 + mb*16 + quad*4 + r;
            int s_ = sperm[row];
            if (s_ < 0) continue;
            #pragma unroll
            for (int nb = 0; nb < 8; nb++){
                int col = nb*16 + lc;
                int h = h0 + (col >> 6), hd = col & 63;
                outp[(((size_t)(b*Hc + h))*Sc + s_)*HDc + hd] = f2b(acc[mb][nb][r]);
            }
        }
    }
}

// ---------------------------------------------------------------------------
// 6. V transpose via LDS tiles: vb [BH][S][HD] -> vtb [BH][HD][S]
// ---------------------------------------------------------------------------
__global__ __launch_bounds__(256) void k_vt(const u16* __restrict__ vb,
                                            u16* __restrict__ vtb)
{
    __shared__ u16 sh[64][72];
    int t = threadIdx.x;
    int s0 = blockIdx.x*64, bh = blockIdx.y;
    {
        int rr = t >> 2, cc = (t & 3)*16;
        const u16* src = vb + ((size_t)bh*Sc + s0 + rr)*HDc + cc;
        *(uint4*)&sh[rr][cc]   = *(const uint4*)(src);
        *(uint4*)&sh[rr][cc+8] = *(const uint4*)(src+8);
    }
    __syncthreads();
    {
        int hd = t >> 2, sc = (t & 3)*16;
        u16 tmp[16];
        #pragma unroll
        for (int j = 0; j < 16; j++) tmp[j] = sh[sc+j][hd];
        u16* dst = vtb + ((size_t)bh*HDc + hd)*Sc + s0 + sc;
        *(uint4*)(dst)   = *(const uint4*)&tmp[0];
        *(uint4*)(dst+8) = *(const uint4*)&tmp[8];
    }
}

// ---------------------------------------------------------------------------
// 7. softmax stats (log2 domain), split-K x4. grid (16, 16, 8)
// ---------------------------------------------------------------------------
__global__ __launch_bounds__(256) void k_stats(
    const u16* __restrict__ qb, const u16* __restrict__ kb,
    const u16* __restrict__ maskb, float* __restrict__ pmst,
    float* __restrict__ plst)
{
    int qs0 = blockIdx.x*128, h = blockIdx.y;
    int b = blockIdx.z >> 2, ch = blockIdx.z & 3;
    int t = threadIdx.x, lane = t & 63, wv_ = t >> 6;
    int quad = lane >> 4, lc = lane & 15;
    __shared__ u16 kt[64][72];
    __shared__ u16 mt[128][72];
    const u16* qp = qb + ((size_t)(b*Hc+h))*Sc*HDc;
    const u16* kp = kb + ((size_t)(b*Hc+h))*Sc*HDc;
    bf8 aq[2][2];
    #pragma unroll
    for (int mb = 0; mb < 2; mb++)
        #pragma unroll
        for (int ks = 0; ks < 2; ks++)
            aq[mb][ks] = *(const bf8*)(qp + (size_t)(qs0 + wv_*32 + mb*16 + lc)*HDc
                                          + ks*32 + quad*8);
    float rm[8], rl[8];
    #pragma unroll
    for (int i=0;i<8;i++){ rm[i] = -1.0e30f; rl[i] = 0.f; }

    int kc0 = ch*512;
    for (int kc = kc0; kc < kc0 + 512; kc += 64){
        __syncthreads();
        {
            int rr = t >> 2, cc = (t & 3)*16;
            const u16* s = kp + (size_t)(kc+rr)*HDc + cc;
            *(uint4*)&kt[rr][cc]   = *(const uint4*)(s);
            *(uint4*)&kt[rr][cc+8] = *(const uint4*)(s+8);
            int rr2 = t >> 1, cc2 = (t & 1)*32;
            const u16* ms = maskb + (size_t)(qs0+rr2)*Sc + kc + cc2;
            *(uint4*)&mt[rr2][cc2]    = *(const uint4*)(ms);
            *(uint4*)&mt[rr2][cc2+8]  = *(const uint4*)(ms+8);
            *(uint4*)&mt[rr2][cc2+16] = *(const uint4*)(ms+16);
            *(uint4*)&mt[rr2][cc2+24] = *(const uint4*)(ms+24);
        }
        __syncthreads();
        f32x4 acc[2][4];
        #pragma unroll
        for (int i=0;i<2;i++)
            #pragma unroll
            for (int j=0;j<4;j++) acc[i][j] = (f32x4){0.f,0.f,0.f,0.f};
        #pragma unroll
        for (int ks = 0; ks < 2; ks++){
            #pragma unroll
            for (int nb = 0; nb < 4; nb++){
                bf8 bb = *(const bf8*)&kt[nb*16 + lc][ks*32 + quad*8];
                acc[0][nb] = MFMA(aq[0][ks], bb, acc[0][nb]);
                acc[1][nb] = MFMA(aq[1][ks], bb, acc[1][nb]);
            }
        }
        #pragma unroll
        for (int mb = 0; mb < 2; mb++){
            #pragma unroll
            for (int r = 0; r < 4; r++){
                int row = wv_*32 + mb*16 + quad*4 + r;
                float sv[4];
                #pragma unroll
                for (int nb = 0; nb < 4; nb++)
                    sv[nb] = fmaf(acc[mb][nb][r], C2, b2f(mt[row][nb*16 + lc]));
                float mx = fmaxf(fmaxf(sv[0],sv[1]), fmaxf(sv[2],sv[3]));
                int slot = mb*4 + r;
                float nm = fmaxf(rm[slot], mx);
                float a2 = rl[slot]*exp2f(rm[slot]-nm);
                #pragma unroll
                for (int nb = 0; nb < 4; nb++) a2 += exp2f(sv[nb]-nm);
                rm[slot] = nm; rl[slot] = a2;
            }
        }
    }
    #pragma unroll
    for (int slot = 0; slot < 8; slot++){
        #pragma unroll
        for (int o = 1; o < 16; o <<= 1){
            float m2 = __shfl_xor(rm[slot], o, 64);
            float l2 = __shfl_xor(rl[slot], o, 64);
            float nm = fmaxf(rm[slot], m2);
            rl[slot] = rl[slot]*exp2f(rm[slot]-nm) + l2*exp2f(m2-nm);
            rm[slot] = nm;
        }
    }
    if (lc == 0){
        #pragma unroll
        for (int mb = 0; mb < 2; mb++){
            #pragma unroll
            for (int r = 0; r < 4; r++){
                int row = qs0 + wv_*32 + mb*16 + quad*4 + r;
                size_t idx = (size_t)ch*65536 + ((size_t)(b*Hc+h))*Sc + row;
                pmst[idx] = rm[mb*4+r];
                plst[idx] = rl[mb*4+r];
            }
        }
    }
}

// ---------------------------------------------------------------------------
// 7b. merge split-K partials -> mst/lst (log2-domain m)
// ---------------------------------------------------------------------------
__global__ __launch_bounds__(256) void k_merge(
    const float* __restrict__ pmst, const float* __restrict__ plst,
    float* __restrict__ mst, float* __restrict__ lst)
{
    int r = blockIdx.x*256 + threadIdx.x;
    float M = -1.0e30f, L = 0.f;
    #pragma unroll
    for (int c = 0; c < 4; c++){
        float m2 = pmst[(size_t)c*65536 + r];
        float l2 = plst[(size_t)c*65536 + r];
        float nm = fmaxf(M, m2);
        L = L*exp2f(M-nm) + l2*exp2f(m2-nm);
        M = nm;
    }
    mst[r] = M; lst[r] = L;
}

// ---------------------------------------------------------------------------
// 8. attn_weights: q-tile 64, k-tile 64, loop all 16 h, NO atomics.
//    grid (32, 32, 2) = (q, k, b). Plain coalesced store.
// ---------------------------------------------------------------------------
__global__ __launch_bounds__(256) void k_attnw(
    const u16* __restrict__ qb, const u16* __restrict__ kb,
    const u16* __restrict__ maskb, const float* __restrict__ mst,
    const float* __restrict__ lst, float* __restrict__ awout)
{
    int qs0 = blockIdx.x*64, ks0 = blockIdx.y*64, b = blockIdx.z;
    int t = threadIdx.x, lane = t & 63, wv_ = t >> 6;
    int quad = lane >> 4, lc = lane & 15;
    __shared__ u16 kt[64][72];
    __shared__ float sm[64], sli[64];
    f32x4 T[4];
    #pragma unroll
    for (int j=0;j<4;j++) T[j] = (f32x4){0.f,0.f,0.f,0.f};

    for (int h = 0; h < Hc; h++){
        __syncthreads();
        const u16* qp = qb + ((size_t)(b*Hc+h))*Sc*HDc;
        const u16* kp = kb + ((size_t)(b*Hc+h))*Sc*HDc;
        bf8 aq[2];
        #pragma unroll
        for (int ks = 0; ks < 2; ks++)
            aq[ks] = *(const bf8*)(qp + (size_t)(qs0 + wv_*16 + lc)*HDc + ks*32 + quad*8);
        {
            int rr = t >> 2, cc = (t & 3)*16;
            const u16* s2 = kp + (size_t)(ks0+rr)*HDc + cc;
            *(uint4*)&kt[rr][cc]   = *(const uint4*)(s2);
            *(uint4*)&kt[rr][cc+8] = *(const uint4*)(s2+8);
        }
        if (t < 64){
            sm[t]  = mst[((size_t)(b*Hc+h))*Sc + qs0 + t];
            sli[t] = 1.f / lst[((size_t)(b*Hc+h))*Sc + qs0 + t];
        }
        __syncthreads();
        f32x4 acc[4];
        #pragma unroll
        for (int j=0;j<4;j++) acc[j] = (f32x4){0.f,0.f,0.f,0.f};
        #pragma unroll
        for (int ks = 0; ks < 2; ks++){
            #pragma unroll
            for (int nb = 0; nb < 4; nb++){
                bf8 bb = *(const bf8*)&kt[nb*16 + lc][ks*32 + quad*8];
                acc[nb] = MFMA(aq[ks], bb, acc[nb]);
            }
        }
        #pragma unroll
        for (int r = 0; r < 4; r++){
            int row = wv_*16 + quad*4 + r;
            float mm = sm[row], li = sli[row];
            #pragma unroll
            for (int nb = 0; nb < 4; nb++){
                float s = fminf(fmaf(acc[nb][r], C2, -mm), 80.f);
                T[nb][r] += exp2f(s)*li;
            }
        }
    }
    #pragma unroll
    for (int r = 0; r < 4; r++){
        int gq = qs0 + wv_*16 + quad*4 + r;
        #pragma unroll
        for (int nb = 0; nb < 4; nb++){
            int gk = ks0 + nb*16 + lc;
            float mk = b2f(maskb[(size_t)gq*Sc + gk]);   // mask*log2e
            awout[(size_t)b*Sc*Sc + (size_t)gq*Sc + gk]
                = T[nb][r]*exp2f(mk)*(1.f/16.f);
        }
    }
}

// ---------------------------------------------------------------------------
// 9. flash PV, split-K x2: grid (32, 16, 4): z = b*2 + half.
//    SWAPPED QK^T (mfma(K,Q)) + pi-permuted K staging: P tile stays in
//    registers in exact PV A-fragment layout -> no LDS P round-trip, no
//    second barrier per k-tile. Stats (m, 1/l) are per-lane registers.
//    LDS row l=16*nb+4*g+r of kt holds global k-row 32*(nb>>1)+8*g+4*(nb&1)+r,
//    so acc slot (nb,g,r) == k 32a1+8g+4b1+r == PV A-frag slot (ks=a1, j=4b1+r).
// ---------------------------------------------------------------------------
__global__ __launch_bounds__(256) void k_flash(
    const u16* __restrict__ qb, const u16* __restrict__ kb,
    const u16* __restrict__ vtb, const u16* __restrict__ maskb,
    const float* __restrict__ mst, const float* __restrict__ lst,
    u16* __restrict__ c0, u16* __restrict__ c1)
{
    int qs0 = blockIdx.x*64, h = blockIdx.y;
    int b = blockIdx.z >> 1, half = blockIdx.z & 1;
    u16* ctxh = half ? c1 : c0;
    int t = threadIdx.x, lane = t & 63, wv_ = t >> 6;
    int quad = lane >> 4, lc = lane & 15;
    __shared__ u16 kt[64][72];
    __shared__ u16 vt[64][72];
    __shared__ u16 mpt[64][72];
    const u16* qp  = qb  + ((size_t)(b*Hc+h))*Sc*HDc;
    const u16* kp  = kb  + ((size_t)(b*Hc+h))*Sc*HDc;
    const u16* vtp = vtb + ((size_t)(b*Hc+h))*HDc*Sc;
    // Q fragment: B-operand layout (col = lc = q, k-dim = hd slice) --
    // byte-identical load to the old A-operand load.
    bf8 aq[2];
    #pragma unroll
    for (int ks = 0; ks < 2; ks++)
        aq[ks] = *(const bf8*)(qp + (size_t)(qs0 + wv_*16 + lc)*HDc + ks*32 + quad*8);
    // per-lane softmax stats for this lane's q row (q = qs0 + wv*16 + lc)
    size_t srow = ((size_t)(b*Hc+h))*Sc + qs0 + wv_*16 + lc;
    float mm = mst[srow];
    float li = 1.f / lst[srow];
    f32x4 oacc[4];
    #pragma unroll
    for (int j=0;j<4;j++) oacc[j] = (f32x4){0.f,0.f,0.f,0.f};

    int rr = t >> 2, cc = (t & 3)*16;
    // pi: global k-row rr -> LDS row (b5<<5)|(b2<<4)|(b4<<3)|(b3<<2)|(b1<<1)|b0
    int pr = (rr & 0x23) | ((rr & 0x04) << 2) | ((rr & 0x18) >> 1);
    int kc0 = half*1024;
    for (int kc = kc0; kc < kc0 + 1024; kc += 64){
        __syncthreads();
        {
            const u16* s1 = kp + (size_t)(kc+rr)*HDc + cc;
            *(uint4*)&kt[pr][cc]   = *(const uint4*)(s1);
            *(uint4*)&kt[pr][cc+8] = *(const uint4*)(s1+8);
            const u16* s2 = vtp + (size_t)rr*Sc + kc + cc;
            *(uint4*)&vt[rr][cc]   = *(const uint4*)(s2);
            *(uint4*)&vt[rr][cc+8] = *(const uint4*)(s2+8);
            const u16* ms = maskb + (size_t)(qs0+rr)*Sc + kc + cc;
            *(uint4*)&mpt[rr][cc]   = *(const uint4*)(ms);
            *(uint4*)&mpt[rr][cc+8] = *(const uint4*)(ms+8);
        }
        __syncthreads();
        // S^T = K * Q^T : acc[nb] row (quad*4+r) = LDS k-row 16nb+4quad+r,
        // col = lc = q
        f32x4 acc[4];
        #pragma unroll
        for (int j=0;j<4;j++) acc[j] = (f32x4){0.f,0.f,0.f,0.f};
        #pragma unroll
        for (int ks = 0; ks < 2; ks++){
            #pragma unroll
            for (int nb = 0; nb < 4; nb++){
                bf8 ak = *(const bf8*)&kt[nb*16 + lc][ks*32 + quad*8];
                acc[nb] = MFMA(ak, aq[ks], acc[nb]);
            }
        }
        // epilogue fully in-register: P packs directly into PV A-fragments
        const u16* mrow = &mpt[wv_*16 + lc][0];
        #pragma unroll
        for (int a1 = 0; a1 < 2; a1++){
            bf8 ap;
            #pragma unroll
            for (int b1 = 0; b1 < 2; b1++){
                int nb = 2*a1 + b1;
                // k_act = 32*a1 + 8*quad + 4*b1 + r  (4 consecutive u16)
                ushort4 mv = *(const ushort4*)(mrow + a1*32 + quad*8 + b1*4);
                #pragma unroll
                for (int r = 0; r < 4; r++){
                    u16 mraw = (r==0?mv.x:r==1?mv.y:r==2?mv.z:mv.w);
                    float s2v = fmaf(acc[nb][r], C2, b2f(mraw) - mm);
                    ap[b1*4 + r] = (short)f2b(exp2f(s2v)*li);
                }
            }
            #pragma unroll
            for (int nb2 = 0; nb2 < 4; nb2++){
                bf8 bv = *(const bf8*)&vt[nb2*16 + lc][a1*32 + quad*8];
                oacc[nb2] = MFMA(ap, bv, oacc[nb2]);
            }
        }
    }
    #pragma unroll
    for (int r = 0; r < 4; r++){
        int tok = qs0 + wv_*16 + quad*4 + r;
        #pragma unroll
        for (int nb = 0; nb < 4; nb++){
            int hd = nb*16 + lc;
            ctxh[((size_t)(b*Sc + tok))*Ec + h*HDc + hd] = f2b(oacc[nb][r]);
        }
    }
}

// ---------------------------------------------------------------------------
// 9b. sum the two bf16 ctx partials: c0 += c1 (elementwise, bf16)
// ---------------------------------------------------------------------------
__global__ __launch_bounds__(256) void k_addc(u16* __restrict__ c0,
                                              const u16* __restrict__ c1)
{
    int i = (blockIdx.x*256 + threadIdx.x)*8;
    ushort4 a0 = *(ushort4*)&c0[i],   a1 = *(ushort4*)&c0[i+4];
    ushort4 b0 = *(const ushort4*)&c1[i], b1 = *(const ushort4*)&c1[i+4];
    ushort4 o0, o1;
    o0.x = f2b(b2f(a0.x)+b2f(b0.x)); o0.y = f2b(b2f(a0.y)+b2f(b0.y));
    o0.z = f2b(b2f(a0.z)+b2f(b0.z)); o0.w = f2b(b2f(a0.w)+b2f(b0.w));
    o1.x = f2b(b2f(a1.x)+b2f(b1.x)); o1.y = f2b(b2f(a1.y)+b2f(b1.y));
    o1.z = f2b(b2f(a1.z)+b2f(b1.z)); o1.w = f2b(b2f(a1.w)+b2f(b1.w));
    *(ushort4*)&c0[i]   = o0;
    *(ushort4*)&c0[i+4] = o1;
}

// ---------------------------------------------------------------------------
// 10. output projection, MFMA. grid (8, NTILES).
// ---------------------------------------------------------------------------
__global__ __launch_bounds__(256) void k_oproj(
    const u16* __restrict__ ctxb, const u16* __restrict__ woT,
    const int* __restrict__ perm, const int* __restrict__ tmeta,
    float* __restrict__ opre)
{
    int meta = tmeta[blockIdx.y];
    if (meta < 0) return;
    int b = meta >> 1, m = meta & 1;
    const u16* W = woT + (size_t)m*Ec*Dc;
    int c0 = blockIdx.x*128;
    int t = threadIdx.x, lane = t & 63, wv_ = t >> 6;
    int quad = lane >> 4, lc = lane & 15;
    __shared__ u16 at[128][72];
    __shared__ u16 bt[128][72];
    __shared__ int sperm[128];
    if (t < 128) sperm[t] = perm[blockIdx.y*128 + t];
    f32x4 acc[2][8];
    #pragma unroll
    for (int i=0;i<2;i++)
        #pragma unroll
        for (int j=0;j<8;j++) acc[i][j] = (f32x4){0.f,0.f,0.f,0.f};
    __syncthreads();

    int rr = t >> 1, hf = t & 1;
    for (int d0 = 0; d0 < Ec; d0 += 64){
        int s_ = sperm[rr];
        if (s_ >= 0){
            const u16* src = ctxb + ((size_t)(b*Sc + s_))*Ec + d0 + hf*32;
            *(uint4*)&at[rr][hf*32]      = *(const uint4*)(src);
            *(uint4*)&at[rr][hf*32 + 8]  = *(const uint4*)(src + 8);
            *(uint4*)&at[rr][hf*32 + 16] = *(const uint4*)(src + 16);
            *(uint4*)&at[rr][hf*32 + 24] = *(const uint4*)(src + 24);
        } else {
            uint4 z = make_uint4(0,0,0,0);
            *(uint4*)&at[rr][hf*32]      = z;
            *(uint4*)&at[rr][hf*32 + 8]  = z;
            *(uint4*)&at[rr][hf*32 + 16] = z;
            *(uint4*)&at[rr][hf*32 + 24] = z;
        }
        const u16* wsrc = W + (size_t)(c0 + rr)*Ec + d0 + hf*32;
        *(uint4*)&bt[rr][hf*32]      = *(const uint4*)(wsrc);
        *(uint4*)&bt[rr][hf*32 + 8]  = *(const uint4*)(wsrc + 8);
        *(uint4*)&bt[rr][hf*32 + 16] = *(const uint4*)(wsrc + 16);
        *(uint4*)&bt[rr][hf*32 + 24] = *(const uint4*)(wsrc + 24);
        __syncthreads();
        #pragma unroll
        for (int ks = 0; ks < 2; ks++){
            bf8 a0 = *(const bf8*)&at[wv_*32 + lc][ks*32 + quad*8];
            bf8 a1 = *(const bf8*)&at[wv_*32 + 16 + lc][ks*32 + quad*8];
            #pragma unroll
            for (int nb = 0; nb < 8; nb++){
                bf8 bb = *(const bf8*)&bt[nb*16 + lc][ks*32 + quad*8];
                acc[0][nb] = MFMA(a0, bb, acc[0][nb]);
                acc[1][nb] = MFMA(a1, bb, acc[1][nb]);
            }
        }
        __syncthreads();
    }
    #pragma unroll
    for (int mb = 0; mb < 2; mb++){
        #pragma unroll
        for (int r = 0; r < 4; r++){
            int row = wv_*32 + mb*16 + quad*4 + r;
            int s_ = sperm[row];
            if (s_ < 0) continue;
            #pragma unroll
            for (int nb = 0; nb < 8; nb++){
                int col = c0 + nb*16 + lc;
                opre[((size_t)(b*Sc + s_))*Dc + col] = acc[mb][nb][r];
            }
        }
    }
}

// ---------------------------------------------------------------------------
// 11. final RMSNorm over D -> out
// ---------------------------------------------------------------------------
__global__ __launch_bounds__(256) void k_onorm(
    const float* __restrict__ opre, const float* __restrict__ anw,
    const int* __restrict__ mod, float* __restrict__ out)
{
    int row = blockIdx.x;
    int m = mod[row];
    int t = threadIdx.x;
    float val[4];
    float ss = 0.f;
    #pragma unroll
    for (int j=0;j<4;j++){
        val[j] = opre[(size_t)row*Dc + t + 256*j];
        ss += val[j]*val[j];
    }
    #pragma unroll
    for (int o=32;o>0;o>>=1) ss += __shfl_xor(ss, o, 64);
    __shared__ float red[4];
    int wid = t>>6, lane = t&63;
    if (lane==0) red[wid]=ss;
    __syncthreads();
    float tot = red[0]+red[1]+red[2]+red[3];
    float rms = rsqrtf(tot*(1.f/1024.f) + EPSc);
    #pragma unroll
    for (int j=0;j<4;j++)
        out[(size_t)row*Dc + t + 256*j] = val[j]*rms*anw[m*Dc + t + 256*j];
}

// ---------------------------------------------------------------------------
extern "C" void kernel_launch(void* const* d_in, const int* in_sizes, int n_in,
                              void* d_out, int out_size, void* d_ws, size_t ws_size,
                              hipStream_t stream)
{
    const float* x    = (const float*)d_in[0];
    const float* mask = (const float*)d_in[1];
    const int*   mod  = (const int*)  d_in[2];
    const float* Wq   = (const float*)d_in[3];
    const float* Wk   = (const float*)d_in[4];
    const float* Wv   = (const float*)d_in[5];
    const float* Wo   = (const float*)d_in[6];
    const float* qnw  = (const float*)d_in[7];
    const float* knw  = (const float*)d_in[8];
    const float* anw  = (const float*)d_in[9];

    float* out   = (float*)d_out;                 // [B,S,D]
    float* awout = out + (size_t)Bc*Sc*Dc;        // [B,S,S]

    float* ws = (float*)d_ws;
    u16* qb    = (u16*)(ws + 0);
    u16* kb    = (u16*)(ws + 2097152);
    u16* vb    = (u16*)(ws + 4194304);   // dead after k_vt -> ctx partial 1
    u16* xb    = (u16*)(ws + 6291456);   // dead after k_qkv -> ctx partial 0
    u16* ctx0  = xb;
    u16* ctx1  = vb;
    u16* vtb   = (u16*)(ws + 8388608);
    u16* wqT   = (u16*)(ws + 10485760);
    u16* wkT   = (u16*)(ws + 11534336);
    u16* wvT   = (u16*)(ws + 12582912);
    u16* woT   = (u16*)(ws + 13631488);
    float* mst = ws + 14680064;
    float* lst = ws + 14745600;
    float* pmst= ws + 14811136;
    float* plst= ws + 15073280;
    u16* maskb = (u16*)(ws + 15335424);  // mask*log2e, bf16
    int* perm  = (int*)(ws + 17432576);
    int* tmeta = perm + NTILES*TILE_R;
    float* opre = ws;                    // aliases qb+kb (dead by then)

    k_perm  <<<dim3(1),            256, 0, stream>>>(mod, perm, tmeta);
    k_f2b   <<<dim3(4096),         256, 0, stream>>>(x, xb, Bc*Sc*Dc);
    k_f2bs  <<<dim3(4096),         256, 0, stream>>>(mask, maskb, Sc*Sc, LOG2E);
    k_tcvt  <<<dim3(32,32,8),      256, 0, stream>>>(Wq, Wk, Wv, Wo, wqT, wkT, wvT, woT);
    k_qkv   <<<dim3(8,NTILES,3),   256, 0, stream>>>(xb, wqT, wkT, wvT, perm, tmeta,
                                                     qnw, knw, qb, kb, vb);
    k_vt    <<<dim3(32,32),        256, 0, stream>>>(vb, vtb);
    k_stats <<<dim3(16,16,8),      256, 0, stream>>>(qb, kb, maskb, pmst, plst);
    k_merge <<<dim3(256),          256, 0, stream>>>(pmst, plst, mst, lst);
    k_attnw <<<dim3(32,32,2),      256, 0, stream>>>(qb, kb, maskb, mst, lst, awout);
    k_flash <<<dim3(32,16,4),      256, 0, stream>>>(qb, kb, vtb, maskb, mst, lst, ctx0, ctx1);
    k_addc  <<<dim3(2048),         256, 0, stream>>>(ctx0, ctx1);
    k_oproj <<<dim3(8,NTILES),     256, 0, stream>>>(ctx0, woT, perm, tmeta, opre);
    k_onorm <<<dim3(4096),         256, 0, stream>>>(opre, anw, mod, out);
}

// Round 2
// 429.737 us; speedup vs baseline: 1.1670x; 1.1555x over previous
//
#include <hip/hip_runtime.h>
#include <cstdint>

#define Bc  2
#define Sc  2048
#define Dc  1024
#define Ec  1024
#define Hc  16
#define HDc 64
#define TTc (Bc*Sc)
#define TILE_R 128
#define NTILES 36
#define EPSc 1e-5f
#define LOG2E 1.44269504f
#define C2    (0.125f*LOG2E)

typedef unsigned short u16;
using bf8   = __attribute__((ext_vector_type(8))) short;
using f32x4 = __attribute__((ext_vector_type(4))) float;
#define MFMA(a,b,c) __builtin_amdgcn_mfma_f32_16x16x32_bf16(a,b,c,0,0,0)

static __device__ __forceinline__ u16 f2b(float f){
    return (u16)((__float_as_uint(f) + 0x8000u) >> 16);
}
static __device__ __forceinline__ float b2f(u16 s){
    return __uint_as_float(((unsigned)s) << 16);
}

// ---------------------------------------------------------------------------
// 1. modality-sorted token permutation, 128-padded segments per (b,m)
// ---------------------------------------------------------------------------
__global__ void k_perm(const int* __restrict__ mod, int* __restrict__ perm,
                       int* __restrict__ tmeta)
{
    __shared__ int cnt[4], segstart[4];
    int t = threadIdx.x;
    if (t < 4) cnt[t] = 0;
    __syncthreads();
    for (int i = t; i < TTc; i += 256){
        int b = i >> 11; int m = mod[i];
        atomicAdd(&cnt[b*2+m], 1);
    }
    __syncthreads();
    if (t == 0){
        int off = 0;
        for (int i = 0; i < 4; i++){
            segstart[i] = off;
            int pad = ((cnt[i] + TILE_R - 1)/TILE_R)*TILE_R;
            for (int tt = off/TILE_R; tt < (off+pad)/TILE_R; tt++) tmeta[tt] = i;
            off += pad;
        }
        for (int tt = off/TILE_R; tt < NTILES; tt++) tmeta[tt] = -1;
    }
    __syncthreads();
    if (t < 4) cnt[t] = 0;
    for (int i = t; i < NTILES*TILE_R; i += 256) perm[i] = -1;
    __syncthreads();
    for (int i = t; i < TTc; i += 256){
        int b = i >> 11, s = i & 2047; int m = mod[i];
        int r = atomicAdd(&cnt[b*2+m], 1);
        perm[segstart[b*2+m] + r] = s;
    }
}

// ---------------------------------------------------------------------------
// 2. fp32 -> bf16 elementwise (optionally scaled)
// ---------------------------------------------------------------------------
__global__ __launch_bounds__(256) void k_f2b(const float* __restrict__ src,
                                             u16* __restrict__ dst, int n)
{
    int i = (blockIdx.x*256 + threadIdx.x)*4;
    if (i >= n) return;
    float4 v = *(const float4*)&src[i];
    ushort4 o;
    o.x = f2b(v.x); o.y = f2b(v.y); o.z = f2b(v.z); o.w = f2b(v.w);
    *(ushort4*)&dst[i] = o;
}

__global__ __launch_bounds__(256) void k_f2bs(const float* __restrict__ src,
                                              u16* __restrict__ dst, int n, float sc)
{
    int i = (blockIdx.x*256 + threadIdx.x)*4;
    if (i >= n) return;
    float4 v = *(const float4*)&src[i];
    ushort4 o;
    o.x = f2b(v.x*sc); o.y = f2b(v.y*sc); o.z = f2b(v.z*sc); o.w = f2b(v.w*sc);
    *(ushort4*)&dst[i] = o;
}

// ---------------------------------------------------------------------------
// 3. transpose+convert all four weights in one launch; grid (32,32,8)
// ---------------------------------------------------------------------------
__global__ __launch_bounds__(256) void k_tcvt(
    const float* __restrict__ s0, const float* __restrict__ s1,
    const float* __restrict__ s2, const float* __restrict__ s3,
    u16* __restrict__ d0, u16* __restrict__ d1,
    u16* __restrict__ d2, u16* __restrict__ d3)
{
    int wsel = blockIdx.z >> 1, m = blockIdx.z & 1;
    const float* src = (wsel==0?s0:wsel==1?s1:wsel==2?s2:s3) + (size_t)m*1048576;
    u16*       dst = (wsel==0?d0:wsel==1?d1:wsel==2?d2:d3) + (size_t)m*1048576;
    __shared__ float sh[32][33];
    int t = threadIdx.x;
    int i0 = blockIdx.x*32, j0 = blockIdx.y*32;
    {
        int i = t >> 3, j4 = (t & 7)*4;
        *(float4*)&sh[i][j4] = *(const float4*)&src[(size_t)(i0+i)*1024 + j0 + j4];
    }
    __syncthreads();
    {
        int j = t >> 3, i4 = (t & 7)*4;
        ushort4 o;
        o.x = f2b(sh[i4+0][j]); o.y = f2b(sh[i4+1][j]);
        o.z = f2b(sh[i4+2][j]); o.w = f2b(sh[i4+3][j]);
        *(ushort4*)&dst[(size_t)(j0+j)*1024 + i0 + i4] = o;
    }
}

// ---------------------------------------------------------------------------
// 4. QKV projection, MFMA, with fused per-head RMSNorm for Q and K.
//    grid (8, NTILES, 3)
// ---------------------------------------------------------------------------
__global__ __launch_bounds__(256) void k_qkv(
    const u16* __restrict__ xb, const u16* __restrict__ wqT,
    const u16* __restrict__ wkT, const u16* __restrict__ wvT,
    const int* __restrict__ perm, const int* __restrict__ tmeta,
    const float* __restrict__ qnw, const float* __restrict__ knw,
    u16* __restrict__ qb, u16* __restrict__ kb, u16* __restrict__ vb)
{
    int meta = tmeta[blockIdx.y];
    if (meta < 0) return;
    int b = meta >> 1, m = meta & 1;
    const u16* W = (blockIdx.z==0 ? wqT : (blockIdx.z==1 ? wkT : wvT)) + (size_t)m*Ec*Dc;
    u16* outp    = (blockIdx.z==0 ? qb  : (blockIdx.z==1 ? kb  : vb));
    int c0 = blockIdx.x*128;
    int t = threadIdx.x, lane = t & 63, wv_ = t >> 6;
    int quad = lane >> 4, lc = lane & 15;

    __shared__ u16 at[128][72];
    __shared__ u16 bt[128][72];
    __shared__ int sperm[128];
    if (t < 128) sperm[t] = perm[blockIdx.y*128 + t];
    f32x4 acc[2][8];
    #pragma unroll
    for (int i=0;i<2;i++)
        #pragma unroll
        for (int j=0;j<8;j++) acc[i][j] = (f32x4){0.f,0.f,0.f,0.f};
    __syncthreads();

    int rr = t >> 1, hf = t & 1;
    for (int d0 = 0; d0 < Dc; d0 += 64){
        int s_ = sperm[rr];
        if (s_ >= 0){
            const u16* src = xb + ((size_t)(b*Sc + s_))*Dc + d0 + hf*32;
            *(uint4*)&at[rr][hf*32]      = *(const uint4*)(src);
            *(uint4*)&at[rr][hf*32 + 8]  = *(const uint4*)(src + 8);
            *(uint4*)&at[rr][hf*32 + 16] = *(const uint4*)(src + 16);
            *(uint4*)&at[rr][hf*32 + 24] = *(const uint4*)(src + 24);
        } else {
            uint4 z = make_uint4(0,0,0,0);
            *(uint4*)&at[rr][hf*32]      = z;
            *(uint4*)&at[rr][hf*32 + 8]  = z;
            *(uint4*)&at[rr][hf*32 + 16] = z;
            *(uint4*)&at[rr][hf*32 + 24] = z;
        }
        const u16* wsrc = W + (size_t)(c0 + rr)*Dc + d0 + hf*32;
        *(uint4*)&bt[rr][hf*32]      = *(const uint4*)(wsrc);
        *(uint4*)&bt[rr][hf*32 + 8]  = *(const uint4*)(wsrc + 8);
        *(uint4*)&bt[rr][hf*32 + 16] = *(const uint4*)(wsrc + 16);
        *(uint4*)&bt[rr][hf*32 + 24] = *(const uint4*)(wsrc + 24);
        __syncthreads();
        #pragma unroll
        for (int ks = 0; ks < 2; ks++){
            bf8 a0 = *(const bf8*)&at[wv_*32 + lc][ks*32 + quad*8];
            bf8 a1 = *(const bf8*)&at[wv_*32 + 16 + lc][ks*32 + quad*8];
            #pragma unroll
            for (int nb = 0; nb < 8; nb++){
                bf8 bb = *(const bf8*)&bt[nb*16 + lc][ks*32 + quad*8];
                acc[0][nb] = MFMA(a0, bb, acc[0][nb]);
                acc[1][nb] = MFMA(a1, bb, acc[1][nb]);
            }
        }
        __syncthreads();
    }

    if (blockIdx.z < 2){
        const float* nw = (blockIdx.z==0 ? qnw : knw) + m*HDc;
        float w0 = nw[lc], w1 = nw[16+lc], w2 = nw[32+lc], w3 = nw[48+lc];
        #pragma unroll
        for (int mb = 0; mb < 2; mb++){
            #pragma unroll
            for (int r = 0; r < 4; r++){
                #pragma unroll
                for (int g = 0; g < 2; g++){
                    float ss = 0.f;
                    #pragma unroll
                    for (int j = 0; j < 4; j++){
                        float v2 = acc[mb][g*4+j][r];
                        ss += v2*v2;
                    }
                    ss += __shfl_xor(ss, 1, 64);
                    ss += __shfl_xor(ss, 2, 64);
                    ss += __shfl_xor(ss, 4, 64);
                    ss += __shfl_xor(ss, 8, 64);
                    float rs = rsqrtf(ss*(1.f/64.f) + EPSc);
                    acc[mb][g*4+0][r] *= rs*w0;
                    acc[mb][g*4+1][r] *= rs*w1;
                    acc[mb][g*4+2][r] *= rs*w2;
                    acc[mb][g*4+3][r] *= rs*w3;
                }
            }
        }
    }

    int h0 = c0 >> 6;
    #pragma unroll
    for (int mb = 0; mb < 2; mb++){
        #pragma unroll
        for (int r = 0; r < 4; r++){
            int row = wv_*32 + mb*16 + quad*4 + r;
            int s_ = sperm[row];
            if (s_ < 0) continue;
            #pragma unroll
            for (int nb = 0; nb < 8; nb++){
                int col = nb*16 + lc;
                int h = h0 + (col >> 6), hd = col & 63;
                outp[(((size_t)(b*Hc + h))*Sc + s_)*HDc + hd] = f2b(acc[mb][nb][r]);
            }
        }
    }
}

// ---------------------------------------------------------------------------
// 6. V transpose via LDS tiles: vb [BH][S][HD] -> vtb [BH][HD][S]
// ---------------------------------------------------------------------------
__global__ __launch_bounds__(256) void k_vt(const u16* __restrict__ vb,
                                            u16* __restrict__ vtb)
{
    __shared__ u16 sh[64][72];
    int t = threadIdx.x;
    int s0 = blockIdx.x*64, bh = blockIdx.y;
    {
        int rr = t >> 2, cc = (t & 3)*16;
        const u16* src = vb + ((size_t)bh*Sc + s0 + rr)*HDc + cc;
        *(uint4*)&sh[rr][cc]   = *(const uint4*)(src);
        *(uint4*)&sh[rr][cc+8] = *(const uint4*)(src+8);
    }
    __syncthreads();
    {
        int hd = t >> 2, sc = (t & 3)*16;
        u16 tmp[16];
        #pragma unroll
        for (int j = 0; j < 16; j++) tmp[j] = sh[sc+j][hd];
        u16* dst = vtb + ((size_t)bh*HDc + hd)*Sc + s0 + sc;
        *(uint4*)(dst)   = *(const uint4*)&tmp[0];
        *(uint4*)(dst+8) = *(const uint4*)&tmp[8];
    }
}

// ---------------------------------------------------------------------------
// 9. flash PV with ONLINE softmax (stats fused), split-K x2:
//    grid (32, 16, 4): z = b*2 + half.
//    Swapped QK^T (mfma(K,Q)) + pi-permuted K staging: each lane's 16
//    P-values belong to ONE q-row (q = lc), so the online row max/sum is
//    2 shfl_xor; oacc rescale factors for rows quad*4+r come via 4 shfl
//    from lanes 0..15. Emits per-half (m, l) and ctx normalized by the
//    half's own l; k_merge2 + k_addc combine the halves exactly.
// ---------------------------------------------------------------------------
__global__ __launch_bounds__(256) void k_flash(
    const u16* __restrict__ qb, const u16* __restrict__ kb,
    const u16* __restrict__ vtb, const u16* __restrict__ maskb,
    float* __restrict__ pm, float* __restrict__ pl,
    u16* __restrict__ c0, u16* __restrict__ c1)
{
    int qs0 = blockIdx.x*64, h = blockIdx.y;
    int b = blockIdx.z >> 1, half = blockIdx.z & 1;
    u16* ctxh = half ? c1 : c0;
    int t = threadIdx.x, lane = t & 63, wv_ = t >> 6;
    int quad = lane >> 4, lc = lane & 15;
    __shared__ u16 kt[64][72];
    __shared__ u16 vt[64][72];
    __shared__ u16 mpt[64][72];
    const u16* qp  = qb  + ((size_t)(b*Hc+h))*Sc*HDc;
    const u16* kp  = kb  + ((size_t)(b*Hc+h))*Sc*HDc;
    const u16* vtp = vtb + ((size_t)(b*Hc+h))*HDc*Sc;
    bf8 aq[2];
    #pragma unroll
    for (int ks = 0; ks < 2; ks++)
        aq[ks] = *(const bf8*)(qp + (size_t)(qs0 + wv_*16 + lc)*HDc + ks*32 + quad*8);
    // online stats for this lane's q row (q = qs0 + wv*16 + lc)
    float rm = -1.0e30f, rl = 0.f;
    f32x4 oacc[4];
    #pragma unroll
    for (int j=0;j<4;j++) oacc[j] = (f32x4){0.f,0.f,0.f,0.f};

    int rr = t >> 2, cc = (t & 3)*16;
    // pi: global k-row rr -> LDS row (b5<<5)|(b2<<4)|(b4<<3)|(b3<<2)|(b1<<1)|b0
    int pr = (rr & 0x23) | ((rr & 0x04) << 2) | ((rr & 0x18) >> 1);
    int kc0 = half*1024;
    for (int kc = kc0; kc < kc0 + 1024; kc += 64){
        __syncthreads();
        {
            const u16* s1 = kp + (size_t)(kc+rr)*HDc + cc;
            *(uint4*)&kt[pr][cc]   = *(const uint4*)(s1);
            *(uint4*)&kt[pr][cc+8] = *(const uint4*)(s1+8);
            const u16* s2 = vtp + (size_t)rr*Sc + kc + cc;
            *(uint4*)&vt[rr][cc]   = *(const uint4*)(s2);
            *(uint4*)&vt[rr][cc+8] = *(const uint4*)(s2+8);
            const u16* ms = maskb + (size_t)(qs0+rr)*Sc + kc + cc;
            *(uint4*)&mpt[rr][cc]   = *(const uint4*)(ms);
            *(uint4*)&mpt[rr][cc+8] = *(const uint4*)(ms+8);
        }
        __syncthreads();
        // S^T = K * Q^T : acc[nb] row (quad*4+r) = LDS k-row 16nb+4quad+r,
        // col = lc = q
        f32x4 acc[4];
        #pragma unroll
        for (int j=0;j<4;j++) acc[j] = (f32x4){0.f,0.f,0.f,0.f};
        #pragma unroll
        for (int ks = 0; ks < 2; ks++){
            #pragma unroll
            for (int nb = 0; nb < 4; nb++){
                bf8 ak = *(const bf8*)&kt[nb*16 + lc][ks*32 + quad*8];
                acc[nb] = MFMA(ak, aq[ks], acc[nb]);
            }
        }
        // scores + mask, tile row-max
        const u16* mrow = &mpt[wv_*16 + lc][0];
        float sv[4][4];
        float mx = -1.0e30f;
        #pragma unroll
        for (int a1 = 0; a1 < 2; a1++){
            #pragma unroll
            for (int b1 = 0; b1 < 2; b1++){
                int nb = 2*a1 + b1;
                ushort4 mv = *(const ushort4*)(mrow + a1*32 + quad*8 + b1*4);
                #pragma unroll
                for (int r = 0; r < 4; r++){
                    u16 mraw = (r==0?mv.x:r==1?mv.y:r==2?mv.z:mv.w);
                    float s2v = fmaf(acc[nb][r], C2, b2f(mraw));
                    sv[nb][r] = s2v;
                    mx = fmaxf(mx, s2v);
                }
            }
        }
        mx = fmaxf(mx, __shfl_xor(mx, 16, 64));
        mx = fmaxf(mx, __shfl_xor(mx, 32, 64));
        float nm = fmaxf(rm, mx);
        if (__any(nm > rm)){
            float fac = exp2f(rm - nm);
            rm = nm;
            rl *= fac;
            float f0 = __shfl(fac, quad*4+0, 64);
            float f1 = __shfl(fac, quad*4+1, 64);
            float f2 = __shfl(fac, quad*4+2, 64);
            float f3 = __shfl(fac, quad*4+3, 64);
            #pragma unroll
            for (int nb = 0; nb < 4; nb++){
                oacc[nb][0] *= f0; oacc[nb][1] *= f1;
                oacc[nb][2] *= f2; oacc[nb][3] *= f3;
            }
        }
        // P (unnormalized, <=1) packs directly into PV A-fragments
        float ts = 0.f;
        #pragma unroll
        for (int a1 = 0; a1 < 2; a1++){
            bf8 ap;
            #pragma unroll
            for (int b1 = 0; b1 < 2; b1++){
                int nb = 2*a1 + b1;
                #pragma unroll
                for (int r = 0; r < 4; r++){
                    float p = exp2f(sv[nb][r] - rm);
                    ts += p;
                    ap[b1*4 + r] = (short)f2b(p);
                }
            }
            #pragma unroll
            for (int nb2 = 0; nb2 < 4; nb2++){
                bf8 bv = *(const bf8*)&vt[nb2*16 + lc][a1*32 + quad*8];
                oacc[nb2] = MFMA(ap, bv, oacc[nb2]);
            }
        }
        ts += __shfl_xor(ts, 16, 64);
        ts += __shfl_xor(ts, 32, 64);
        rl += ts;
    }
    // per-half stats out (lanes with quad==0 hold rows 0..15 of this wave)
    if (quad == 0){
        size_t srow = ((size_t)(b*Hc+h))*Sc + qs0 + wv_*16 + lc;
        pm[(size_t)half*65536 + srow] = rm;
        pl[(size_t)half*65536 + srow] = rl;
    }
    // ctx normalized by this half's own l
    float i0 = 1.f/__shfl(rl, quad*4+0, 64);
    float i1 = 1.f/__shfl(rl, quad*4+1, 64);
    float i2 = 1.f/__shfl(rl, quad*4+2, 64);
    float i3 = 1.f/__shfl(rl, quad*4+3, 64);
    #pragma unroll
    for (int r = 0; r < 4; r++){
        float ir = (r==0?i0:r==1?i1:r==2?i2:i3);
        int tok = qs0 + wv_*16 + quad*4 + r;
        #pragma unroll
        for (int nb = 0; nb < 4; nb++){
            int hd = nb*16 + lc;
            ctxh[((size_t)(b*Sc + tok))*Ec + h*HDc + hd] = f2b(oacc[nb][r]*ir);
        }
    }
}

// ---------------------------------------------------------------------------
// 9b. merge the two half stats -> combine weights + attnw constant.
//     cc = M + log2(L) so attnw's per-element work is exp2(s*C2 - cc).
// ---------------------------------------------------------------------------
__global__ __launch_bounds__(256) void k_merge(
    const float* __restrict__ pm, const float* __restrict__ pl,
    float* __restrict__ lstc, float* __restrict__ w0, float* __restrict__ w1)
{
    int r = blockIdx.x*256 + threadIdx.x;
    float m0 = pm[r],        m1 = pm[65536 + r];
    float l0 = pl[r],        l1 = pl[65536 + r];
    float M  = fmaxf(m0, m1);
    float e0 = exp2f(m0 - M)*l0;
    float e1 = exp2f(m1 - M)*l1;
    float L  = e0 + e1;
    float iL = 1.f/L;
    lstc[r] = M + log2f(L);
    w0[r] = e0*iL;
    w1[r] = e1*iL;
}

// ---------------------------------------------------------------------------
// 9c. weighted combine of the two ctx halves: c0 = w0*c0 + w1*c1
// ---------------------------------------------------------------------------
__global__ __launch_bounds__(256) void k_addc(u16* __restrict__ c0,
                                              const u16* __restrict__ c1,
                                              const float* __restrict__ w0,
                                              const float* __restrict__ w1)
{
    int i = (blockIdx.x*256 + threadIdx.x)*8;
    int hh = (i >> 6) & 15, s = (i >> 10) & 2047, bb = i >> 21;
    int wi = ((bb*Hc + hh) << 11) + s;
    float wa = w0[wi], wb = w1[wi];
    ushort4 a0 = *(ushort4*)&c0[i],   a1 = *(ushort4*)&c0[i+4];
    ushort4 b0 = *(const ushort4*)&c1[i], b1 = *(const ushort4*)&c1[i+4];
    ushort4 o0, o1;
    o0.x = f2b(b2f(a0.x)*wa + b2f(b0.x)*wb); o0.y = f2b(b2f(a0.y)*wa + b2f(b0.y)*wb);
    o0.z = f2b(b2f(a0.z)*wa + b2f(b0.z)*wb); o0.w = f2b(b2f(a0.w)*wa + b2f(b0.w)*wb);
    o1.x = f2b(b2f(a1.x)*wa + b2f(b1.x)*wb); o1.y = f2b(b2f(a1.y)*wa + b2f(b1.y)*wb);
    o1.z = f2b(b2f(a1.z)*wa + b2f(b1.z)*wb); o1.w = f2b(b2f(a1.w)*wa + b2f(b1.w)*wb);
    *(ushort4*)&c0[i]   = o0;
    *(ushort4*)&c0[i+4] = o1;
}

// ---------------------------------------------------------------------------
// 8. attn_weights: q-tile 64, k-tile 64, loop all 16 h, NO atomics.
//    grid (32, 32, 2) = (q, k, b). Uses folded cc = M + log2(L).
// ---------------------------------------------------------------------------
__global__ __launch_bounds__(256) void k_attnw(
    const u16* __restrict__ qb, const u16* __restrict__ kb,
    const u16* __restrict__ maskb, const float* __restrict__ lstc,
    float* __restrict__ awout)
{
    int qs0 = blockIdx.x*64, ks0 = blockIdx.y*64, b = blockIdx.z;
    int t = threadIdx.x, lane = t & 63, wv_ = t >> 6;
    int quad = lane >> 4, lc = lane & 15;
    __shared__ u16 kt[64][72];
    __shared__ float scc[64];
    f32x4 T[4];
    #pragma unroll
    for (int j=0;j<4;j++) T[j] = (f32x4){0.f,0.f,0.f,0.f};

    for (int h = 0; h < Hc; h++){
        __syncthreads();
        const u16* qp = qb + ((size_t)(b*Hc+h))*Sc*HDc;
        const u16* kp = kb + ((size_t)(b*Hc+h))*Sc*HDc;
        bf8 aq[2];
        #pragma unroll
        for (int ks = 0; ks < 2; ks++)
            aq[ks] = *(const bf8*)(qp + (size_t)(qs0 + wv_*16 + lc)*HDc + ks*32 + quad*8);
        {
            int rr = t >> 2, cc = (t & 3)*16;
            const u16* s2 = kp + (size_t)(ks0+rr)*HDc + cc;
            *(uint4*)&kt[rr][cc]   = *(const uint4*)(s2);
            *(uint4*)&kt[rr][cc+8] = *(const uint4*)(s2+8);
        }
        if (t < 64)
            scc[t] = lstc[((size_t)(b*Hc+h))*Sc + qs0 + t];
        __syncthreads();
        f32x4 acc[4];
        #pragma unroll
        for (int j=0;j<4;j++) acc[j] = (f32x4){0.f,0.f,0.f,0.f};
        #pragma unroll
        for (int ks = 0; ks < 2; ks++){
            #pragma unroll
            for (int nb = 0; nb < 4; nb++){
                bf8 bb = *(const bf8*)&kt[nb*16 + lc][ks*32 + quad*8];
                acc[nb] = MFMA(aq[ks], bb, acc[nb]);
            }
        }
        #pragma unroll
        for (int r = 0; r < 4; r++){
            int row = wv_*16 + quad*4 + r;
            float cv = scc[row];
            #pragma unroll
            for (int nb = 0; nb < 4; nb++){
                float s = fminf(fmaf(acc[nb][r], C2, -cv), 80.f);
                T[nb][r] += exp2f(s);
            }
        }
    }
    #pragma unroll
    for (int r = 0; r < 4; r++){
        int gq = qs0 + wv_*16 + quad*4 + r;
        #pragma unroll
        for (int nb = 0; nb < 4; nb++){
            int gk = ks0 + nb*16 + lc;
            float mk = b2f(maskb[(size_t)gq*Sc + gk]);   // mask*log2e
            awout[(size_t)b*Sc*Sc + (size_t)gq*Sc + gk]
                = T[nb][r]*exp2f(mk)*(1.f/16.f);
        }
    }
}

// ---------------------------------------------------------------------------
// 10. output projection, MFMA. grid (8, NTILES).
// ---------------------------------------------------------------------------
__global__ __launch_bounds__(256) void k_oproj(
    const u16* __restrict__ ctxb, const u16* __restrict__ woT,
    const int* __restrict__ perm, const int* __restrict__ tmeta,
    float* __restrict__ opre)
{
    int meta = tmeta[blockIdx.y];
    if (meta < 0) return;
    int b = meta >> 1, m = meta & 1;
    const u16* W = woT + (size_t)m*Ec*Dc;
    int c0 = blockIdx.x*128;
    int t = threadIdx.x, lane = t & 63, wv_ = t >> 6;
    int quad = lane >> 4, lc = lane & 15;
    __shared__ u16 at[128][72];
    __shared__ u16 bt[128][72];
    __shared__ int sperm[128];
    if (t < 128) sperm[t] = perm[blockIdx.y*128 + t];
    f32x4 acc[2][8];
    #pragma unroll
    for (int i=0;i<2;i++)
        #pragma unroll
        for (int j=0;j<8;j++) acc[i][j] = (f32x4){0.f,0.f,0.f,0.f};
    __syncthreads();

    int rr = t >> 1, hf = t & 1;
    for (int d0 = 0; d0 < Ec; d0 += 64){
        int s_ = sperm[rr];
        if (s_ >= 0){
            const u16* src = ctxb + ((size_t)(b*Sc + s_))*Ec + d0 + hf*32;
            *(uint4*)&at[rr][hf*32]      = *(const uint4*)(src);
            *(uint4*)&at[rr][hf*32 + 8]  = *(const uint4*)(src + 8);
            *(uint4*)&at[rr][hf*32 + 16] = *(const uint4*)(src + 16);
            *(uint4*)&at[rr][hf*32 + 24] = *(const uint4*)(src + 24);
        } else {
            uint4 z = make_uint4(0,0,0,0);
            *(uint4*)&at[rr][hf*32]      = z;
            *(uint4*)&at[rr][hf*32 + 8]  = z;
            *(uint4*)&at[rr][hf*32 + 16] = z;
            *(uint4*)&at[rr][hf*32 + 24] = z;
        }
        const u16* wsrc = W + (size_t)(c0 + rr)*Ec + d0 + hf*32;
        *(uint4*)&bt[rr][hf*32]      = *(const uint4*)(wsrc);
        *(uint4*)&bt[rr][hf*32 + 8]  = *(const uint4*)(wsrc + 8);
        *(uint4*)&bt[rr][hf*32 + 16] = *(const uint4*)(wsrc + 16);
        *(uint4*)&bt[rr][hf*32 + 24] = *(const uint4*)(wsrc + 24);
        __syncthreads();
        #pragma unroll
        for (int ks = 0; ks < 2; ks++){
            bf8 a0 = *(const bf8*)&at[wv_*32 + lc][ks*32 + quad*8];
            bf8 a1 = *(const bf8*)&at[wv_*32 + 16 + lc][ks*32 + quad*8];
            #pragma unroll
            for (int nb = 0; nb < 8; nb++){
                bf8 bb = *(const bf8*)&bt[nb*16 + lc][ks*32 + quad*8];
                acc[0][nb] = MFMA(a0, bb, acc[0][nb]);
                acc[1][nb] = MFMA(a1, bb, acc[1][nb]);
            }
        }
        __syncthreads();
    }
    #pragma unroll
    for (int mb = 0; mb < 2; mb++){
        #pragma unroll
        for (int r = 0; r < 4; r++){
            int row = wv_*32 + mb*16 + quad*4 + r;
            int s_ = sperm[row];
            if (s_ < 0) continue;
            #pragma unroll
            for (int nb = 0; nb < 8; nb++){
                int col = c0 + nb*16 + lc;
                opre[((size_t)(b*Sc + s_))*Dc + col] = acc[mb][nb][r];
            }
        }
    }
}

// ---------------------------------------------------------------------------
// 11. final RMSNorm over D -> out
// ---------------------------------------------------------------------------
__global__ __launch_bounds__(256) void k_onorm(
    const float* __restrict__ opre, const float* __restrict__ anw,
    const int* __restrict__ mod, float* __restrict__ out)
{
    int row = blockIdx.x;
    int m = mod[row];
    int t = threadIdx.x;
    float val[4];
    float ss = 0.f;
    #pragma unroll
    for (int j=0;j<4;j++){
        val[j] = opre[(size_t)row*Dc + t + 256*j];
        ss += val[j]*val[j];
    }
    #pragma unroll
    for (int o=32;o>0;o>>=1) ss += __shfl_xor(ss, o, 64);
    __shared__ float red[4];
    int wid = t>>6, lane = t&63;
    if (lane==0) red[wid]=ss;
    __syncthreads();
    float tot = red[0]+red[1]+red[2]+red[3];
    float rms = rsqrtf(tot*(1.f/1024.f) + EPSc);
    #pragma unroll
    for (int j=0;j<4;j++)
        out[(size_t)row*Dc + t + 256*j] = val[j]*rms*anw[m*Dc + t + 256*j];
}

// ---------------------------------------------------------------------------
extern "C" void kernel_launch(void* const* d_in, const int* in_sizes, int n_in,
                              void* d_out, int out_size, void* d_ws, size_t ws_size,
                              hipStream_t stream)
{
    const float* x    = (const float*)d_in[0];
    const float* mask = (const float*)d_in[1];
    const int*   mod  = (const int*)  d_in[2];
    const float* Wq   = (const float*)d_in[3];
    const float* Wk   = (const float*)d_in[4];
    const float* Wv   = (const float*)d_in[5];
    const float* Wo   = (const float*)d_in[6];
    const float* qnw  = (const float*)d_in[7];
    const float* knw  = (const float*)d_in[8];
    const float* anw  = (const float*)d_in[9];

    float* out   = (float*)d_out;                 // [B,S,D]
    float* awout = out + (size_t)Bc*Sc*Dc;        // [B,S,S]

    float* ws = (float*)d_ws;
    u16* qb    = (u16*)(ws + 0);
    u16* kb    = (u16*)(ws + 2097152);
    u16* vb    = (u16*)(ws + 4194304);   // dead after k_vt -> ctx partial 1
    u16* xb    = (u16*)(ws + 6291456);   // dead after k_qkv -> ctx partial 0
    u16* ctx0  = xb;
    u16* ctx1  = vb;
    u16* vtb   = (u16*)(ws + 8388608);
    u16* wqT   = (u16*)(ws + 10485760);
    u16* wkT   = (u16*)(ws + 11534336);
    u16* wvT   = (u16*)(ws + 12582912);
    u16* woT   = (u16*)(ws + 13631488);
    float* lstc= ws + 14680064;          // M + log2(L), 65536
    float* pm  = ws + 14811136;          // per-half m, 2*65536
    float* pl  = pm + 131072;            // per-half l, 2*65536
    float* w0  = ws + 15073280;          // combine weights, 65536 each
    float* w1  = w0 + 65536;
    u16* maskb = (u16*)(ws + 15335424);  // mask*log2e, bf16
    int* perm  = (int*)(ws + 17432576);
    int* tmeta = perm + NTILES*TILE_R;
    float* opre = ws;                    // aliases qb+kb (dead by then)

    k_perm  <<<dim3(1),            256, 0, stream>>>(mod, perm, tmeta);
    k_f2b   <<<dim3(4096),         256, 0, stream>>>(x, xb, Bc*Sc*Dc);
    k_f2bs  <<<dim3(4096),         256, 0, stream>>>(mask, maskb, Sc*Sc, LOG2E);
    k_tcvt  <<<dim3(32,32,8),      256, 0, stream>>>(Wq, Wk, Wv, Wo, wqT, wkT, wvT, woT);
    k_qkv   <<<dim3(8,NTILES,3),   256, 0, stream>>>(xb, wqT, wkT, wvT, perm, tmeta,
                                                     qnw, knw, qb, kb, vb);
    k_vt    <<<dim3(32,32),        256, 0, stream>>>(vb, vtb);
    k_flash <<<dim3(32,16,4),      256, 0, stream>>>(qb, kb, vtb, maskb, pm, pl, ctx0, ctx1);
    k_merge <<<dim3(256),          256, 0, stream>>>(pm, pl, lstc, w0, w1);
    k_attnw <<<dim3(32,32,2),      256, 0, stream>>>(qb, kb, maskb, lstc, awout);
    k_addc  <<<dim3(2048),         256, 0, stream>>>(ctx0, ctx1, w0, w1);
    k_oproj <<<dim3(8,NTILES),     256, 0, stream>>>(ctx0, woT, perm, tmeta, opre);
    k_onorm <<<dim3(4096),         256, 0, stream>>>(opre, anw, mod, out);
}

// Round 3
// 402.955 us; speedup vs baseline: 1.2445x; 1.0665x over previous
//
#include <hip/hip_runtime.h>
#include <cstdint>

#define Bc  2
#define Sc  2048
#define Dc  1024
#define Ec  1024
#define Hc  16
#define HDc 64
#define TTc (Bc*Sc)
#define TILE_R 128
#define NTILES 36
#define EPSc 1e-5f
#define LOG2E 1.44269504f
#define C2    (0.125f*LOG2E)

typedef unsigned short u16;
using bf8   = __attribute__((ext_vector_type(8))) short;
using f32x4 = __attribute__((ext_vector_type(4))) float;
#define MFMA(a,b,c) __builtin_amdgcn_mfma_f32_16x16x32_bf16(a,b,c,0,0,0)

static __device__ __forceinline__ u16 f2b(float f){
    return (u16)((__float_as_uint(f) + 0x8000u) >> 16);
}
static __device__ __forceinline__ float b2f(u16 s){
    return __uint_as_float(((unsigned)s) << 16);
}
// XOR-swizzled LDS addressing: tiles are [R][64] u16, 8-u16 (16B) groups,
// group index col8 swizzled by row&7 -> fragment ds_read_b128 is
// bank-conflict-free (bank start (col8^row&7)*4 covers all 32 banks
// across lc=0..7).
static __device__ __forceinline__ u16* swz(u16* base, int row, int col8){
    return base + row*64 + ((col8 ^ (row & 7)) << 3);
}
static __device__ __forceinline__ const u16* swzc(const u16* base, int row, int col8){
    return base + row*64 + ((col8 ^ (row & 7)) << 3);
}

// ---------------------------------------------------------------------------
// 1. modality-sorted token permutation, 128-padded segments per (b,m)
// ---------------------------------------------------------------------------
__global__ void k_perm(const int* __restrict__ mod, int* __restrict__ perm,
                       int* __restrict__ tmeta)
{
    __shared__ int cnt[4], segstart[4];
    int t = threadIdx.x;
    if (t < 4) cnt[t] = 0;
    __syncthreads();
    for (int i = t; i < TTc; i += 256){
        int b = i >> 11; int m = mod[i];
        atomicAdd(&cnt[b*2+m], 1);
    }
    __syncthreads();
    if (t == 0){
        int off = 0;
        for (int i = 0; i < 4; i++){
            segstart[i] = off;
            int pad = ((cnt[i] + TILE_R - 1)/TILE_R)*TILE_R;
            for (int tt = off/TILE_R; tt < (off+pad)/TILE_R; tt++) tmeta[tt] = i;
            off += pad;
        }
        for (int tt = off/TILE_R; tt < NTILES; tt++) tmeta[tt] = -1;
    }
    __syncthreads();
    if (t < 4) cnt[t] = 0;
    for (int i = t; i < NTILES*TILE_R; i += 256) perm[i] = -1;
    __syncthreads();
    for (int i = t; i < TTc; i += 256){
        int b = i >> 11, s = i & 2047; int m = mod[i];
        int r = atomicAdd(&cnt[b*2+m], 1);
        perm[segstart[b*2+m] + r] = s;
    }
}

// ---------------------------------------------------------------------------
// 2. fp32 -> bf16 elementwise (optionally scaled)
// ---------------------------------------------------------------------------
__global__ __launch_bounds__(256) void k_f2b(const float* __restrict__ src,
                                             u16* __restrict__ dst, int n)
{
    int i = (blockIdx.x*256 + threadIdx.x)*4;
    if (i >= n) return;
    float4 v = *(const float4*)&src[i];
    ushort4 o;
    o.x = f2b(v.x); o.y = f2b(v.y); o.z = f2b(v.z); o.w = f2b(v.w);
    *(ushort4*)&dst[i] = o;
}

__global__ __launch_bounds__(256) void k_f2bs(const float* __restrict__ src,
                                              u16* __restrict__ dst, int n, float sc)
{
    int i = (blockIdx.x*256 + threadIdx.x)*4;
    if (i >= n) return;
    float4 v = *(const float4*)&src[i];
    ushort4 o;
    o.x = f2b(v.x*sc); o.y = f2b(v.y*sc); o.z = f2b(v.z*sc); o.w = f2b(v.w*sc);
    *(ushort4*)&dst[i] = o;
}

// ---------------------------------------------------------------------------
// 3. transpose+convert all four weights in one launch; grid (32,32,8)
// ---------------------------------------------------------------------------
__global__ __launch_bounds__(256) void k_tcvt(
    const float* __restrict__ s0, const float* __restrict__ s1,
    const float* __restrict__ s2, const float* __restrict__ s3,
    u16* __restrict__ d0, u16* __restrict__ d1,
    u16* __restrict__ d2, u16* __restrict__ d3)
{
    int wsel = blockIdx.z >> 1, m = blockIdx.z & 1;
    const float* src = (wsel==0?s0:wsel==1?s1:wsel==2?s2:s3) + (size_t)m*1048576;
    u16*       dst = (wsel==0?d0:wsel==1?d1:wsel==2?d2:d3) + (size_t)m*1048576;
    __shared__ float sh[32][33];
    int t = threadIdx.x;
    int i0 = blockIdx.x*32, j0 = blockIdx.y*32;
    {
        int i = t >> 3, j4 = (t & 7)*4;
        *(float4*)&sh[i][j4] = *(const float4*)&src[(size_t)(i0+i)*1024 + j0 + j4];
    }
    __syncthreads();
    {
        int j = t >> 3, i4 = (t & 7)*4;
        ushort4 o;
        o.x = f2b(sh[i4+0][j]); o.y = f2b(sh[i4+1][j]);
        o.z = f2b(sh[i4+2][j]); o.w = f2b(sh[i4+3][j]);
        *(ushort4*)&dst[(size_t)(j0+j)*1024 + i0 + i4] = o;
    }
}

// ---------------------------------------------------------------------------
// 4. QKV projection, MFMA, with fused per-head RMSNorm for Q and K.
//    grid (8, NTILES, 3). LDS tiles XOR-swizzled [128][64].
// ---------------------------------------------------------------------------
__global__ __launch_bounds__(256) void k_qkv(
    const u16* __restrict__ xb, const u16* __restrict__ wqT,
    const u16* __restrict__ wkT, const u16* __restrict__ wvT,
    const int* __restrict__ perm, const int* __restrict__ tmeta,
    const float* __restrict__ qnw, const float* __restrict__ knw,
    u16* __restrict__ qb, u16* __restrict__ kb, u16* __restrict__ vb)
{
    int meta = tmeta[blockIdx.y];
    if (meta < 0) return;
    int b = meta >> 1, m = meta & 1;
    const u16* W = (blockIdx.z==0 ? wqT : (blockIdx.z==1 ? wkT : wvT)) + (size_t)m*Ec*Dc;
    u16* outp    = (blockIdx.z==0 ? qb  : (blockIdx.z==1 ? kb  : vb));
    int c0 = blockIdx.x*128;
    int t = threadIdx.x, lane = t & 63, wv_ = t >> 6;
    int quad = lane >> 4, lc = lane & 15;

    __shared__ u16 at[128*64];
    __shared__ u16 bt[128*64];
    __shared__ int sperm[128];
    if (t < 128) sperm[t] = perm[blockIdx.y*128 + t];
    f32x4 acc[2][8];
    #pragma unroll
    for (int i=0;i<2;i++)
        #pragma unroll
        for (int j=0;j<8;j++) acc[i][j] = (f32x4){0.f,0.f,0.f,0.f};
    __syncthreads();

    int rr = t >> 1, hf = t & 1;
    for (int d0 = 0; d0 < Dc; d0 += 64){
        int s_ = sperm[rr];
        if (s_ >= 0){
            const u16* src = xb + ((size_t)(b*Sc + s_))*Dc + d0 + hf*32;
            *(uint4*)swz(at, rr, hf*4+0) = *(const uint4*)(src);
            *(uint4*)swz(at, rr, hf*4+1) = *(const uint4*)(src + 8);
            *(uint4*)swz(at, rr, hf*4+2) = *(const uint4*)(src + 16);
            *(uint4*)swz(at, rr, hf*4+3) = *(const uint4*)(src + 24);
        } else {
            uint4 z = make_uint4(0,0,0,0);
            *(uint4*)swz(at, rr, hf*4+0) = z;
            *(uint4*)swz(at, rr, hf*4+1) = z;
            *(uint4*)swz(at, rr, hf*4+2) = z;
            *(uint4*)swz(at, rr, hf*4+3) = z;
        }
        const u16* wsrc = W + (size_t)(c0 + rr)*Dc + d0 + hf*32;
        *(uint4*)swz(bt, rr, hf*4+0) = *(const uint4*)(wsrc);
        *(uint4*)swz(bt, rr, hf*4+1) = *(const uint4*)(wsrc + 8);
        *(uint4*)swz(bt, rr, hf*4+2) = *(const uint4*)(wsrc + 16);
        *(uint4*)swz(bt, rr, hf*4+3) = *(const uint4*)(wsrc + 24);
        __syncthreads();
        #pragma unroll
        for (int ks = 0; ks < 2; ks++){
            bf8 a0 = *(const bf8*)swzc(at, wv_*32 + lc,      ks*4 + quad);
            bf8 a1 = *(const bf8*)swzc(at, wv_*32 + 16 + lc, ks*4 + quad);
            #pragma unroll
            for (int nb = 0; nb < 8; nb++){
                bf8 bb = *(const bf8*)swzc(bt, nb*16 + lc, ks*4 + quad);
                acc[0][nb] = MFMA(a0, bb, acc[0][nb]);
                acc[1][nb] = MFMA(a1, bb, acc[1][nb]);
            }
        }
        __syncthreads();
    }

    if (blockIdx.z < 2){
        const float* nw = (blockIdx.z==0 ? qnw : knw) + m*HDc;
        float w0 = nw[lc], w1 = nw[16+lc], w2 = nw[32+lc], w3 = nw[48+lc];
        #pragma unroll
        for (int mb = 0; mb < 2; mb++){
            #pragma unroll
            for (int r = 0; r < 4; r++){
                #pragma unroll
                for (int g = 0; g < 2; g++){
                    float ss = 0.f;
                    #pragma unroll
                    for (int j = 0; j < 4; j++){
                        float v2 = acc[mb][g*4+j][r];
                        ss += v2*v2;
                    }
                    ss += __shfl_xor(ss, 1, 64);
                    ss += __shfl_xor(ss, 2, 64);
                    ss += __shfl_xor(ss, 4, 64);
                    ss += __shfl_xor(ss, 8, 64);
                    float rs = rsqrtf(ss*(1.f/64.f) + EPSc);
                    acc[mb][g*4+0][r] *= rs*w0;
                    acc[mb][g*4+1][r] *= rs*w1;
                    acc[mb][g*4+2][r] *= rs*w2;
                    acc[mb][g*4+3][r] *= rs*w3;
                }
            }
        }
    }

    int h0 = c0 >> 6;
    #pragma unroll
    for (int mb = 0; mb < 2; mb++){
        #pragma unroll
        for (int r = 0; r < 4; r++){
            int row = wv_*32 + mb*16 + quad*4 + r;
            int s_ = sperm[row];
            if (s_ < 0) continue;
            #pragma unroll
            for (int nb = 0; nb < 8; nb++){
                int col = nb*16 + lc;
                int h = h0 + (col >> 6), hd = col & 63;
                outp[(((size_t)(b*Hc + h))*Sc + s_)*HDc + hd] = f2b(acc[mb][nb][r]);
            }
        }
    }
}

// ---------------------------------------------------------------------------
// 6. V transpose via LDS tiles: vb [BH][S][HD] -> vtb [BH][HD][S]
// ---------------------------------------------------------------------------
__global__ __launch_bounds__(256) void k_vt(const u16* __restrict__ vb,
                                            u16* __restrict__ vtb)
{
    __shared__ u16 sh[64][72];
    int t = threadIdx.x;
    int s0 = blockIdx.x*64, bh = blockIdx.y;
    {
        int rr = t >> 2, cc = (t & 3)*16;
        const u16* src = vb + ((size_t)bh*Sc + s0 + rr)*HDc + cc;
        *(uint4*)&sh[rr][cc]   = *(const uint4*)(src);
        *(uint4*)&sh[rr][cc+8] = *(const uint4*)(src+8);
    }
    __syncthreads();
    {
        int hd = t >> 2, sc = (t & 3)*16;
        u16 tmp[16];
        #pragma unroll
        for (int j = 0; j < 16; j++) tmp[j] = sh[sc+j][hd];
        u16* dst = vtb + ((size_t)bh*HDc + hd)*Sc + s0 + sc;
        *(uint4*)(dst)   = *(const uint4*)&tmp[0];
        *(uint4*)(dst+8) = *(const uint4*)&tmp[8];
    }
}

// ---------------------------------------------------------------------------
// 9. flash PV with ONLINE softmax (stats fused), split-K x2:
//    grid (32, 16, 4): z = b*2 + half.
//    Swapped QK^T (mfma(K,Q)) + pi-permuted K staging: each lane's 16
//    P-values belong to ONE q-row (q = lc); P packs directly into PV
//    A-fragments. K/V tiles XOR-swizzled [64][64] (conflict-free frag
//    reads); mask read per-lane direct from global (L2-resident).
// ---------------------------------------------------------------------------
__global__ __launch_bounds__(256) void k_flash(
    const u16* __restrict__ qb, const u16* __restrict__ kb,
    const u16* __restrict__ vtb, const u16* __restrict__ maskb,
    float* __restrict__ pm, float* __restrict__ pl,
    u16* __restrict__ c0, u16* __restrict__ c1)
{
    int qs0 = blockIdx.x*64, h = blockIdx.y;
    int b = blockIdx.z >> 1, half = blockIdx.z & 1;
    u16* ctxh = half ? c1 : c0;
    int t = threadIdx.x, lane = t & 63, wv_ = t >> 6;
    int quad = lane >> 4, lc = lane & 15;
    __shared__ u16 kt[64*64];
    __shared__ u16 vt[64*64];
    const u16* qp  = qb  + ((size_t)(b*Hc+h))*Sc*HDc;
    const u16* kp  = kb  + ((size_t)(b*Hc+h))*Sc*HDc;
    const u16* vtp = vtb + ((size_t)(b*Hc+h))*HDc*Sc;
    const u16* mq  = maskb + (size_t)(qs0 + wv_*16 + lc)*Sc;  // this lane's q-row
    bf8 aq[2];
    #pragma unroll
    for (int ks = 0; ks < 2; ks++)
        aq[ks] = *(const bf8*)(qp + (size_t)(qs0 + wv_*16 + lc)*HDc + ks*32 + quad*8);
    // online stats for this lane's q row (q = qs0 + wv*16 + lc)
    float rm = -1.0e30f, rl = 0.f;
    f32x4 oacc[4];
    #pragma unroll
    for (int j=0;j<4;j++) oacc[j] = (f32x4){0.f,0.f,0.f,0.f};

    int rr = t >> 2, c8 = (t & 3)*2;
    // pi: global k-row rr -> LDS row (b5<<5)|(b2<<4)|(b4<<3)|(b3<<2)|(b1<<1)|b0
    int pr = (rr & 0x23) | ((rr & 0x04) << 2) | ((rr & 0x18) >> 1);
    int kc0 = half*1024;
    for (int kc = kc0; kc < kc0 + 1024; kc += 64){
        // per-lane mask loads (global, L2-hit) issued before the barrier so
        // their latency hides under staging + sync.
        ushort4 mv[2][2];
        #pragma unroll
        for (int a1 = 0; a1 < 2; a1++)
            #pragma unroll
            for (int b1 = 0; b1 < 2; b1++)
                mv[a1][b1] = *(const ushort4*)(mq + kc + a1*32 + quad*8 + b1*4);
        __syncthreads();
        {
            const u16* s1 = kp + (size_t)(kc+rr)*HDc + c8*8;
            *(uint4*)swz(kt, pr, c8)   = *(const uint4*)(s1);
            *(uint4*)swz(kt, pr, c8+1) = *(const uint4*)(s1+8);
            const u16* s2 = vtp + (size_t)rr*Sc + kc + c8*8;
            *(uint4*)swz(vt, rr, c8)   = *(const uint4*)(s2);
            *(uint4*)swz(vt, rr, c8+1) = *(const uint4*)(s2+8);
        }
        __syncthreads();
        // S^T = K * Q^T : acc[nb] row (quad*4+r) = LDS k-row 16nb+4quad+r,
        // col = lc = q
        f32x4 acc[4];
        #pragma unroll
        for (int j=0;j<4;j++) acc[j] = (f32x4){0.f,0.f,0.f,0.f};
        #pragma unroll
        for (int ks = 0; ks < 2; ks++){
            #pragma unroll
            for (int nb = 0; nb < 4; nb++){
                bf8 ak = *(const bf8*)swzc(kt, nb*16 + lc, ks*4 + quad);
                acc[nb] = MFMA(ak, aq[ks], acc[nb]);
            }
        }
        // scores + mask, tile row-max
        float sv[4][4];
        float mx = -1.0e30f;
        #pragma unroll
        for (int a1 = 0; a1 < 2; a1++){
            #pragma unroll
            for (int b1 = 0; b1 < 2; b1++){
                int nb = 2*a1 + b1;
                #pragma unroll
                for (int r = 0; r < 4; r++){
                    u16 mraw = (r==0?mv[a1][b1].x:r==1?mv[a1][b1].y:
                                r==2?mv[a1][b1].z:mv[a1][b1].w);
                    float s2v = fmaf(acc[nb][r], C2, b2f(mraw));
                    sv[nb][r] = s2v;
                    mx = fmaxf(mx, s2v);
                }
            }
        }
        mx = fmaxf(mx, __shfl_xor(mx, 16, 64));
        mx = fmaxf(mx, __shfl_xor(mx, 32, 64));
        float nm = fmaxf(rm, mx);
        if (__any(nm > rm)){
            float fac = exp2f(rm - nm);
            rm = nm;
            rl *= fac;
            float f0 = __shfl(fac, quad*4+0, 64);
            float f1 = __shfl(fac, quad*4+1, 64);
            float f2 = __shfl(fac, quad*4+2, 64);
            float f3 = __shfl(fac, quad*4+3, 64);
            #pragma unroll
            for (int nb = 0; nb < 4; nb++){
                oacc[nb][0] *= f0; oacc[nb][1] *= f1;
                oacc[nb][2] *= f2; oacc[nb][3] *= f3;
            }
        }
        // P (unnormalized, <=1) packs directly into PV A-fragments
        float ts = 0.f;
        #pragma unroll
        for (int a1 = 0; a1 < 2; a1++){
            bf8 ap;
            #pragma unroll
            for (int b1 = 0; b1 < 2; b1++){
                int nb = 2*a1 + b1;
                #pragma unroll
                for (int r = 0; r < 4; r++){
                    float p = exp2f(sv[nb][r] - rm);
                    ts += p;
                    ap[b1*4 + r] = (short)f2b(p);
                }
            }
            #pragma unroll
            for (int nb2 = 0; nb2 < 4; nb2++){
                bf8 bv = *(const bf8*)swzc(vt, nb2*16 + lc, a1*4 + quad);
                oacc[nb2] = MFMA(ap, bv, oacc[nb2]);
            }
        }
        ts += __shfl_xor(ts, 16, 64);
        ts += __shfl_xor(ts, 32, 64);
        rl += ts;
    }
    // per-half stats out (lanes with quad==0 hold rows 0..15 of this wave)
    if (quad == 0){
        size_t srow = ((size_t)(b*Hc+h))*Sc + qs0 + wv_*16 + lc;
        pm[(size_t)half*65536 + srow] = rm;
        pl[(size_t)half*65536 + srow] = rl;
    }
    // ctx normalized by this half's own l
    float i0 = 1.f/__shfl(rl, quad*4+0, 64);
    float i1 = 1.f/__shfl(rl, quad*4+1, 64);
    float i2 = 1.f/__shfl(rl, quad*4+2, 64);
    float i3 = 1.f/__shfl(rl, quad*4+3, 64);
    #pragma unroll
    for (int r = 0; r < 4; r++){
        float ir = (r==0?i0:r==1?i1:r==2?i2:i3);
        int tok = qs0 + wv_*16 + quad*4 + r;
        #pragma unroll
        for (int nb = 0; nb < 4; nb++){
            int hd = nb*16 + lc;
            ctxh[((size_t)(b*Sc + tok))*Ec + h*HDc + hd] = f2b(oacc[nb][r]*ir);
        }
    }
}

// ---------------------------------------------------------------------------
// 9b. merge the two half stats -> combine weights + attnw constant.
//     cc = M + log2(L) so attnw's per-element work is exp2(s*C2 - cc).
// ---------------------------------------------------------------------------
__global__ __launch_bounds__(256) void k_merge(
    const float* __restrict__ pm, const float* __restrict__ pl,
    float* __restrict__ lstc, float* __restrict__ w0, float* __restrict__ w1)
{
    int r = blockIdx.x*256 + threadIdx.x;
    float m0 = pm[r],        m1 = pm[65536 + r];
    float l0 = pl[r],        l1 = pl[65536 + r];
    float M  = fmaxf(m0, m1);
    float e0 = exp2f(m0 - M)*l0;
    float e1 = exp2f(m1 - M)*l1;
    float L  = e0 + e1;
    float iL = 1.f/L;
    lstc[r] = M + log2f(L);
    w0[r] = e0*iL;
    w1[r] = e1*iL;
}

// ---------------------------------------------------------------------------
// 9c. weighted combine of the two ctx halves: c0 = w0*c0 + w1*c1
// ---------------------------------------------------------------------------
__global__ __launch_bounds__(256) void k_addc(u16* __restrict__ c0,
                                              const u16* __restrict__ c1,
                                              const float* __restrict__ w0,
                                              const float* __restrict__ w1)
{
    int i = (blockIdx.x*256 + threadIdx.x)*8;
    int hh = (i >> 6) & 15, s = (i >> 10) & 2047, bb = i >> 21;
    int wi = ((bb*Hc + hh) << 11) + s;
    float wa = w0[wi], wb = w1[wi];
    ushort4 a0 = *(ushort4*)&c0[i],   a1 = *(ushort4*)&c0[i+4];
    ushort4 b0 = *(const ushort4*)&c1[i], b1 = *(const ushort4*)&c1[i+4];
    ushort4 o0, o1;
    o0.x = f2b(b2f(a0.x)*wa + b2f(b0.x)*wb); o0.y = f2b(b2f(a0.y)*wa + b2f(b0.y)*wb);
    o0.z = f2b(b2f(a0.z)*wa + b2f(b0.z)*wb); o0.w = f2b(b2f(a0.w)*wa + b2f(b0.w)*wb);
    o1.x = f2b(b2f(a1.x)*wa + b2f(b1.x)*wb); o1.y = f2b(b2f(a1.y)*wa + b2f(b1.y)*wb);
    o1.z = f2b(b2f(a1.z)*wa + b2f(b1.z)*wb); o1.w = f2b(b2f(a1.w)*wa + b2f(b1.w)*wb);
    *(ushort4*)&c0[i]   = o0;
    *(ushort4*)&c0[i+4] = o1;
}

// ---------------------------------------------------------------------------
// 8. attn_weights: q-tile 64, k-tile 64, loop all 16 h, NO atomics.
//    grid (32, 32, 2) = (q, k, b). Uses folded cc = M + log2(L).
//    K tile XOR-swizzled [64][64].
// ---------------------------------------------------------------------------
__global__ __launch_bounds__(256) void k_attnw(
    const u16* __restrict__ qb, const u16* __restrict__ kb,
    const u16* __restrict__ maskb, const float* __restrict__ lstc,
    float* __restrict__ awout)
{
    int qs0 = blockIdx.x*64, ks0 = blockIdx.y*64, b = blockIdx.z;
    int t = threadIdx.x, lane = t & 63, wv_ = t >> 6;
    int quad = lane >> 4, lc = lane & 15;
    __shared__ u16 kt[64*64];
    __shared__ float scc[64];
    f32x4 T[4];
    #pragma unroll
    for (int j=0;j<4;j++) T[j] = (f32x4){0.f,0.f,0.f,0.f};

    for (int h = 0; h < Hc; h++){
        __syncthreads();
        const u16* qp = qb + ((size_t)(b*Hc+h))*Sc*HDc;
        const u16* kp = kb + ((size_t)(b*Hc+h))*Sc*HDc;
        bf8 aq[2];
        #pragma unroll
        for (int ks = 0; ks < 2; ks++)
            aq[ks] = *(const bf8*)(qp + (size_t)(qs0 + wv_*16 + lc)*HDc + ks*32 + quad*8);
        {
            int rr = t >> 2, c8 = (t & 3)*2;
            const u16* s2 = kp + (size_t)(ks0+rr)*HDc + c8*8;
            *(uint4*)swz(kt, rr, c8)   = *(const uint4*)(s2);
            *(uint4*)swz(kt, rr, c8+1) = *(const uint4*)(s2+8);
        }
        if (t < 64)
            scc[t] = lstc[((size_t)(b*Hc+h))*Sc + qs0 + t];
        __syncthreads();
        f32x4 acc[4];
        #pragma unroll
        for (int j=0;j<4;j++) acc[j] = (f32x4){0.f,0.f,0.f,0.f};
        #pragma unroll
        for (int ks = 0; ks < 2; ks++){
            #pragma unroll
            for (int nb = 0; nb < 4; nb++){
                bf8 bb = *(const bf8*)swzc(kt, nb*16 + lc, ks*4 + quad);
                acc[nb] = MFMA(aq[ks], bb, acc[nb]);
            }
        }
        #pragma unroll
        for (int r = 0; r < 4; r++){
            int row = wv_*16 + quad*4 + r;
            float cv = scc[row];
            #pragma unroll
            for (int nb = 0; nb < 4; nb++){
                float s = fminf(fmaf(acc[nb][r], C2, -cv), 80.f);
                T[nb][r] += exp2f(s);
            }
        }
    }
    #pragma unroll
    for (int r = 0; r < 4; r++){
        int gq = qs0 + wv_*16 + quad*4 + r;
        #pragma unroll
        for (int nb = 0; nb < 4; nb++){
            int gk = ks0 + nb*16 + lc;
            float mk = b2f(maskb[(size_t)gq*Sc + gk]);   // mask*log2e
            awout[(size_t)b*Sc*Sc + (size_t)gq*Sc + gk]
                = T[nb][r]*exp2f(mk)*(1.f/16.f);
        }
    }
}

// ---------------------------------------------------------------------------
// 10. output projection, MFMA. grid (8, NTILES). XOR-swizzled tiles.
// ---------------------------------------------------------------------------
__global__ __launch_bounds__(256) void k_oproj(
    const u16* __restrict__ ctxb, const u16* __restrict__ woT,
    const int* __restrict__ perm, const int* __restrict__ tmeta,
    float* __restrict__ opre)
{
    int meta = tmeta[blockIdx.y];
    if (meta < 0) return;
    int b = meta >> 1, m = meta & 1;
    const u16* W = woT + (size_t)m*Ec*Dc;
    int c0 = blockIdx.x*128;
    int t = threadIdx.x, lane = t & 63, wv_ = t >> 6;
    int quad = lane >> 4, lc = lane & 15;
    __shared__ u16 at[128*64];
    __shared__ u16 bt[128*64];
    __shared__ int sperm[128];
    if (t < 128) sperm[t] = perm[blockIdx.y*128 + t];
    f32x4 acc[2][8];
    #pragma unroll
    for (int i=0;i<2;i++)
        #pragma unroll
        for (int j=0;j<8;j++) acc[i][j] = (f32x4){0.f,0.f,0.f,0.f};
    __syncthreads();

    int rr = t >> 1, hf = t & 1;
    for (int d0 = 0; d0 < Ec; d0 += 64){
        int s_ = sperm[rr];
        if (s_ >= 0){
            const u16* src = ctxb + ((size_t)(b*Sc + s_))*Ec + d0 + hf*32;
            *(uint4*)swz(at, rr, hf*4+0) = *(const uint4*)(src);
            *(uint4*)swz(at, rr, hf*4+1) = *(const uint4*)(src + 8);
            *(uint4*)swz(at, rr, hf*4+2) = *(const uint4*)(src + 16);
            *(uint4*)swz(at, rr, hf*4+3) = *(const uint4*)(src + 24);
        } else {
            uint4 z = make_uint4(0,0,0,0);
            *(uint4*)swz(at, rr, hf*4+0) = z;
            *(uint4*)swz(at, rr, hf*4+1) = z;
            *(uint4*)swz(at, rr, hf*4+2) = z;
            *(uint4*)swz(at, rr, hf*4+3) = z;
        }
        const u16* wsrc = W + (size_t)(c0 + rr)*Ec + d0 + hf*32;
        *(uint4*)swz(bt, rr, hf*4+0) = *(const uint4*)(wsrc);
        *(uint4*)swz(bt, rr, hf*4+1) = *(const uint4*)(wsrc + 8);
        *(uint4*)swz(bt, rr, hf*4+2) = *(const uint4*)(wsrc + 16);
        *(uint4*)swz(bt, rr, hf*4+3) = *(const uint4*)(wsrc + 24);
        __syncthreads();
        #pragma unroll
        for (int ks = 0; ks < 2; ks++){
            bf8 a0 = *(const bf8*)swzc(at, wv_*32 + lc,      ks*4 + quad);
            bf8 a1 = *(const bf8*)swzc(at, wv_*32 + 16 + lc, ks*4 + quad);
            #pragma unroll
            for (int nb = 0; nb < 8; nb++){
                bf8 bb = *(const bf8*)swzc(bt, nb*16 + lc, ks*4 + quad);
                acc[0][nb] = MFMA(a0, bb, acc[0][nb]);
                acc[1][nb] = MFMA(a1, bb, acc[1][nb]);
            }
        }
        __syncthreads();
    }
    #pragma unroll
    for (int mb = 0; mb < 2; mb++){
        #pragma unroll
        for (int r = 0; r < 4; r++){
            int row = wv_*32 + mb*16 + quad*4 + r;
            int s_ = sperm[row];
            if (s_ < 0) continue;
            #pragma unroll
            for (int nb = 0; nb < 8; nb++){
                int col = c0 + nb*16 + lc;
                opre[((size_t)(b*Sc + s_))*Dc + col] = acc[mb][nb][r];
            }
        }
    }
}

// ---------------------------------------------------------------------------
// 11. final RMSNorm over D -> out
// ---------------------------------------------------------------------------
__global__ __launch_bounds__(256) void k_onorm(
    const float* __restrict__ opre, const float* __restrict__ anw,
    const int* __restrict__ mod, float* __restrict__ out)
{
    int row = blockIdx.x;
    int m = mod[row];
    int t = threadIdx.x;
    float val[4];
    float ss = 0.f;
    #pragma unroll
    for (int j=0;j<4;j++){
        val[j] = opre[(size_t)row*Dc + t + 256*j];
        ss += val[j]*val[j];
    }
    #pragma unroll
    for (int o=32;o>0;o>>=1) ss += __shfl_xor(ss, o, 64);
    __shared__ float red[4];
    int wid = t>>6, lane = t&63;
    if (lane==0) red[wid]=ss;
    __syncthreads();
    float tot = red[0]+red[1]+red[2]+red[3];
    float rms = rsqrtf(tot*(1.f/1024.f) + EPSc);
    #pragma unroll
    for (int j=0;j<4;j++)
        out[(size_t)row*Dc + t + 256*j] = val[j]*rms*anw[m*Dc + t + 256*j];
}

// ---------------------------------------------------------------------------
extern "C" void kernel_launch(void* const* d_in, const int* in_sizes, int n_in,
                              void* d_out, int out_size, void* d_ws, size_t ws_size,
                              hipStream_t stream)
{
    const float* x    = (const float*)d_in[0];
    const float* mask = (const float*)d_in[1];
    const int*   mod  = (const int*)  d_in[2];
    const float* Wq   = (const float*)d_in[3];
    const float* Wk   = (const float*)d_in[4];
    const float* Wv   = (const float*)d_in[5];
    const float* Wo   = (const float*)d_in[6];
    const float* qnw  = (const float*)d_in[7];
    const float* knw  = (const float*)d_in[8];
    const float* anw  = (const float*)d_in[9];

    float* out   = (float*)d_out;                 // [B,S,D]
    float* awout = out + (size_t)Bc*Sc*Dc;        // [B,S,S]

    float* ws = (float*)d_ws;
    u16* qb    = (u16*)(ws + 0);
    u16* kb    = (u16*)(ws + 2097152);
    u16* vb    = (u16*)(ws + 4194304);   // dead after k_vt -> ctx partial 1
    u16* xb    = (u16*)(ws + 6291456);   // dead after k_qkv -> ctx partial 0
    u16* ctx0  = xb;
    u16* ctx1  = vb;
    u16* vtb   = (u16*)(ws + 8388608);
    u16* wqT   = (u16*)(ws + 10485760);
    u16* wkT   = (u16*)(ws + 11534336);
    u16* wvT   = (u16*)(ws + 12582912);
    u16* woT   = (u16*)(ws + 13631488);
    float* lstc= ws + 14680064;          // M + log2(L), 65536
    float* pm  = ws + 14811136;          // per-half m, 2*65536
    float* pl  = pm + 131072;            // per-half l, 2*65536
    float* w0  = ws + 15073280;          // combine weights, 65536 each
    float* w1  = w0 + 65536;
    u16* maskb = (u16*)(ws + 15335424);  // mask*log2e, bf16
    int* perm  = (int*)(ws + 17432576);
    int* tmeta = perm + NTILES*TILE_R;
    float* opre = ws;                    // aliases qb+kb (dead by then)

    k_perm  <<<dim3(1),            256, 0, stream>>>(mod, perm, tmeta);
    k_f2b   <<<dim3(4096),         256, 0, stream>>>(x, xb, Bc*Sc*Dc);
    k_f2bs  <<<dim3(4096),         256, 0, stream>>>(mask, maskb, Sc*Sc, LOG2E);
    k_tcvt  <<<dim3(32,32,8),      256, 0, stream>>>(Wq, Wk, Wv, Wo, wqT, wkT, wvT, woT);
    k_qkv   <<<dim3(8,NTILES,3),   256, 0, stream>>>(xb, wqT, wkT, wvT, perm, tmeta,
                                                     qnw, knw, qb, kb, vb);
    k_vt    <<<dim3(32,32),        256, 0, stream>>>(vb, vtb);
    k_flash <<<dim3(32,16,4),      256, 0, stream>>>(qb, kb, vtb, maskb, pm, pl, ctx0, ctx1);
    k_merge <<<dim3(256),          256, 0, stream>>>(pm, pl, lstc, w0, w1);
    k_attnw <<<dim3(32,32,2),      256, 0, stream>>>(qb, kb, maskb, lstc, awout);
    k_addc  <<<dim3(2048),         256, 0, stream>>>(ctx0, ctx1, w0, w1);
    k_oproj <<<dim3(8,NTILES),     256, 0, stream>>>(ctx0, woT, perm, tmeta, opre);
    k_onorm <<<dim3(4096),         256, 0, stream>>>(opre, anw, mod, out);
}

// Round 5
// 392.778 us; speedup vs baseline: 1.2768x; 1.0259x over previous
//
#include <hip/hip_runtime.h>
#include <cstdint>

#define Bc  2
#define Sc  2048
#define Dc  1024
#define Ec  1024
#define Hc  16
#define HDc 64
#define TTc (Bc*Sc)
#define TILE_R 128
#define NTILES 36
#define EPSc 1e-5f
#define LOG2E 1.44269504f
#define C2    (0.125f*LOG2E)

typedef unsigned short u16;
using bf8   = __attribute__((ext_vector_type(8))) short;
using f32x4 = __attribute__((ext_vector_type(4))) float;
#define MFMA(a,b,c) __builtin_amdgcn_mfma_f32_16x16x32_bf16(a,b,c,0,0,0)

static __device__ __forceinline__ u16 f2b(float f){
    return (u16)((__float_as_uint(f) + 0x8000u) >> 16);
}
static __device__ __forceinline__ float b2f(u16 s){
    return __uint_as_float(((unsigned)s) << 16);
}
// pack two f32 -> one dword of 2 bf16 (low = a, high = b), single VALU op
static __device__ __forceinline__ unsigned cvtpk(float a, float b){
    unsigned r;
    asm("v_cvt_pk_bf16_f32 %0, %1, %2" : "=v"(r) : "v"(a), "v"(b));
    return r;
}
union bfpack { unsigned u[4]; bf8 v; };
// XOR-swizzled LDS addressing: tiles are [R][64] u16, 8-u16 (16B) groups,
// group index col8 swizzled by row&7 -> fragment ds_read_b128 is
// bank-conflict-free.
static __device__ __forceinline__ u16* swz(u16* base, int row, int col8){
    return base + row*64 + ((col8 ^ (row & 7)) << 3);
}
static __device__ __forceinline__ const u16* swzc(const u16* base, int row, int col8){
    return base + row*64 + ((col8 ^ (row & 7)) << 3);
}

// ---------------------------------------------------------------------------
// 1. modality-sorted token permutation, 128-padded segments per (b,m)
// ---------------------------------------------------------------------------
__global__ void k_perm(const int* __restrict__ mod, int* __restrict__ perm,
                       int* __restrict__ tmeta)
{
    __shared__ int cnt[4], segstart[4];
    int t = threadIdx.x;
    if (t < 4) cnt[t] = 0;
    __syncthreads();
    for (int i = t; i < TTc; i += 256){
        int b = i >> 11; int m = mod[i];
        atomicAdd(&cnt[b*2+m], 1);
    }
    __syncthreads();
    if (t == 0){
        int off = 0;
        for (int i = 0; i < 4; i++){
            segstart[i] = off;
            int pad = ((cnt[i] + TILE_R - 1)/TILE_R)*TILE_R;
            for (int tt = off/TILE_R; tt < (off+pad)/TILE_R; tt++) tmeta[tt] = i;
            off += pad;
        }
        for (int tt = off/TILE_R; tt < NTILES; tt++) tmeta[tt] = -1;
    }
    __syncthreads();
    if (t < 4) cnt[t] = 0;
    for (int i = t; i < NTILES*TILE_R; i += 256) perm[i] = -1;
    __syncthreads();
    for (int i = t; i < TTc; i += 256){
        int b = i >> 11, s = i & 2047; int m = mod[i];
        int r = atomicAdd(&cnt[b*2+m], 1);
        perm[segstart[b*2+m] + r] = s;
    }
}

// ---------------------------------------------------------------------------
// 2. fp32 -> bf16 elementwise (optionally scaled)
// ---------------------------------------------------------------------------
__global__ __launch_bounds__(256) void k_f2b(const float* __restrict__ src,
                                             u16* __restrict__ dst, int n)
{
    int i = (blockIdx.x*256 + threadIdx.x)*4;
    if (i >= n) return;
    float4 v = *(const float4*)&src[i];
    ushort4 o;
    o.x = f2b(v.x); o.y = f2b(v.y); o.z = f2b(v.z); o.w = f2b(v.w);
    *(ushort4*)&dst[i] = o;
}

__global__ __launch_bounds__(256) void k_f2bs(const float* __restrict__ src,
                                              u16* __restrict__ dst, int n, float sc)
{
    int i = (blockIdx.x*256 + threadIdx.x)*4;
    if (i >= n) return;
    float4 v = *(const float4*)&src[i];
    ushort4 o;
    o.x = f2b(v.x*sc); o.y = f2b(v.y*sc); o.z = f2b(v.z*sc); o.w = f2b(v.w*sc);
    *(ushort4*)&dst[i] = o;
}

// ---------------------------------------------------------------------------
// 3. transpose+convert all four weights in one launch; grid (32,32,8)
// ---------------------------------------------------------------------------
__global__ __launch_bounds__(256) void k_tcvt(
    const float* __restrict__ s0, const float* __restrict__ s1,
    const float* __restrict__ s2, const float* __restrict__ s3,
    u16* __restrict__ d0, u16* __restrict__ d1,
    u16* __restrict__ d2, u16* __restrict__ d3)
{
    int wsel = blockIdx.z >> 1, m = blockIdx.z & 1;
    const float* src = (wsel==0?s0:wsel==1?s1:wsel==2?s2:s3) + (size_t)m*1048576;
    u16*       dst = (wsel==0?d0:wsel==1?d1:wsel==2?d2:d3) + (size_t)m*1048576;
    __shared__ float sh[32][33];
    int t = threadIdx.x;
    int i0 = blockIdx.x*32, j0 = blockIdx.y*32;
    {
        int i = t >> 3, j4 = (t & 7)*4;
        *(float4*)&sh[i][j4] = *(const float4*)&src[(size_t)(i0+i)*1024 + j0 + j4];
    }
    __syncthreads();
    {
        int j = t >> 3, i4 = (t & 7)*4;
        ushort4 o;
        o.x = f2b(sh[i4+0][j]); o.y = f2b(sh[i4+1][j]);
        o.z = f2b(sh[i4+2][j]); o.w = f2b(sh[i4+3][j]);
        *(ushort4*)&dst[(size_t)(j0+j)*1024 + i0 + i4] = o;
    }
}

// ---------------------------------------------------------------------------
// 4. QKV projection, MFMA, with fused per-head RMSNorm for Q and K.
//    grid (8, NTILES, 3). LDS tiles XOR-swizzled [128][64].
//    Q additionally folded with C2 = 0.125*log2e (saves score-scale in
//    k_flash and k_attnw).
// ---------------------------------------------------------------------------
__global__ __launch_bounds__(256) void k_qkv(
    const u16* __restrict__ xb, const u16* __restrict__ wqT,
    const u16* __restrict__ wkT, const u16* __restrict__ wvT,
    const int* __restrict__ perm, const int* __restrict__ tmeta,
    const float* __restrict__ qnw, const float* __restrict__ knw,
    u16* __restrict__ qb, u16* __restrict__ kb, u16* __restrict__ vb)
{
    int meta = tmeta[blockIdx.y];
    if (meta < 0) return;
    int b = meta >> 1, m = meta & 1;
    const u16* W = (blockIdx.z==0 ? wqT : (blockIdx.z==1 ? wkT : wvT)) + (size_t)m*Ec*Dc;
    u16* outp    = (blockIdx.z==0 ? qb  : (blockIdx.z==1 ? kb  : vb));
    int c0 = blockIdx.x*128;
    int t = threadIdx.x, lane = t & 63, wv_ = t >> 6;
    int quad = lane >> 4, lc = lane & 15;

    __shared__ u16 at[128*64];
    __shared__ u16 bt[128*64];
    __shared__ int sperm[128];
    if (t < 128) sperm[t] = perm[blockIdx.y*128 + t];
    f32x4 acc[2][8];
    #pragma unroll
    for (int i=0;i<2;i++)
        #pragma unroll
        for (int j=0;j<8;j++) acc[i][j] = (f32x4){0.f,0.f,0.f,0.f};
    __syncthreads();

    int rr = t >> 1, hf = t & 1;
    for (int d0 = 0; d0 < Dc; d0 += 64){
        int s_ = sperm[rr];
        if (s_ >= 0){
            const u16* src = xb + ((size_t)(b*Sc + s_))*Dc + d0 + hf*32;
            *(uint4*)swz(at, rr, hf*4+0) = *(const uint4*)(src);
            *(uint4*)swz(at, rr, hf*4+1) = *(const uint4*)(src + 8);
            *(uint4*)swz(at, rr, hf*4+2) = *(const uint4*)(src + 16);
            *(uint4*)swz(at, rr, hf*4+3) = *(const uint4*)(src + 24);
        } else {
            uint4 z = make_uint4(0,0,0,0);
            *(uint4*)swz(at, rr, hf*4+0) = z;
            *(uint4*)swz(at, rr, hf*4+1) = z;
            *(uint4*)swz(at, rr, hf*4+2) = z;
            *(uint4*)swz(at, rr, hf*4+3) = z;
        }
        const u16* wsrc = W + (size_t)(c0 + rr)*Dc + d0 + hf*32;
        *(uint4*)swz(bt, rr, hf*4+0) = *(const uint4*)(wsrc);
        *(uint4*)swz(bt, rr, hf*4+1) = *(const uint4*)(wsrc + 8);
        *(uint4*)swz(bt, rr, hf*4+2) = *(const uint4*)(wsrc + 16);
        *(uint4*)swz(bt, rr, hf*4+3) = *(const uint4*)(wsrc + 24);
        __syncthreads();
        #pragma unroll
        for (int ks = 0; ks < 2; ks++){
            bf8 a0 = *(const bf8*)swzc(at, wv_*32 + lc,      ks*4 + quad);
            bf8 a1 = *(const bf8*)swzc(at, wv_*32 + 16 + lc, ks*4 + quad);
            #pragma unroll
            for (int nb = 0; nb < 8; nb++){
                bf8 bb = *(const bf8*)swzc(bt, nb*16 + lc, ks*4 + quad);
                acc[0][nb] = MFMA(a0, bb, acc[0][nb]);
                acc[1][nb] = MFMA(a1, bb, acc[1][nb]);
            }
        }
        __syncthreads();
    }

    if (blockIdx.z < 2){
        const float* nw = (blockIdx.z==0 ? qnw : knw) + m*HDc;
        float cs = (blockIdx.z==0) ? C2 : 1.f;   // fold score scale into Q
        float w0 = nw[lc]*cs, w1 = nw[16+lc]*cs, w2 = nw[32+lc]*cs, w3 = nw[48+lc]*cs;
        #pragma unroll
        for (int mb = 0; mb < 2; mb++){
            #pragma unroll
            for (int r = 0; r < 4; r++){
                #pragma unroll
                for (int g = 0; g < 2; g++){
                    float ss = 0.f;
                    #pragma unroll
                    for (int j = 0; j < 4; j++){
                        float v2 = acc[mb][g*4+j][r];
                        ss += v2*v2;
                    }
                    ss += __shfl_xor(ss, 1, 64);
                    ss += __shfl_xor(ss, 2, 64);
                    ss += __shfl_xor(ss, 4, 64);
                    ss += __shfl_xor(ss, 8, 64);
                    float rs = rsqrtf(ss*(1.f/64.f) + EPSc);
                    acc[mb][g*4+0][r] *= rs*w0;
                    acc[mb][g*4+1][r] *= rs*w1;
                    acc[mb][g*4+2][r] *= rs*w2;
                    acc[mb][g*4+3][r] *= rs*w3;
                }
            }
        }
    }

    int h0 = c0 >> 6;
    #pragma unroll
    for (int mb = 0; mb < 2; mb++){
        #pragma unroll
        for (int r = 0; r < 4; r++){
            int row = wv_*32 + mb*16 + quad*4 + r;
            int s_ = sperm[row];
            if (s_ < 0) continue;
            #pragma unroll
            for (int nb = 0; nb < 8; nb++){
                int col = nb*16 + lc;
                int h = h0 + (col >> 6), hd = col & 63;
                outp[(((size_t)(b*Hc + h))*Sc + s_)*HDc + hd] = f2b(acc[mb][nb][r]);
            }
        }
    }
}

// ---------------------------------------------------------------------------
// 6. V transpose via LDS tiles: vb [BH][S][HD] -> vtb [BH][HD][S]
// ---------------------------------------------------------------------------
__global__ __launch_bounds__(256) void k_vt(const u16* __restrict__ vb,
                                            u16* __restrict__ vtb)
{
    __shared__ u16 sh[64][72];
    int t = threadIdx.x;
    int s0 = blockIdx.x*64, bh = blockIdx.y;
    {
        int rr = t >> 2, cc = (t & 3)*16;
        const u16* src = vb + ((size_t)bh*Sc + s0 + rr)*HDc + cc;
        *(uint4*)&sh[rr][cc]   = *(const uint4*)(src);
        *(uint4*)&sh[rr][cc+8] = *(const uint4*)(src+8);
    }
    __syncthreads();
    {
        int hd = t >> 2, sc = (t & 3)*16;
        u16 tmp[16];
        #pragma unroll
        for (int j = 0; j < 16; j++) tmp[j] = sh[sc+j][hd];
        u16* dst = vtb + ((size_t)bh*HDc + hd)*Sc + s0 + sc;
        *(uint4*)(dst)   = *(const uint4*)&tmp[0];
        *(uint4*)(dst+8) = *(const uint4*)&tmp[8];
    }
}

// ---------------------------------------------------------------------------
// 9. flash PV with ONLINE softmax + defer-max (THR=8), split-K x2:
//    grid (32, 16, 4): z = b*2 + half.
//    Swapped QK^T + pi-permuted K staging keeps P in registers in exact PV
//    A-fragment layout. Defer-max + per-lane partial l => ZERO cross-lane
//    ops per tile in the common path (reduce once at end). P packed via
//    v_cvt_pk_bf16_f32 (2 elems/op).
// ---------------------------------------------------------------------------
__global__ __launch_bounds__(256) void k_flash(
    const u16* __restrict__ qb, const u16* __restrict__ kb,
    const u16* __restrict__ vtb, const u16* __restrict__ maskb,
    float* __restrict__ pm, float* __restrict__ pl,
    u16* __restrict__ c0, u16* __restrict__ c1)
{
    int qs0 = blockIdx.x*64, h = blockIdx.y;
    int b = blockIdx.z >> 1, half = blockIdx.z & 1;
    u16* ctxh = half ? c1 : c0;
    int t = threadIdx.x, lane = t & 63, wv_ = t >> 6;
    int quad = lane >> 4, lc = lane & 15;
    __shared__ u16 kt[64*64];
    __shared__ u16 vt[64*64];
    const u16* qp  = qb  + ((size_t)(b*Hc+h))*Sc*HDc;
    const u16* kp  = kb  + ((size_t)(b*Hc+h))*Sc*HDc;
    const u16* vtp = vtb + ((size_t)(b*Hc+h))*HDc*Sc;
    const u16* mq  = maskb + (size_t)(qs0 + wv_*16 + lc)*Sc;  // this lane's q-row
    bf8 aq[2];
    #pragma unroll
    for (int ks = 0; ks < 2; ks++)
        aq[ks] = *(const bf8*)(qp + (size_t)(qs0 + wv_*16 + lc)*HDc + ks*32 + quad*8);
    // online stats for this lane's q row (rm row-uniform; rl per-lane partial)
    float rm = -1.0e30f, rl = 0.f;
    f32x4 oacc[4];
    #pragma unroll
    for (int j=0;j<4;j++) oacc[j] = (f32x4){0.f,0.f,0.f,0.f};

    int rr = t >> 2, c8 = (t & 3)*2;
    // pi: global k-row rr -> LDS row (b5<<5)|(b2<<4)|(b4<<3)|(b3<<2)|(b1<<1)|b0
    int pr = (rr & 0x23) | ((rr & 0x04) << 2) | ((rr & 0x18) >> 1);
    int kc0 = half*1024;
    for (int kc = kc0; kc < kc0 + 1024; kc += 64){
        // per-lane mask loads (global, L2-hit) issued before the barrier
        ushort4 mv[2][2];
        #pragma unroll
        for (int a1 = 0; a1 < 2; a1++)
            #pragma unroll
            for (int b1 = 0; b1 < 2; b1++)
                mv[a1][b1] = *(const ushort4*)(mq + kc + a1*32 + quad*8 + b1*4);
        __syncthreads();
        {
            const u16* s1 = kp + (size_t)(kc+rr)*HDc + c8*8;
            *(uint4*)swz(kt, pr, c8)   = *(const uint4*)(s1);
            *(uint4*)swz(kt, pr, c8+1) = *(const uint4*)(s1+8);
            const u16* s2 = vtp + (size_t)rr*Sc + kc + c8*8;
            *(uint4*)swz(vt, rr, c8)   = *(const uint4*)(s2);
            *(uint4*)swz(vt, rr, c8+1) = *(const uint4*)(s2+8);
        }
        __syncthreads();
        // S^T = K * Q^T (Q pre-scaled by C2)
        f32x4 acc[4];
        #pragma unroll
        for (int j=0;j<4;j++) acc[j] = (f32x4){0.f,0.f,0.f,0.f};
        #pragma unroll
        for (int ks = 0; ks < 2; ks++){
            #pragma unroll
            for (int nb = 0; nb < 4; nb++){
                bf8 ak = *(const bf8*)swzc(kt, nb*16 + lc, ks*4 + quad);
                acc[nb] = MFMA(ak, aq[ks], acc[nb]);
            }
        }
        // scores + mask, per-lane partial max
        float sv[4][4];
        float mxl = -3.0e38f;
        #pragma unroll
        for (int a1 = 0; a1 < 2; a1++){
            #pragma unroll
            for (int b1 = 0; b1 < 2; b1++){
                int nb = 2*a1 + b1;
                #pragma unroll
                for (int r = 0; r < 4; r++){
                    u16 mraw = (r==0?mv[a1][b1].x:r==1?mv[a1][b1].y:
                                r==2?mv[a1][b1].z:mv[a1][b1].w);
                    float s2v = acc[nb][r] + b2f(mraw);
                    sv[nb][r] = s2v;
                    mxl = fmaxf(mxl, s2v);
                }
            }
        }
        // defer-max: only reduce/rescale when some lane grew past rm + 8
        if (__any(mxl > rm + 8.f)){
            float mx = fmaxf(mxl, __shfl_xor(mxl, 16, 64));
            mx = fmaxf(mx, __shfl_xor(mx, 32, 64));
            float nm = fmaxf(rm, mx);
            float fac = exp2f(rm - nm);
            rm = nm;
            rl *= fac;
            float f0 = __shfl(fac, quad*4+0, 64);
            float f1 = __shfl(fac, quad*4+1, 64);
            float f2 = __shfl(fac, quad*4+2, 64);
            float f3 = __shfl(fac, quad*4+3, 64);
            #pragma unroll
            for (int nb = 0; nb < 4; nb++){
                oacc[nb][0] *= f0; oacc[nb][1] *= f1;
                oacc[nb][2] *= f2; oacc[nb][3] *= f3;
            }
        }
        // P (bounded by 2^8) packed via cvt_pk straight into PV A-fragments
        #pragma unroll
        for (int a1 = 0; a1 < 2; a1++){
            bfpack pk;
            {
                float p0 = exp2f(sv[2*a1][0] - rm);
                float p1 = exp2f(sv[2*a1][1] - rm);
                float p2 = exp2f(sv[2*a1][2] - rm);
                float p3 = exp2f(sv[2*a1][3] - rm);
                rl += (p0 + p1) + (p2 + p3);
                pk.u[0] = cvtpk(p0, p1); pk.u[1] = cvtpk(p2, p3);
            }
            {
                float p0 = exp2f(sv[2*a1+1][0] - rm);
                float p1 = exp2f(sv[2*a1+1][1] - rm);
                float p2 = exp2f(sv[2*a1+1][2] - rm);
                float p3 = exp2f(sv[2*a1+1][3] - rm);
                rl += (p0 + p1) + (p2 + p3);
                pk.u[2] = cvtpk(p0, p1); pk.u[3] = cvtpk(p2, p3);
            }
            bf8 ap = pk.v;
            #pragma unroll
            for (int nb2 = 0; nb2 < 4; nb2++){
                bf8 bv = *(const bf8*)swzc(vt, nb2*16 + lc, a1*4 + quad);
                oacc[nb2] = MFMA(ap, bv, oacc[nb2]);
            }
        }
    }
    // reduce per-lane partial l across the 4 lanes of each q-row (once)
    rl += __shfl_xor(rl, 16, 64);
    rl += __shfl_xor(rl, 32, 64);
    // per-half stats out (lanes with quad==0 hold rows 0..15 of this wave)
    if (quad == 0){
        size_t srow = ((size_t)(b*Hc+h))*Sc + qs0 + wv_*16 + lc;
        pm[(size_t)half*65536 + srow] = rm;
        pl[(size_t)half*65536 + srow] = rl;
    }
    // ctx normalized by this half's own l
    float i0 = 1.f/__shfl(rl, quad*4+0, 64);
    float i1 = 1.f/__shfl(rl, quad*4+1, 64);
    float i2 = 1.f/__shfl(rl, quad*4+2, 64);
    float i3 = 1.f/__shfl(rl, quad*4+3, 64);
    #pragma unroll
    for (int r = 0; r < 4; r++){
        float ir = (r==0?i0:r==1?i1:r==2?i2:i3);
        int tok = qs0 + wv_*16 + quad*4 + r;
        #pragma unroll
        for (int nb = 0; nb < 4; nb++){
            int hd = nb*16 + lc;
            ctxh[((size_t)(b*Sc + tok))*Ec + h*HDc + hd] = f2b(oacc[nb][r]*ir);
        }
    }
}

// ---------------------------------------------------------------------------
// 9b. merge the two half stats -> combine weights + attnw constant.
//     cc = M + log2(L) so attnw's per-element work is exp2(s - cc).
// ---------------------------------------------------------------------------
__global__ __launch_bounds__(256) void k_merge(
    const float* __restrict__ pm, const float* __restrict__ pl,
    float* __restrict__ lstc, float* __restrict__ w0, float* __restrict__ w1)
{
    int r = blockIdx.x*256 + threadIdx.x;
    float m0 = pm[r],        m1 = pm[65536 + r];
    float l0 = pl[r],        l1 = pl[65536 + r];
    float M  = fmaxf(m0, m1);
    float e0 = exp2f(m0 - M)*l0;
    float e1 = exp2f(m1 - M)*l1;
    float L  = e0 + e1;
    float iL = 1.f/L;
    lstc[r] = M + log2f(L);
    w0[r] = e0*iL;
    w1[r] = e1*iL;
}

// ---------------------------------------------------------------------------
// 9c. weighted combine of the two ctx halves: c0 = w0*c0 + w1*c1
// ---------------------------------------------------------------------------
__global__ __launch_bounds__(256) void k_addc(u16* __restrict__ c0,
                                              const u16* __restrict__ c1,
                                              const float* __restrict__ w0,
                                              const float* __restrict__ w1)
{
    int i = (blockIdx.x*256 + threadIdx.x)*8;
    int hh = (i >> 6) & 15, s = (i >> 10) & 2047, bb = i >> 21;
    int wi = ((bb*Hc + hh) << 11) + s;
    float wa = w0[wi], wb = w1[wi];
    ushort4 a0 = *(ushort4*)&c0[i],   a1 = *(ushort4*)&c0[i+4];
    ushort4 b0 = *(const ushort4*)&c1[i], b1 = *(const ushort4*)&c1[i+4];
    ushort4 o0, o1;
    o0.x = f2b(b2f(a0.x)*wa + b2f(b0.x)*wb); o0.y = f2b(b2f(a0.y)*wa + b2f(b0.y)*wb);
    o0.z = f2b(b2f(a0.z)*wa + b2f(b0.z)*wb); o0.w = f2b(b2f(a0.w)*wa + b2f(b0.w)*wb);
    o1.x = f2b(b2f(a1.x)*wa + b2f(b1.x)*wb); o1.y = f2b(b2f(a1.y)*wa + b2f(b1.y)*wb);
    o1.z = f2b(b2f(a1.z)*wa + b2f(b1.z)*wb); o1.w = f2b(b2f(a1.w)*wa + b2f(b1.w)*wb);
    *(ushort4*)&c0[i]   = o0;
    *(ushort4*)&c0[i+4] = o1;
}

// ---------------------------------------------------------------------------
// 8. attn_weights: q-tile 64, k-tile 64, loop all 16 h, NO atomics.
//    grid (32, 32, 2) = (q, k, b). Uses folded cc = M + log2(L); Q is
//    pre-scaled by C2; s - cc <= 0 so no clamp needed.
// ---------------------------------------------------------------------------
__global__ __launch_bounds__(256) void k_attnw(
    const u16* __restrict__ qb, const u16* __restrict__ kb,
    const u16* __restrict__ maskb, const float* __restrict__ lstc,
    float* __restrict__ awout)
{
    int qs0 = blockIdx.x*64, ks0 = blockIdx.y*64, b = blockIdx.z;
    int t = threadIdx.x, lane = t & 63, wv_ = t >> 6;
    int quad = lane >> 4, lc = lane & 15;
    __shared__ u16 kt[64*64];
    __shared__ float scc[64];
    f32x4 T[4];
    #pragma unroll
    for (int j=0;j<4;j++) T[j] = (f32x4){0.f,0.f,0.f,0.f};

    for (int h = 0; h < Hc; h++){
        __syncthreads();
        const u16* qp = qb + ((size_t)(b*Hc+h))*Sc*HDc;
        const u16* kp = kb + ((size_t)(b*Hc+h))*Sc*HDc;
        bf8 aq[2];
        #pragma unroll
        for (int ks = 0; ks < 2; ks++)
            aq[ks] = *(const bf8*)(qp + (size_t)(qs0 + wv_*16 + lc)*HDc + ks*32 + quad*8);
        {
            int rr = t >> 2, c8 = (t & 3)*2;
            const u16* s2 = kp + (size_t)(ks0+rr)*HDc + c8*8;
            *(uint4*)swz(kt, rr, c8)   = *(const uint4*)(s2);
            *(uint4*)swz(kt, rr, c8+1) = *(const uint4*)(s2+8);
        }
        if (t < 64)
            scc[t] = lstc[((size_t)(b*Hc+h))*Sc + qs0 + t];
        __syncthreads();
        f32x4 acc[4];
        #pragma unroll
        for (int j=0;j<4;j++) acc[j] = (f32x4){0.f,0.f,0.f,0.f};
        #pragma unroll
        for (int ks = 0; ks < 2; ks++){
            #pragma unroll
            for (int nb = 0; nb < 4; nb++){
                bf8 bb = *(const bf8*)swzc(kt, nb*16 + lc, ks*4 + quad);
                acc[nb] = MFMA(aq[ks], bb, acc[nb]);
            }
        }
        #pragma unroll
        for (int r = 0; r < 4; r++){
            int row = wv_*16 + quad*4 + r;
            float cv = scc[row];
            #pragma unroll
            for (int nb = 0; nb < 4; nb++)
                T[nb][r] += exp2f(acc[nb][r] - cv);
        }
    }
    #pragma unroll
    for (int r = 0; r < 4; r++){
        int gq = qs0 + wv_*16 + quad*4 + r;
        #pragma unroll
        for (int nb = 0; nb < 4; nb++){
            int gk = ks0 + nb*16 + lc;
            float mk = b2f(maskb[(size_t)gq*Sc + gk]);   // mask*log2e
            awout[(size_t)b*Sc*Sc + (size_t)gq*Sc + gk]
                = T[nb][r]*exp2f(mk)*(1.f/16.f);
        }
    }
}

// ---------------------------------------------------------------------------
// 10. output projection, MFMA. grid (8, NTILES). XOR-swizzled tiles.
// ---------------------------------------------------------------------------
__global__ __launch_bounds__(256) void k_oproj(
    const u16* __restrict__ ctxb, const u16* __restrict__ woT,
    const int* __restrict__ perm, const int* __restrict__ tmeta,
    float* __restrict__ opre)
{
    int meta = tmeta[blockIdx.y];
    if (meta < 0) return;
    int b = meta >> 1, m = meta & 1;
    const u16* W = woT + (size_t)m*Ec*Dc;
    int c0 = blockIdx.x*128;
    int t = threadIdx.x, lane = t & 63, wv_ = t >> 6;
    int quad = lane >> 4, lc = lane & 15;
    __shared__ u16 at[128*64];
    __shared__ u16 bt[128*64];
    __shared__ int sperm[128];
    if (t < 128) sperm[t] = perm[blockIdx.y*128 + t];
    f32x4 acc[2][8];
    #pragma unroll
    for (int i=0;i<2;i++)
        #pragma unroll
        for (int j=0;j<8;j++) acc[i][j] = (f32x4){0.f,0.f,0.f,0.f};
    __syncthreads();

    int rr = t >> 1, hf = t & 1;
    for (int d0 = 0; d0 < Ec; d0 += 64){
        int s_ = sperm[rr];
        if (s_ >= 0){
            const u16* src = ctxb + ((size_t)(b*Sc + s_))*Ec + d0 + hf*32;
            *(uint4*)swz(at, rr, hf*4+0) = *(const uint4*)(src);
            *(uint4*)swz(at, rr, hf*4+1) = *(const uint4*)(src + 8);
            *(uint4*)swz(at, rr, hf*4+2) = *(const uint4*)(src + 16);
            *(uint4*)swz(at, rr, hf*4+3) = *(const uint4*)(src + 24);
        } else {
            uint4 z = make_uint4(0,0,0,0);
            *(uint4*)swz(at, rr, hf*4+0) = z;
            *(uint4*)swz(at, rr, hf*4+1) = z;
            *(uint4*)swz(at, rr, hf*4+2) = z;
            *(uint4*)swz(at, rr, hf*4+3) = z;
        }
        const u16* wsrc = W + (size_t)(c0 + rr)*Ec + d0 + hf*32;
        *(uint4*)swz(bt, rr, hf*4+0) = *(const uint4*)(wsrc);
        *(uint4*)swz(bt, rr, hf*4+1) = *(const uint4*)(wsrc + 8);
        *(uint4*)swz(bt, rr, hf*4+2) = *(const uint4*)(wsrc + 16);
        *(uint4*)swz(bt, rr, hf*4+3) = *(const uint4*)(wsrc + 24);
        __syncthreads();
        #pragma unroll
        for (int ks = 0; ks < 2; ks++){
            bf8 a0 = *(const bf8*)swzc(at, wv_*32 + lc,      ks*4 + quad);
            bf8 a1 = *(const bf8*)swzc(at, wv_*32 + 16 + lc, ks*4 + quad);
            #pragma unroll
            for (int nb = 0; nb < 8; nb++){
                bf8 bb = *(const bf8*)swzc(bt, nb*16 + lc, ks*4 + quad);
                acc[0][nb] = MFMA(a0, bb, acc[0][nb]);
                acc[1][nb] = MFMA(a1, bb, acc[1][nb]);
            }
        }
        __syncthreads();
    }
    #pragma unroll
    for (int mb = 0; mb < 2; mb++){
        #pragma unroll
        for (int r = 0; r < 4; r++){
            int row = wv_*32 + mb*16 + quad*4 + r;
            int s_ = sperm[row];
            if (s_ < 0) continue;
            #pragma unroll
            for (int nb = 0; nb < 8; nb++){
                int col = c0 + nb*16 + lc;
                opre[((size_t)(b*Sc + s_))*Dc + col] = acc[mb][nb][r];
            }
        }
    }
}

// ---------------------------------------------------------------------------
// 11. final RMSNorm over D -> out
// ---------------------------------------------------------------------------
__global__ __launch_bounds__(256) void k_onorm(
    const float* __restrict__ opre, const float* __restrict__ anw,
    const int* __restrict__ mod, float* __restrict__ out)
{
    int row = blockIdx.x;
    int m = mod[row];
    int t = threadIdx.x;
    float val[4];
    float ss = 0.f;
    #pragma unroll
    for (int j=0;j<4;j++){
        val[j] = opre[(size_t)row*Dc + t + 256*j];
        ss += val[j]*val[j];
    }
    #pragma unroll
    for (int o=32;o>0;o>>=1) ss += __shfl_xor(ss, o, 64);
    __shared__ float red[4];
    int wid = t>>6, lane = t&63;
    if (lane==0) red[wid]=ss;
    __syncthreads();
    float tot = red[0]+red[1]+red[2]+red[3];
    float rms = rsqrtf(tot*(1.f/1024.f) + EPSc);
    #pragma unroll
    for (int j=0;j<4;j++)
        out[(size_t)row*Dc + t + 256*j] = val[j]*rms*anw[m*Dc + t + 256*j];
}

// ---------------------------------------------------------------------------
extern "C" void kernel_launch(void* const* d_in, const int* in_sizes, int n_in,
                              void* d_out, int out_size, void* d_ws, size_t ws_size,
                              hipStream_t stream)
{
    const float* x    = (const float*)d_in[0];
    const float* mask = (const float*)d_in[1];
    const int*   mod  = (const int*)  d_in[2];
    const float* Wq   = (const float*)d_in[3];
    const float* Wk   = (const float*)d_in[4];
    const float* Wv   = (const float*)d_in[5];
    const float* Wo   = (const float*)d_in[6];
    const float* qnw  = (const float*)d_in[7];
    const float* knw  = (const float*)d_in[8];
    const float* anw  = (const float*)d_in[9];

    float* out   = (float*)d_out;                 // [B,S,D]
    float* awout = out + (size_t)Bc*Sc*Dc;        // [B,S,S]

    float* ws = (float*)d_ws;
    u16* qb    = (u16*)(ws + 0);
    u16* kb    = (u16*)(ws + 2097152);
    u16* vb    = (u16*)(ws + 4194304);   // dead after k_vt -> ctx partial 1
    u16* xb    = (u16*)(ws + 6291456);   // dead after k_qkv -> ctx partial 0
    u16* ctx0  = xb;
    u16* ctx1  = vb;
    u16* vtb   = (u16*)(ws + 8388608);
    u16* wqT   = (u16*)(ws + 10485760);
    u16* wkT   = (u16*)(ws + 11534336);
    u16* wvT   = (u16*)(ws + 12582912);
    u16* woT   = (u16*)(ws + 13631488);
    float* lstc= ws + 14680064;          // M + log2(L), 65536
    float* pm  = ws + 14811136;          // per-half m, 2*65536
    float* pl  = pm + 131072;            // per-half l, 2*65536
    float* w0  = ws + 15073280;          // combine weights, 65536 each
    float* w1  = w0 + 65536;
    u16* maskb = (u16*)(ws + 15335424);  // mask*log2e, bf16
    int* perm  = (int*)(ws + 17432576);
    int* tmeta = perm + NTILES*TILE_R;
    float* opre = ws;                    // aliases qb+kb (dead by then)

    k_perm  <<<dim3(1),            256, 0, stream>>>(mod, perm, tmeta);
    k_f2b   <<<dim3(4096),         256, 0, stream>>>(x, xb, Bc*Sc*Dc);
    k_f2bs  <<<dim3(4096),         256, 0, stream>>>(mask, maskb, Sc*Sc, LOG2E);
    k_tcvt  <<<dim3(32,32,8),      256, 0, stream>>>(Wq, Wk, Wv, Wo, wqT, wkT, wvT, woT);
    k_qkv   <<<dim3(8,NTILES,3),   256, 0, stream>>>(xb, wqT, wkT, wvT, perm, tmeta,
                                                     qnw, knw, qb, kb, vb);
    k_vt    <<<dim3(32,32),        256, 0, stream>>>(vb, vtb);
    k_flash <<<dim3(32,16,4),      256, 0, stream>>>(qb, kb, vtb, maskb, pm, pl, ctx0, ctx1);
    k_merge <<<dim3(256),          256, 0, stream>>>(pm, pl, lstc, w0, w1);
    k_attnw <<<dim3(32,32,2),      256, 0, stream>>>(qb, kb, maskb, lstc, awout);
    k_addc  <<<dim3(2048),         256, 0, stream>>>(ctx0, ctx1, w0, w1);
    k_oproj <<<dim3(8,NTILES),     256, 0, stream>>>(ctx0, woT, perm, tmeta, opre);
    k_onorm <<<dim3(4096),         256, 0, stream>>>(opre, anw, mod, out);
}

// Round 6
// 371.496 us; speedup vs baseline: 1.3499x; 1.0573x over previous
//
#include <hip/hip_runtime.h>
#include <cstdint>

#define Bc  2
#define Sc  2048
#define Dc  1024
#define Ec  1024
#define Hc  16
#define HDc 64
#define TTc (Bc*Sc)
#define TILE_R 128
#define NTILES 36
#define EPSc 1e-5f
#define LOG2E 1.44269504f
#define C2    (0.125f*LOG2E)

typedef unsigned short u16;
using bf8   = __attribute__((ext_vector_type(8))) short;
using f32x4 = __attribute__((ext_vector_type(4))) float;
#define MFMA(a,b,c) __builtin_amdgcn_mfma_f32_16x16x32_bf16(a,b,c,0,0,0)

static __device__ __forceinline__ u16 f2b(float f){
    return (u16)((__float_as_uint(f) + 0x8000u) >> 16);
}
static __device__ __forceinline__ float b2f(u16 s){
    return __uint_as_float(((unsigned)s) << 16);
}
// raw v_exp_f32 (2^x): inputs here are <= ~8; underflow flushes to 0 which is
// exactly the wanted semantics. Avoids OCML's multi-instruction wrapper.
static __device__ __forceinline__ float ex2(float x){
    return __builtin_amdgcn_exp2f(x);
}
// pack two f32 -> one dword of 2 bf16 (low = a, high = b), single VALU op
static __device__ __forceinline__ unsigned cvtpk(float a, float b){
    unsigned r;
    asm("v_cvt_pk_bf16_f32 %0, %1, %2" : "=v"(r) : "v"(a), "v"(b));
    return r;
}
union bfpack { unsigned u[4]; bf8 v; };
// XOR-swizzled LDS addressing: tiles are [R][64] u16, 8-u16 (16B) groups,
// group index col8 swizzled by row&7 -> fragment ds_read_b128 is
// bank-conflict-free.
static __device__ __forceinline__ u16* swz(u16* base, int row, int col8){
    return base + row*64 + ((col8 ^ (row & 7)) << 3);
}
static __device__ __forceinline__ const u16* swzc(const u16* base, int row, int col8){
    return base + row*64 + ((col8 ^ (row & 7)) << 3);
}
// async global->LDS, 16B per lane. LDS dest = wave-uniform base + lane*16
// (linear); the swizzle is applied by inverse-permuting the per-lane global
// source address (rule: linear dest + inv-swz source + swz read).
typedef const __attribute__((address_space(1))) void* gp1;
typedef __attribute__((address_space(3))) void* lp3;
static __device__ __forceinline__ void gl16(const void* g, void* l){
    __builtin_amdgcn_global_load_lds((gp1)g, (lp3)l, 16, 0, 0);
}

// ---------------------------------------------------------------------------
// 1. modality-sorted token permutation, 128-padded segments per (b,m).
//    Also zeroes the 4KB zbuf used by gload_lds staging for padding rows.
// ---------------------------------------------------------------------------
__global__ void k_perm(const int* __restrict__ mod, int* __restrict__ perm,
                       int* __restrict__ tmeta, u16* __restrict__ zbuf)
{
    __shared__ int cnt[4], segstart[4];
    int t = threadIdx.x;
    for (int i = t; i < 2048; i += 256) zbuf[i] = 0;
    if (t < 4) cnt[t] = 0;
    __syncthreads();
    for (int i = t; i < TTc; i += 256){
        int b = i >> 11; int m = mod[i];
        atomicAdd(&cnt[b*2+m], 1);
    }
    __syncthreads();
    if (t == 0){
        int off = 0;
        for (int i = 0; i < 4; i++){
            segstart[i] = off;
            int pad = ((cnt[i] + TILE_R - 1)/TILE_R)*TILE_R;
            for (int tt = off/TILE_R; tt < (off+pad)/TILE_R; tt++) tmeta[tt] = i;
            off += pad;
        }
        for (int tt = off/TILE_R; tt < NTILES; tt++) tmeta[tt] = -1;
    }
    __syncthreads();
    if (t < 4) cnt[t] = 0;
    for (int i = t; i < NTILES*TILE_R; i += 256) perm[i] = -1;
    __syncthreads();
    for (int i = t; i < TTc; i += 256){
        int b = i >> 11, s = i & 2047; int m = mod[i];
        int r = atomicAdd(&cnt[b*2+m], 1);
        perm[segstart[b*2+m] + r] = s;
    }
}

// ---------------------------------------------------------------------------
// 2. fp32 -> bf16 elementwise
// ---------------------------------------------------------------------------
__global__ __launch_bounds__(256) void k_f2b(const float* __restrict__ src,
                                             u16* __restrict__ dst, int n)
{
    int i = (blockIdx.x*256 + threadIdx.x)*4;
    if (i >= n) return;
    float4 v = *(const float4*)&src[i];
    ushort4 o;
    o.x = f2b(v.x); o.y = f2b(v.y); o.z = f2b(v.z); o.w = f2b(v.w);
    *(ushort4*)&dst[i] = o;
}

// ---------------------------------------------------------------------------
// 3. transpose+convert all four weights in one launch; grid (32,32,8)
// ---------------------------------------------------------------------------
__global__ __launch_bounds__(256) void k_tcvt(
    const float* __restrict__ s0, const float* __restrict__ s1,
    const float* __restrict__ s2, const float* __restrict__ s3,
    u16* __restrict__ d0, u16* __restrict__ d1,
    u16* __restrict__ d2, u16* __restrict__ d3)
{
    int wsel = blockIdx.z >> 1, m = blockIdx.z & 1;
    const float* src = (wsel==0?s0:wsel==1?s1:wsel==2?s2:s3) + (size_t)m*1048576;
    u16*       dst = (wsel==0?d0:wsel==1?d1:wsel==2?d2:d3) + (size_t)m*1048576;
    __shared__ float sh[32][33];
    int t = threadIdx.x;
    int i0 = blockIdx.x*32, j0 = blockIdx.y*32;
    {
        int i = t >> 3, j4 = (t & 7)*4;
        *(float4*)&sh[i][j4] = *(const float4*)&src[(size_t)(i0+i)*1024 + j0 + j4];
    }
    __syncthreads();
    {
        int j = t >> 3, i4 = (t & 7)*4;
        ushort4 o;
        o.x = f2b(sh[i4+0][j]); o.y = f2b(sh[i4+1][j]);
        o.z = f2b(sh[i4+2][j]); o.w = f2b(sh[i4+3][j]);
        *(ushort4*)&dst[(size_t)(j0+j)*1024 + i0 + i4] = o;
    }
}

// ---------------------------------------------------------------------------
// 4. QKV projection, MFMA, fused per-head RMSNorm for Q and K.
//    grid (8, NTILES, 3). LDS tiles XOR-swizzled [128][64], staged via
//    global_load_lds (linear dest, inverse-swizzled per-lane source).
//    Q folded with C2 = 0.125*log2e.
// ---------------------------------------------------------------------------
__global__ __launch_bounds__(256) void k_qkv(
    const u16* __restrict__ xb, const u16* __restrict__ wqT,
    const u16* __restrict__ wkT, const u16* __restrict__ wvT,
    const int* __restrict__ perm, const int* __restrict__ tmeta,
    const float* __restrict__ qnw, const float* __restrict__ knw,
    const u16* __restrict__ zbuf,
    u16* __restrict__ qb, u16* __restrict__ kb, u16* __restrict__ vb)
{
    int meta = tmeta[blockIdx.y];
    if (meta < 0) return;
    int b = meta >> 1, m = meta & 1;
    const u16* W = (blockIdx.z==0 ? wqT : (blockIdx.z==1 ? wkT : wvT)) + (size_t)m*Ec*Dc;
    u16* outp    = (blockIdx.z==0 ? qb  : (blockIdx.z==1 ? kb  : vb));
    int c0 = blockIdx.x*128;
    int t = threadIdx.x, lane = t & 63, wv_ = t >> 6;
    int quad = lane >> 4, lc = lane & 15;

    __shared__ u16 at[128*64];
    __shared__ u16 bt[128*64];
    __shared__ int sperm[128];
    if (t < 128) sperm[t] = perm[blockIdx.y*128 + t];
    f32x4 acc[2][8];
    #pragma unroll
    for (int i=0;i<2;i++)
        #pragma unroll
        for (int j=0;j<8;j++) acc[i][j] = (f32x4){0.f,0.f,0.f,0.f};
    __syncthreads();

    // staging sources: wave w instr i lane l covers LDS row w*32+i*8+(l>>3),
    // stored group l&7 -> true col8 = (l&7)^(l>>3) (row&7 == l>>3).
    int colsw = ((lane & 7) ^ (lane >> 3)) << 3;
    const u16* ab[4]; const u16* bb[4];
    #pragma unroll
    for (int i = 0; i < 4; i++){
        int row = wv_*32 + i*8 + (lane >> 3);
        int s_ = sperm[row];
        ab[i] = (s_ >= 0) ? (xb + ((size_t)(b*Sc + s_))*Dc + colsw) : zbuf;
        bb[i] = W + (size_t)(c0 + row)*Dc + colsw;
    }

    for (int d0 = 0; d0 < Dc; d0 += 64){
        #pragma unroll
        for (int i = 0; i < 4; i++){
            gl16(ab[i] + d0, &at[(wv_*4 + i)*512]);
            gl16(bb[i] + d0, &bt[(wv_*4 + i)*512]);
        }
        __syncthreads();
        #pragma unroll
        for (int ks = 0; ks < 2; ks++){
            bf8 a0 = *(const bf8*)swzc(at, wv_*32 + lc,      ks*4 + quad);
            bf8 a1 = *(const bf8*)swzc(at, wv_*32 + 16 + lc, ks*4 + quad);
            #pragma unroll
            for (int nb = 0; nb < 8; nb++){
                bf8 bb2 = *(const bf8*)swzc(bt, nb*16 + lc, ks*4 + quad);
                acc[0][nb] = MFMA(a0, bb2, acc[0][nb]);
                acc[1][nb] = MFMA(a1, bb2, acc[1][nb]);
            }
        }
        __syncthreads();
    }

    if (blockIdx.z < 2){
        const float* nw = (blockIdx.z==0 ? qnw : knw) + m*HDc;
        float cs = (blockIdx.z==0) ? C2 : 1.f;   // fold score scale into Q
        float w0 = nw[lc]*cs, w1 = nw[16+lc]*cs, w2 = nw[32+lc]*cs, w3 = nw[48+lc]*cs;
        #pragma unroll
        for (int mb = 0; mb < 2; mb++){
            #pragma unroll
            for (int r = 0; r < 4; r++){
                #pragma unroll
                for (int g = 0; g < 2; g++){
                    float ss = 0.f;
                    #pragma unroll
                    for (int j = 0; j < 4; j++){
                        float v2 = acc[mb][g*4+j][r];
                        ss += v2*v2;
                    }
                    ss += __shfl_xor(ss, 1, 64);
                    ss += __shfl_xor(ss, 2, 64);
                    ss += __shfl_xor(ss, 4, 64);
                    ss += __shfl_xor(ss, 8, 64);
                    float rs = rsqrtf(ss*(1.f/64.f) + EPSc);
                    acc[mb][g*4+0][r] *= rs*w0;
                    acc[mb][g*4+1][r] *= rs*w1;
                    acc[mb][g*4+2][r] *= rs*w2;
                    acc[mb][g*4+3][r] *= rs*w3;
                }
            }
        }
    }

    int h0 = c0 >> 6;
    #pragma unroll
    for (int mb = 0; mb < 2; mb++){
        #pragma unroll
        for (int r = 0; r < 4; r++){
            int row = wv_*32 + mb*16 + quad*4 + r;
            int s_ = sperm[row];
            if (s_ < 0) continue;
            #pragma unroll
            for (int nb = 0; nb < 8; nb++){
                int col = nb*16 + lc;
                int h = h0 + (col >> 6), hd = col & 63;
                outp[(((size_t)(b*Hc + h))*Sc + s_)*HDc + hd] = f2b(acc[mb][nb][r]);
            }
        }
    }
}

// ---------------------------------------------------------------------------
// 6. V transpose via LDS tiles: vb [BH][S][HD] -> vtb [BH][HD][S]
// ---------------------------------------------------------------------------
__global__ __launch_bounds__(256) void k_vt(const u16* __restrict__ vb,
                                            u16* __restrict__ vtb)
{
    __shared__ u16 sh[64][72];
    int t = threadIdx.x;
    int s0 = blockIdx.x*64, bh = blockIdx.y;
    {
        int rr = t >> 2, cc = (t & 3)*16;
        const u16* src = vb + ((size_t)bh*Sc + s0 + rr)*HDc + cc;
        *(uint4*)&sh[rr][cc]   = *(const uint4*)(src);
        *(uint4*)&sh[rr][cc+8] = *(const uint4*)(src+8);
    }
    __syncthreads();
    {
        int hd = t >> 2, sc = (t & 3)*16;
        u16 tmp[16];
        #pragma unroll
        for (int j = 0; j < 16; j++) tmp[j] = sh[sc+j][hd];
        u16* dst = vtb + ((size_t)bh*HDc + hd)*Sc + s0 + sc;
        *(uint4*)(dst)   = *(const uint4*)&tmp[0];
        *(uint4*)(dst+8) = *(const uint4*)&tmp[8];
    }
}

// ---------------------------------------------------------------------------
// 9. flash PV with ONLINE softmax + defer-max (THR=8), split-K x2:
//    grid (32, 16, 4): z = b*2 + half.
//    Swapped QK^T + pi-permuted K staging keeps P in registers in exact PV
//    A-fragment layout. Mask read directly as f32 (fmaf with LOG2E). Native
//    v_exp_f32. Zero cross-lane ops per tile in the common path.
// ---------------------------------------------------------------------------
__global__ __launch_bounds__(256) void k_flash(
    const u16* __restrict__ qb, const u16* __restrict__ kb,
    const u16* __restrict__ vtb, const float* __restrict__ maskf,
    float* __restrict__ pm, float* __restrict__ pl,
    u16* __restrict__ c0, u16* __restrict__ c1)
{
    int qs0 = blockIdx.x*64, h = blockIdx.y;
    int b = blockIdx.z >> 1, half = blockIdx.z & 1;
    u16* ctxh = half ? c1 : c0;
    int t = threadIdx.x, lane = t & 63, wv_ = t >> 6;
    int quad = lane >> 4, lc = lane & 15;
    __shared__ u16 kt[64*64];
    __shared__ u16 vt[64*64];
    const u16* qp  = qb  + ((size_t)(b*Hc+h))*Sc*HDc;
    const u16* kp  = kb  + ((size_t)(b*Hc+h))*Sc*HDc;
    const u16* vtp = vtb + ((size_t)(b*Hc+h))*HDc*Sc;
    const float* mq = maskf + (size_t)(qs0 + wv_*16 + lc)*Sc;  // this lane's q-row
    bf8 aq[2];
    #pragma unroll
    for (int ks = 0; ks < 2; ks++)
        aq[ks] = *(const bf8*)(qp + (size_t)(qs0 + wv_*16 + lc)*HDc + ks*32 + quad*8);
    // online stats for this lane's q row (rm row-uniform; rl per-lane partial)
    float rm = -1.0e30f, rl = 0.f;
    f32x4 oacc[4];
    #pragma unroll
    for (int j=0;j<4;j++) oacc[j] = (f32x4){0.f,0.f,0.f,0.f};

    int rr = t >> 2, c8 = (t & 3)*2;
    // pi: global k-row rr -> LDS row (b5<<5)|(b2<<4)|(b4<<3)|(b3<<2)|(b1<<1)|b0
    int pr = (rr & 0x23) | ((rr & 0x04) << 2) | ((rr & 0x18) >> 1);
    int kc0 = half*1024;
    for (int kc = kc0; kc < kc0 + 1024; kc += 64){
        // per-lane mask loads (f32, L2-hit) issued before the barrier
        float4 mvf[2][2];
        #pragma unroll
        for (int a1 = 0; a1 < 2; a1++)
            #pragma unroll
            for (int b1 = 0; b1 < 2; b1++)
                mvf[a1][b1] = *(const float4*)(mq + kc + a1*32 + quad*8 + b1*4);
        __syncthreads();
        {
            const u16* s1 = kp + (size_t)(kc+rr)*HDc + c8*8;
            *(uint4*)swz(kt, pr, c8)   = *(const uint4*)(s1);
            *(uint4*)swz(kt, pr, c8+1) = *(const uint4*)(s1+8);
            const u16* s2 = vtp + (size_t)rr*Sc + kc + c8*8;
            *(uint4*)swz(vt, rr, c8)   = *(const uint4*)(s2);
            *(uint4*)swz(vt, rr, c8+1) = *(const uint4*)(s2+8);
        }
        __syncthreads();
        // S^T = K * Q^T (Q pre-scaled by C2)
        f32x4 acc[4];
        #pragma unroll
        for (int j=0;j<4;j++) acc[j] = (f32x4){0.f,0.f,0.f,0.f};
        #pragma unroll
        for (int ks = 0; ks < 2; ks++){
            #pragma unroll
            for (int nb = 0; nb < 4; nb++){
                bf8 ak = *(const bf8*)swzc(kt, nb*16 + lc, ks*4 + quad);
                acc[nb] = MFMA(ak, aq[ks], acc[nb]);
            }
        }
        // scores + mask (fmaf), per-lane partial max
        float svv[4][4];
        float mxl = -3.0e38f;
        #pragma unroll
        for (int a1 = 0; a1 < 2; a1++){
            #pragma unroll
            for (int b1 = 0; b1 < 2; b1++){
                int nb = 2*a1 + b1;
                #pragma unroll
                for (int r = 0; r < 4; r++){
                    float mk = (r==0?mvf[a1][b1].x:r==1?mvf[a1][b1].y:
                                r==2?mvf[a1][b1].z:mvf[a1][b1].w);
                    float s2v = fmaf(mk, LOG2E, acc[nb][r]);
                    svv[nb][r] = s2v;
                    mxl = fmaxf(mxl, s2v);
                }
            }
        }
        // defer-max: only reduce/rescale when some lane grew past rm + 8
        if (__any(mxl > rm + 8.f)){
            float mx = fmaxf(mxl, __shfl_xor(mxl, 16, 64));
            mx = fmaxf(mx, __shfl_xor(mx, 32, 64));
            float nm = fmaxf(rm, mx);
            float fac = ex2(rm - nm);
            rm = nm;
            rl *= fac;
            float f0 = __shfl(fac, quad*4+0, 64);
            float f1 = __shfl(fac, quad*4+1, 64);
            float f2 = __shfl(fac, quad*4+2, 64);
            float f3 = __shfl(fac, quad*4+3, 64);
            #pragma unroll
            for (int nb = 0; nb < 4; nb++){
                oacc[nb][0] *= f0; oacc[nb][1] *= f1;
                oacc[nb][2] *= f2; oacc[nb][3] *= f3;
            }
        }
        // P (bounded by 2^8) packed via cvt_pk straight into PV A-fragments
        #pragma unroll
        for (int a1 = 0; a1 < 2; a1++){
            bfpack pk;
            {
                float p0 = ex2(svv[2*a1][0] - rm);
                float p1 = ex2(svv[2*a1][1] - rm);
                float p2 = ex2(svv[2*a1][2] - rm);
                float p3 = ex2(svv[2*a1][3] - rm);
                rl += (p0 + p1) + (p2 + p3);
                pk.u[0] = cvtpk(p0, p1); pk.u[1] = cvtpk(p2, p3);
            }
            {
                float p0 = ex2(svv[2*a1+1][0] - rm);
                float p1 = ex2(svv[2*a1+1][1] - rm);
                float p2 = ex2(svv[2*a1+1][2] - rm);
                float p3 = ex2(svv[2*a1+1][3] - rm);
                rl += (p0 + p1) + (p2 + p3);
                pk.u[2] = cvtpk(p0, p1); pk.u[3] = cvtpk(p2, p3);
            }
            bf8 ap = pk.v;
            #pragma unroll
            for (int nb2 = 0; nb2 < 4; nb2++){
                bf8 bv = *(const bf8*)swzc(vt, nb2*16 + lc, a1*4 + quad);
                oacc[nb2] = MFMA(ap, bv, oacc[nb2]);
            }
        }
    }
    // reduce per-lane partial l across the 4 lanes of each q-row (once)
    rl += __shfl_xor(rl, 16, 64);
    rl += __shfl_xor(rl, 32, 64);
    // per-half stats out (lanes with quad==0 hold rows 0..15 of this wave)
    if (quad == 0){
        size_t srow = ((size_t)(b*Hc+h))*Sc + qs0 + wv_*16 + lc;
        pm[(size_t)half*65536 + srow] = rm;
        pl[(size_t)half*65536 + srow] = rl;
    }
    // ctx normalized by this half's own l
    float i0 = 1.f/__shfl(rl, quad*4+0, 64);
    float i1 = 1.f/__shfl(rl, quad*4+1, 64);
    float i2 = 1.f/__shfl(rl, quad*4+2, 64);
    float i3 = 1.f/__shfl(rl, quad*4+3, 64);
    #pragma unroll
    for (int r = 0; r < 4; r++){
        float ir = (r==0?i0:r==1?i1:r==2?i2:i3);
        int tok = qs0 + wv_*16 + quad*4 + r;
        #pragma unroll
        for (int nb = 0; nb < 4; nb++){
            int hd = nb*16 + lc;
            ctxh[((size_t)(b*Sc + tok))*Ec + h*HDc + hd] = f2b(oacc[nb][r]*ir);
        }
    }
}

// ---------------------------------------------------------------------------
// 9b. merge the two half stats -> combine weights + attnw constant.
// ---------------------------------------------------------------------------
__global__ __launch_bounds__(256) void k_merge(
    const float* __restrict__ pm, const float* __restrict__ pl,
    float* __restrict__ lstc, float* __restrict__ w0, float* __restrict__ w1)
{
    int r = blockIdx.x*256 + threadIdx.x;
    float m0 = pm[r],        m1 = pm[65536 + r];
    float l0 = pl[r],        l1 = pl[65536 + r];
    float M  = fmaxf(m0, m1);
    float e0 = ex2(m0 - M)*l0;
    float e1 = ex2(m1 - M)*l1;
    float L  = e0 + e1;
    float iL = 1.f/L;
    lstc[r] = M + log2f(L);
    w0[r] = e0*iL;
    w1[r] = e1*iL;
}

// ---------------------------------------------------------------------------
// 9c. weighted combine of the two ctx halves: c0 = w0*c0 + w1*c1
// ---------------------------------------------------------------------------
__global__ __launch_bounds__(256) void k_addc(u16* __restrict__ c0,
                                              const u16* __restrict__ c1,
                                              const float* __restrict__ w0,
                                              const float* __restrict__ w1)
{
    int i = (blockIdx.x*256 + threadIdx.x)*8;
    int hh = (i >> 6) & 15, s = (i >> 10) & 2047, bb = i >> 21;
    int wi = ((bb*Hc + hh) << 11) + s;
    float wa = w0[wi], wb = w1[wi];
    ushort4 a0 = *(ushort4*)&c0[i],   a1 = *(ushort4*)&c0[i+4];
    ushort4 b0 = *(const ushort4*)&c1[i], b1 = *(const ushort4*)&c1[i+4];
    ushort4 o0, o1;
    o0.x = f2b(b2f(a0.x)*wa + b2f(b0.x)*wb); o0.y = f2b(b2f(a0.y)*wa + b2f(b0.y)*wb);
    o0.z = f2b(b2f(a0.z)*wa + b2f(b0.z)*wb); o0.w = f2b(b2f(a0.w)*wa + b2f(b0.w)*wb);
    o1.x = f2b(b2f(a1.x)*wa + b2f(b1.x)*wb); o1.y = f2b(b2f(a1.y)*wa + b2f(b1.y)*wb);
    o1.z = f2b(b2f(a1.z)*wa + b2f(b1.z)*wb); o1.w = f2b(b2f(a1.w)*wa + b2f(b1.w)*wb);
    *(ushort4*)&c0[i]   = o0;
    *(ushort4*)&c0[i+4] = o1;
}

// ---------------------------------------------------------------------------
// 8. attn_weights: q-tile 64, k-tile 64, loop all 16 h, NO atomics.
//    grid (32, 32, 2) = (q, k, b). Folded cc = M + log2(L); Q pre-scaled by
//    C2. Native v_exp_f32. Mask read as f32 in the epilogue.
// ---------------------------------------------------------------------------
__global__ __launch_bounds__(256) void k_attnw(
    const u16* __restrict__ qb, const u16* __restrict__ kb,
    const float* __restrict__ maskf, const float* __restrict__ lstc,
    float* __restrict__ awout)
{
    int qs0 = blockIdx.x*64, ks0 = blockIdx.y*64, b = blockIdx.z;
    int t = threadIdx.x, lane = t & 63, wv_ = t >> 6;
    int quad = lane >> 4, lc = lane & 15;
    __shared__ u16 kt[64*64];
    __shared__ float scc[64];
    f32x4 T[4];
    #pragma unroll
    for (int j=0;j<4;j++) T[j] = (f32x4){0.f,0.f,0.f,0.f};

    for (int h = 0; h < Hc; h++){
        __syncthreads();
        const u16* qp = qb + ((size_t)(b*Hc+h))*Sc*HDc;
        const u16* kp = kb + ((size_t)(b*Hc+h))*Sc*HDc;
        bf8 aq[2];
        #pragma unroll
        for (int ks = 0; ks < 2; ks++)
            aq[ks] = *(const bf8*)(qp + (size_t)(qs0 + wv_*16 + lc)*HDc + ks*32 + quad*8);
        {
            int rr = t >> 2, c8 = (t & 3)*2;
            const u16* s2 = kp + (size_t)(ks0+rr)*HDc + c8*8;
            *(uint4*)swz(kt, rr, c8)   = *(const uint4*)(s2);
            *(uint4*)swz(kt, rr, c8+1) = *(const uint4*)(s2+8);
        }
        if (t < 64)
            scc[t] = lstc[((size_t)(b*Hc+h))*Sc + qs0 + t];
        __syncthreads();
        f32x4 acc[4];
        #pragma unroll
        for (int j=0;j<4;j++) acc[j] = (f32x4){0.f,0.f,0.f,0.f};
        #pragma unroll
        for (int ks = 0; ks < 2; ks++){
            #pragma unroll
            for (int nb = 0; nb < 4; nb++){
                bf8 bb = *(const bf8*)swzc(kt, nb*16 + lc, ks*4 + quad);
                acc[nb] = MFMA(aq[ks], bb, acc[nb]);
            }
        }
        #pragma unroll
        for (int r = 0; r < 4; r++){
            int row = wv_*16 + quad*4 + r;
            float cv = scc[row];
            #pragma unroll
            for (int nb = 0; nb < 4; nb++)
                T[nb][r] += ex2(acc[nb][r] - cv);
        }
    }
    #pragma unroll
    for (int r = 0; r < 4; r++){
        int gq = qs0 + wv_*16 + quad*4 + r;
        #pragma unroll
        for (int nb = 0; nb < 4; nb++){
            int gk = ks0 + nb*16 + lc;
            float mk = maskf[(size_t)gq*Sc + gk];
            awout[(size_t)b*Sc*Sc + (size_t)gq*Sc + gk]
                = T[nb][r]*ex2(mk*LOG2E)*(1.f/16.f);
        }
    }
}

// ---------------------------------------------------------------------------
// 10. output projection, MFMA. grid (8, NTILES). XOR-swizzled tiles staged
//     via global_load_lds (same mapping as k_qkv).
// ---------------------------------------------------------------------------
__global__ __launch_bounds__(256) void k_oproj(
    const u16* __restrict__ ctxb, const u16* __restrict__ woT,
    const int* __restrict__ perm, const int* __restrict__ tmeta,
    const u16* __restrict__ zbuf, float* __restrict__ opre)
{
    int meta = tmeta[blockIdx.y];
    if (meta < 0) return;
    int b = meta >> 1, m = meta & 1;
    const u16* W = woT + (size_t)m*Ec*Dc;
    int c0 = blockIdx.x*128;
    int t = threadIdx.x, lane = t & 63, wv_ = t >> 6;
    int quad = lane >> 4, lc = lane & 15;
    __shared__ u16 at[128*64];
    __shared__ u16 bt[128*64];
    __shared__ int sperm[128];
    if (t < 128) sperm[t] = perm[blockIdx.y*128 + t];
    f32x4 acc[2][8];
    #pragma unroll
    for (int i=0;i<2;i++)
        #pragma unroll
        for (int j=0;j<8;j++) acc[i][j] = (f32x4){0.f,0.f,0.f,0.f};
    __syncthreads();

    int colsw = ((lane & 7) ^ (lane >> 3)) << 3;
    const u16* ab[4]; const u16* bb[4];
    #pragma unroll
    for (int i = 0; i < 4; i++){
        int row = wv_*32 + i*8 + (lane >> 3);
        int s_ = sperm[row];
        ab[i] = (s_ >= 0) ? (ctxb + ((size_t)(b*Sc + s_))*Ec + colsw) : zbuf;
        bb[i] = W + (size_t)(c0 + row)*Ec + colsw;
    }

    for (int d0 = 0; d0 < Ec; d0 += 64){
        #pragma unroll
        for (int i = 0; i < 4; i++){
            gl16(ab[i] + d0, &at[(wv_*4 + i)*512]);
            gl16(bb[i] + d0, &bt[(wv_*4 + i)*512]);
        }
        __syncthreads();
        #pragma unroll
        for (int ks = 0; ks < 2; ks++){
            bf8 a0 = *(const bf8*)swzc(at, wv_*32 + lc,      ks*4 + quad);
            bf8 a1 = *(const bf8*)swzc(at, wv_*32 + 16 + lc, ks*4 + quad);
            #pragma unroll
            for (int nb = 0; nb < 8; nb++){
                bf8 bb2 = *(const bf8*)swzc(bt, nb*16 + lc, ks*4 + quad);
                acc[0][nb] = MFMA(a0, bb2, acc[0][nb]);
                acc[1][nb] = MFMA(a1, bb2, acc[1][nb]);
            }
        }
        __syncthreads();
    }
    #pragma unroll
    for (int mb = 0; mb < 2; mb++){
        #pragma unroll
        for (int r = 0; r < 4; r++){
            int row = wv_*32 + mb*16 + quad*4 + r;
            int s_ = sperm[row];
            if (s_ < 0) continue;
            #pragma unroll
            for (int nb = 0; nb < 8; nb++){
                int col = c0 + nb*16 + lc;
                opre[((size_t)(b*Sc + s_))*Dc + col] = acc[mb][nb][r];
            }
        }
    }
}

// ---------------------------------------------------------------------------
// 11. final RMSNorm over D -> out
// ---------------------------------------------------------------------------
__global__ __launch_bounds__(256) void k_onorm(
    const float* __restrict__ opre, const float* __restrict__ anw,
    const int* __restrict__ mod, float* __restrict__ out)
{
    int row = blockIdx.x;
    int m = mod[row];
    int t = threadIdx.x;
    float val[4];
    float ss = 0.f;
    #pragma unroll
    for (int j=0;j<4;j++){
        val[j] = opre[(size_t)row*Dc + t + 256*j];
        ss += val[j]*val[j];
    }
    #pragma unroll
    for (int o=32;o>0;o>>=1) ss += __shfl_xor(ss, o, 64);
    __shared__ float red[4];
    int wid = t>>6, lane = t&63;
    if (lane==0) red[wid]=ss;
    __syncthreads();
    float tot = red[0]+red[1]+red[2]+red[3];
    float rms = rsqrtf(tot*(1.f/1024.f) + EPSc);
    #pragma unroll
    for (int j=0;j<4;j++)
        out[(size_t)row*Dc + t + 256*j] = val[j]*rms*anw[m*Dc + t + 256*j];
}

// ---------------------------------------------------------------------------
extern "C" void kernel_launch(void* const* d_in, const int* in_sizes, int n_in,
                              void* d_out, int out_size, void* d_ws, size_t ws_size,
                              hipStream_t stream)
{
    const float* x    = (const float*)d_in[0];
    const float* mask = (const float*)d_in[1];
    const int*   mod  = (const int*)  d_in[2];
    const float* Wq   = (const float*)d_in[3];
    const float* Wk   = (const float*)d_in[4];
    const float* Wv   = (const float*)d_in[5];
    const float* Wo   = (const float*)d_in[6];
    const float* qnw  = (const float*)d_in[7];
    const float* knw  = (const float*)d_in[8];
    const float* anw  = (const float*)d_in[9];

    float* out   = (float*)d_out;                 // [B,S,D]
    float* awout = out + (size_t)Bc*Sc*Dc;        // [B,S,S]

    float* ws = (float*)d_ws;
    u16* qb    = (u16*)(ws + 0);
    u16* kb    = (u16*)(ws + 2097152);
    u16* vb    = (u16*)(ws + 4194304);   // dead after k_vt -> ctx partial 1
    u16* xb    = (u16*)(ws + 6291456);   // dead after k_qkv -> ctx partial 0
    u16* ctx0  = xb;
    u16* ctx1  = vb;
    u16* vtb   = (u16*)(ws + 8388608);
    u16* wqT   = (u16*)(ws + 10485760);
    u16* wkT   = (u16*)(ws + 11534336);
    u16* wvT   = (u16*)(ws + 12582912);
    u16* woT   = (u16*)(ws + 13631488);
    float* lstc= ws + 14680064;          // M + log2(L), 65536
    float* pm  = ws + 14811136;          // per-half m, 2*65536
    float* pl  = pm + 131072;            // per-half l, 2*65536
    float* w0  = ws + 15073280;          // combine weights, 65536 each
    float* w1  = w0 + 65536;
    int* perm  = (int*)(ws + 17432576);
    int* tmeta = perm + NTILES*TILE_R;
    u16* zbuf  = (u16*)(tmeta + NTILES + 28);   // 4KB zero scratch (aligned)
    float* opre = ws;                    // aliases qb+kb (dead by then)

    k_perm  <<<dim3(1),            256, 0, stream>>>(mod, perm, tmeta, zbuf);
    k_f2b   <<<dim3(4096),         256, 0, stream>>>(x, xb, Bc*Sc*Dc);
    k_tcvt  <<<dim3(32,32,8),      256, 0, stream>>>(Wq, Wk, Wv, Wo, wqT, wkT, wvT, woT);
    k_qkv   <<<dim3(8,NTILES,3),   256, 0, stream>>>(xb, wqT, wkT, wvT, perm, tmeta,
                                                     qnw, knw, zbuf, qb, kb, vb);
    k_vt    <<<dim3(32,32),        256, 0, stream>>>(vb, vtb);
    k_flash <<<dim3(32,16,4),      256, 0, stream>>>(qb, kb, vtb, mask, pm, pl, ctx0, ctx1);
    k_merge <<<dim3(256),          256, 0, stream>>>(pm, pl, lstc, w0, w1);
    k_attnw <<<dim3(32,32,2),      256, 0, stream>>>(qb, kb, mask, lstc, awout);
    k_addc  <<<dim3(2048),         256, 0, stream>>>(ctx0, ctx1, w0, w1);
    k_oproj <<<dim3(8,NTILES),     256, 0, stream>>>(ctx0, woT, perm, tmeta, zbuf, opre);
    k_onorm <<<dim3(4096),         256, 0, stream>>>(opre, anw, mod, out);
}

// Round 7
// 346.974 us; speedup vs baseline: 1.4453x; 1.0707x over previous
//
#include <hip/hip_runtime.h>
#include <cstdint>

#define Bc  2
#define Sc  2048
#define Dc  1024
#define Ec  1024
#define Hc  16
#define HDc 64
#define TTc (Bc*Sc)
#define TILE_R 128
#define NTILES 36
#define EPSc 1e-5f
#define LOG2E 1.44269504f
#define C2    (0.125f*LOG2E)

typedef unsigned short u16;
using bf8   = __attribute__((ext_vector_type(8))) short;
using f32x4 = __attribute__((ext_vector_type(4))) float;
#define MFMA(a,b,c) __builtin_amdgcn_mfma_f32_16x16x32_bf16(a,b,c,0,0,0)

static __device__ __forceinline__ u16 f2b(float f){
    return (u16)((__float_as_uint(f) + 0x8000u) >> 16);
}
static __device__ __forceinline__ float b2f(u16 s){
    return __uint_as_float(((unsigned)s) << 16);
}
// raw v_exp_f32 (2^x): inputs here are <= ~8; underflow flushes to 0 which is
// exactly the wanted semantics. Avoids OCML's multi-instruction wrapper.
static __device__ __forceinline__ float ex2(float x){
    return __builtin_amdgcn_exp2f(x);
}
// pack two f32 -> one dword of 2 bf16 (low = a, high = b), single VALU op
static __device__ __forceinline__ unsigned cvtpk(float a, float b){
    unsigned r;
    asm("v_cvt_pk_bf16_f32 %0, %1, %2" : "=v"(r) : "v"(a), "v"(b));
    return r;
}
union bfpack { unsigned u[4]; bf8 v; };
// XOR-swizzled LDS addressing: tiles are [R][64] u16, 8-u16 (16B) groups,
// group index col8 swizzled by row&7 -> fragment ds_read_b128 is
// bank-conflict-free.
static __device__ __forceinline__ u16* swz(u16* base, int row, int col8){
    return base + row*64 + ((col8 ^ (row & 7)) << 3);
}
static __device__ __forceinline__ const u16* swzc(const u16* base, int row, int col8){
    return base + row*64 + ((col8 ^ (row & 7)) << 3);
}
// async global->LDS, 16B per lane. LDS dest = wave-uniform base + lane*16
// (linear); the swizzle is applied by inverse-permuting the per-lane global
// source address (rule: linear dest + inv-swz source + swz read).
typedef const __attribute__((address_space(1))) void* gp1;
typedef __attribute__((address_space(3))) void* lp3;
static __device__ __forceinline__ void gl16(const void* g, void* l){
    __builtin_amdgcn_global_load_lds((gp1)g, (lp3)l, 16, 0, 0);
}

// ---------------------------------------------------------------------------
// 1. modality-sorted token permutation, 128-padded segments per (b,m).
//    Also zeroes the 4KB zbuf used by gload_lds staging for padding rows.
// ---------------------------------------------------------------------------
__global__ void k_perm(const int* __restrict__ mod, int* __restrict__ perm,
                       int* __restrict__ tmeta, u16* __restrict__ zbuf)
{
    __shared__ int cnt[4], segstart[4];
    int t = threadIdx.x;
    for (int i = t; i < 2048; i += 256) zbuf[i] = 0;
    if (t < 4) cnt[t] = 0;
    __syncthreads();
    for (int i = t; i < TTc; i += 256){
        int b = i >> 11; int m = mod[i];
        atomicAdd(&cnt[b*2+m], 1);
    }
    __syncthreads();
    if (t == 0){
        int off = 0;
        for (int i = 0; i < 4; i++){
            segstart[i] = off;
            int pad = ((cnt[i] + TILE_R - 1)/TILE_R)*TILE_R;
            for (int tt = off/TILE_R; tt < (off+pad)/TILE_R; tt++) tmeta[tt] = i;
            off += pad;
        }
        for (int tt = off/TILE_R; tt < NTILES; tt++) tmeta[tt] = -1;
    }
    __syncthreads();
    if (t < 4) cnt[t] = 0;
    for (int i = t; i < NTILES*TILE_R; i += 256) perm[i] = -1;
    __syncthreads();
    for (int i = t; i < TTc; i += 256){
        int b = i >> 11, s = i & 2047; int m = mod[i];
        int r = atomicAdd(&cnt[b*2+m], 1);
        perm[segstart[b*2+m] + r] = s;
    }
}

// ---------------------------------------------------------------------------
// 2. fp32 -> bf16 elementwise (plain and scaled variants)
// ---------------------------------------------------------------------------
__global__ __launch_bounds__(256) void k_f2b(const float* __restrict__ src,
                                             u16* __restrict__ dst, int n)
{
    int i = (blockIdx.x*256 + threadIdx.x)*4;
    if (i >= n) return;
    float4 v = *(const float4*)&src[i];
    ushort4 o;
    o.x = f2b(v.x); o.y = f2b(v.y); o.z = f2b(v.z); o.w = f2b(v.w);
    *(ushort4*)&dst[i] = o;
}

__global__ __launch_bounds__(256) void k_f2bs(const float* __restrict__ src,
                                              u16* __restrict__ dst, int n, float sc)
{
    int i = (blockIdx.x*256 + threadIdx.x)*4;
    if (i >= n) return;
    float4 v = *(const float4*)&src[i];
    ushort4 o;
    o.x = f2b(v.x*sc); o.y = f2b(v.y*sc); o.z = f2b(v.z*sc); o.w = f2b(v.w*sc);
    *(ushort4*)&dst[i] = o;
}

// ---------------------------------------------------------------------------
// 3. transpose+convert all four weights in one launch; grid (32,32,8)
// ---------------------------------------------------------------------------
__global__ __launch_bounds__(256) void k_tcvt(
    const float* __restrict__ s0, const float* __restrict__ s1,
    const float* __restrict__ s2, const float* __restrict__ s3,
    u16* __restrict__ d0, u16* __restrict__ d1,
    u16* __restrict__ d2, u16* __restrict__ d3)
{
    int wsel = blockIdx.z >> 1, m = blockIdx.z & 1;
    const float* src = (wsel==0?s0:wsel==1?s1:wsel==2?s2:s3) + (size_t)m*1048576;
    u16*       dst = (wsel==0?d0:wsel==1?d1:wsel==2?d2:d3) + (size_t)m*1048576;
    __shared__ float sh[32][33];
    int t = threadIdx.x;
    int i0 = blockIdx.x*32, j0 = blockIdx.y*32;
    {
        int i = t >> 3, j4 = (t & 7)*4;
        *(float4*)&sh[i][j4] = *(const float4*)&src[(size_t)(i0+i)*1024 + j0 + j4];
    }
    __syncthreads();
    {
        int j = t >> 3, i4 = (t & 7)*4;
        ushort4 o;
        o.x = f2b(sh[i4+0][j]); o.y = f2b(sh[i4+1][j]);
        o.z = f2b(sh[i4+2][j]); o.w = f2b(sh[i4+3][j]);
        *(ushort4*)&dst[(size_t)(j0+j)*1024 + i0 + i4] = o;
    }
}

// ---------------------------------------------------------------------------
// 4. QKV projection, MFMA, fused per-head RMSNorm for Q and K.
//    grid (8, NTILES, 3). LDS tiles XOR-swizzled [128][64], staged via
//    global_load_lds (linear dest, inverse-swizzled per-lane source).
//    Q folded with C2 = 0.125*log2e.
// ---------------------------------------------------------------------------
__global__ __launch_bounds__(256) void k_qkv(
    const u16* __restrict__ xb, const u16* __restrict__ wqT,
    const u16* __restrict__ wkT, const u16* __restrict__ wvT,
    const int* __restrict__ perm, const int* __restrict__ tmeta,
    const float* __restrict__ qnw, const float* __restrict__ knw,
    const u16* __restrict__ zbuf,
    u16* __restrict__ qb, u16* __restrict__ kb, u16* __restrict__ vb)
{
    int meta = tmeta[blockIdx.y];
    if (meta < 0) return;
    int b = meta >> 1, m = meta & 1;
    const u16* W = (blockIdx.z==0 ? wqT : (blockIdx.z==1 ? wkT : wvT)) + (size_t)m*Ec*Dc;
    u16* outp    = (blockIdx.z==0 ? qb  : (blockIdx.z==1 ? kb  : vb));
    int c0 = blockIdx.x*128;
    int t = threadIdx.x, lane = t & 63, wv_ = t >> 6;
    int quad = lane >> 4, lc = lane & 15;

    __shared__ u16 at[128*64];
    __shared__ u16 bt[128*64];
    __shared__ int sperm[128];
    if (t < 128) sperm[t] = perm[blockIdx.y*128 + t];
    f32x4 acc[2][8];
    #pragma unroll
    for (int i=0;i<2;i++)
        #pragma unroll
        for (int j=0;j<8;j++) acc[i][j] = (f32x4){0.f,0.f,0.f,0.f};
    __syncthreads();

    // staging sources: wave w instr i lane l covers LDS row w*32+i*8+(l>>3),
    // stored group l&7 -> true col8 = (l&7)^(l>>3) (row&7 == l>>3).
    int colsw = ((lane & 7) ^ (lane >> 3)) << 3;
    const u16* ab[4]; const u16* bb[4];
    #pragma unroll
    for (int i = 0; i < 4; i++){
        int row = wv_*32 + i*8 + (lane >> 3);
        int s_ = sperm[row];
        ab[i] = (s_ >= 0) ? (xb + ((size_t)(b*Sc + s_))*Dc + colsw) : zbuf;
        bb[i] = W + (size_t)(c0 + row)*Dc + colsw;
    }

    for (int d0 = 0; d0 < Dc; d0 += 64){
        #pragma unroll
        for (int i = 0; i < 4; i++){
            gl16(ab[i] + d0, &at[(wv_*4 + i)*512]);
            gl16(bb[i] + d0, &bt[(wv_*4 + i)*512]);
        }
        __syncthreads();
        #pragma unroll
        for (int ks = 0; ks < 2; ks++){
            bf8 a0 = *(const bf8*)swzc(at, wv_*32 + lc,      ks*4 + quad);
            bf8 a1 = *(const bf8*)swzc(at, wv_*32 + 16 + lc, ks*4 + quad);
            #pragma unroll
            for (int nb = 0; nb < 8; nb++){
                bf8 bb2 = *(const bf8*)swzc(bt, nb*16 + lc, ks*4 + quad);
                acc[0][nb] = MFMA(a0, bb2, acc[0][nb]);
                acc[1][nb] = MFMA(a1, bb2, acc[1][nb]);
            }
        }
        __syncthreads();
    }

    if (blockIdx.z < 2){
        const float* nw = (blockIdx.z==0 ? qnw : knw) + m*HDc;
        float cs = (blockIdx.z==0) ? C2 : 1.f;   // fold score scale into Q
        float w0 = nw[lc]*cs, w1 = nw[16+lc]*cs, w2 = nw[32+lc]*cs, w3 = nw[48+lc]*cs;
        #pragma unroll
        for (int mb = 0; mb < 2; mb++){
            #pragma unroll
            for (int r = 0; r < 4; r++){
                #pragma unroll
                for (int g = 0; g < 2; g++){
                    float ss = 0.f;
                    #pragma unroll
                    for (int j = 0; j < 4; j++){
                        float v2 = acc[mb][g*4+j][r];
                        ss += v2*v2;
                    }
                    ss += __shfl_xor(ss, 1, 64);
                    ss += __shfl_xor(ss, 2, 64);
                    ss += __shfl_xor(ss, 4, 64);
                    ss += __shfl_xor(ss, 8, 64);
                    float rs = rsqrtf(ss*(1.f/64.f) + EPSc);
                    acc[mb][g*4+0][r] *= rs*w0;
                    acc[mb][g*4+1][r] *= rs*w1;
                    acc[mb][g*4+2][r] *= rs*w2;
                    acc[mb][g*4+3][r] *= rs*w3;
                }
            }
        }
    }

    int h0 = c0 >> 6;
    #pragma unroll
    for (int mb = 0; mb < 2; mb++){
        #pragma unroll
        for (int r = 0; r < 4; r++){
            int row = wv_*32 + mb*16 + quad*4 + r;
            int s_ = sperm[row];
            if (s_ < 0) continue;
            #pragma unroll
            for (int nb = 0; nb < 8; nb++){
                int col = nb*16 + lc;
                int h = h0 + (col >> 6), hd = col & 63;
                outp[(((size_t)(b*Hc + h))*Sc + s_)*HDc + hd] = f2b(acc[mb][nb][r]);
            }
        }
    }
}

// ---------------------------------------------------------------------------
// 6. V transpose via LDS tiles: vb [BH][S][HD] -> vtb [BH][HD][S]
// ---------------------------------------------------------------------------
__global__ __launch_bounds__(256) void k_vt(const u16* __restrict__ vb,
                                            u16* __restrict__ vtb)
{
    __shared__ u16 sh[64][72];
    int t = threadIdx.x;
    int s0 = blockIdx.x*64, bh = blockIdx.y;
    {
        int rr = t >> 2, cc = (t & 3)*16;
        const u16* src = vb + ((size_t)bh*Sc + s0 + rr)*HDc + cc;
        *(uint4*)&sh[rr][cc]   = *(const uint4*)(src);
        *(uint4*)&sh[rr][cc+8] = *(const uint4*)(src+8);
    }
    __syncthreads();
    {
        int hd = t >> 2, sc = (t & 3)*16;
        u16 tmp[16];
        #pragma unroll
        for (int j = 0; j < 16; j++) tmp[j] = sh[sc+j][hd];
        u16* dst = vtb + ((size_t)bh*HDc + hd)*Sc + s0 + sc;
        *(uint4*)(dst)   = *(const uint4*)&tmp[0];
        *(uint4*)(dst+8) = *(const uint4*)&tmp[8];
    }
}

// ---------------------------------------------------------------------------
// 9. flash PV with ONLINE softmax + defer-max (THR=8), split-K x2:
//    grid (32, 16, 4): z = b*2 + half.
//    Swapped QK^T + pi-permuted K staging keeps P in registers in exact PV
//    A-fragment layout. Mask: bf16, pre-scaled by LOG2E (per-lane 8B loads
//    -- half the L2/HBM bytes of the f32 path, which was the r6 regression).
//    Native v_exp_f32. Zero cross-lane ops per tile in the common path.
// ---------------------------------------------------------------------------
__global__ __launch_bounds__(256) void k_flash(
    const u16* __restrict__ qb, const u16* __restrict__ kb,
    const u16* __restrict__ vtb, const u16* __restrict__ maskb,
    float* __restrict__ pm, float* __restrict__ pl,
    u16* __restrict__ c0, u16* __restrict__ c1)
{
    int qs0 = blockIdx.x*64, h = blockIdx.y;
    int b = blockIdx.z >> 1, half = blockIdx.z & 1;
    u16* ctxh = half ? c1 : c0;
    int t = threadIdx.x, lane = t & 63, wv_ = t >> 6;
    int quad = lane >> 4, lc = lane & 15;
    __shared__ u16 kt[64*64];
    __shared__ u16 vt[64*64];
    const u16* qp  = qb  + ((size_t)(b*Hc+h))*Sc*HDc;
    const u16* kp  = kb  + ((size_t)(b*Hc+h))*Sc*HDc;
    const u16* vtp = vtb + ((size_t)(b*Hc+h))*HDc*Sc;
    const u16* mq  = maskb + (size_t)(qs0 + wv_*16 + lc)*Sc;  // this lane's q-row
    bf8 aq[2];
    #pragma unroll
    for (int ks = 0; ks < 2; ks++)
        aq[ks] = *(const bf8*)(qp + (size_t)(qs0 + wv_*16 + lc)*HDc + ks*32 + quad*8);
    // online stats for this lane's q row (rm row-uniform; rl per-lane partial)
    float rm = -1.0e30f, rl = 0.f;
    f32x4 oacc[4];
    #pragma unroll
    for (int j=0;j<4;j++) oacc[j] = (f32x4){0.f,0.f,0.f,0.f};

    int rr = t >> 2, c8 = (t & 3)*2;
    // pi: global k-row rr -> LDS row (b5<<5)|(b2<<4)|(b4<<3)|(b3<<2)|(b1<<1)|b0
    int pr = (rr & 0x23) | ((rr & 0x04) << 2) | ((rr & 0x18) >> 1);
    int kc0 = half*1024;
    for (int kc = kc0; kc < kc0 + 1024; kc += 64){
        // per-lane mask loads (bf16, L2-hit) issued before the barrier
        ushort4 mv[2][2];
        #pragma unroll
        for (int a1 = 0; a1 < 2; a1++)
            #pragma unroll
            for (int b1 = 0; b1 < 2; b1++)
                mv[a1][b1] = *(const ushort4*)(mq + kc + a1*32 + quad*8 + b1*4);
        __syncthreads();
        {
            const u16* s1 = kp + (size_t)(kc+rr)*HDc + c8*8;
            *(uint4*)swz(kt, pr, c8)   = *(const uint4*)(s1);
            *(uint4*)swz(kt, pr, c8+1) = *(const uint4*)(s1+8);
            const u16* s2 = vtp + (size_t)rr*Sc + kc + c8*8;
            *(uint4*)swz(vt, rr, c8)   = *(const uint4*)(s2);
            *(uint4*)swz(vt, rr, c8+1) = *(const uint4*)(s2+8);
        }
        __syncthreads();
        // S^T = K * Q^T (Q pre-scaled by C2)
        f32x4 acc[4];
        #pragma unroll
        for (int j=0;j<4;j++) acc[j] = (f32x4){0.f,0.f,0.f,0.f};
        #pragma unroll
        for (int ks = 0; ks < 2; ks++){
            #pragma unroll
            for (int nb = 0; nb < 4; nb++){
                bf8 ak = *(const bf8*)swzc(kt, nb*16 + lc, ks*4 + quad);
                acc[nb] = MFMA(ak, aq[ks], acc[nb]);
            }
        }
        // scores + mask, per-lane partial max
        float svv[4][4];
        float mxl = -3.0e38f;
        #pragma unroll
        for (int a1 = 0; a1 < 2; a1++){
            #pragma unroll
            for (int b1 = 0; b1 < 2; b1++){
                int nb = 2*a1 + b1;
                #pragma unroll
                for (int r = 0; r < 4; r++){
                    u16 mraw = (r==0?mv[a1][b1].x:r==1?mv[a1][b1].y:
                                r==2?mv[a1][b1].z:mv[a1][b1].w);
                    float s2v = acc[nb][r] + b2f(mraw);
                    svv[nb][r] = s2v;
                    mxl = fmaxf(mxl, s2v);
                }
            }
        }
        // defer-max: only reduce/rescale when some lane grew past rm + 8
        if (__any(mxl > rm + 8.f)){
            float mx = fmaxf(mxl, __shfl_xor(mxl, 16, 64));
            mx = fmaxf(mx, __shfl_xor(mx, 32, 64));
            float nm = fmaxf(rm, mx);
            float fac = ex2(rm - nm);
            rm = nm;
            rl *= fac;
            float f0 = __shfl(fac, quad*4+0, 64);
            float f1 = __shfl(fac, quad*4+1, 64);
            float f2 = __shfl(fac, quad*4+2, 64);
            float f3 = __shfl(fac, quad*4+3, 64);
            #pragma unroll
            for (int nb = 0; nb < 4; nb++){
                oacc[nb][0] *= f0; oacc[nb][1] *= f1;
                oacc[nb][2] *= f2; oacc[nb][3] *= f3;
            }
        }
        // P (bounded by 2^8) packed via cvt_pk straight into PV A-fragments
        #pragma unroll
        for (int a1 = 0; a1 < 2; a1++){
            bfpack pk;
            {
                float p0 = ex2(svv[2*a1][0] - rm);
                float p1 = ex2(svv[2*a1][1] - rm);
                float p2 = ex2(svv[2*a1][2] - rm);
                float p3 = ex2(svv[2*a1][3] - rm);
                rl += (p0 + p1) + (p2 + p3);
                pk.u[0] = cvtpk(p0, p1); pk.u[1] = cvtpk(p2, p3);
            }
            {
                float p0 = ex2(svv[2*a1+1][0] - rm);
                float p1 = ex2(svv[2*a1+1][1] - rm);
                float p2 = ex2(svv[2*a1+1][2] - rm);
                float p3 = ex2(svv[2*a1+1][3] - rm);
                rl += (p0 + p1) + (p2 + p3);
                pk.u[2] = cvtpk(p0, p1); pk.u[3] = cvtpk(p2, p3);
            }
            bf8 ap = pk.v;
            #pragma unroll
            for (int nb2 = 0; nb2 < 4; nb2++){
                bf8 bv = *(const bf8*)swzc(vt, nb2*16 + lc, a1*4 + quad);
                oacc[nb2] = MFMA(ap, bv, oacc[nb2]);
            }
        }
    }
    // reduce per-lane partial l across the 4 lanes of each q-row (once)
    rl += __shfl_xor(rl, 16, 64);
    rl += __shfl_xor(rl, 32, 64);
    // per-half stats out (lanes with quad==0 hold rows 0..15 of this wave)
    if (quad == 0){
        size_t srow = ((size_t)(b*Hc+h))*Sc + qs0 + wv_*16 + lc;
        pm[(size_t)half*65536 + srow] = rm;
        pl[(size_t)half*65536 + srow] = rl;
    }
    // ctx normalized by this half's own l
    float i0 = 1.f/__shfl(rl, quad*4+0, 64);
    float i1 = 1.f/__shfl(rl, quad*4+1, 64);
    float i2 = 1.f/__shfl(rl, quad*4+2, 64);
    float i3 = 1.f/__shfl(rl, quad*4+3, 64);
    #pragma unroll
    for (int r = 0; r < 4; r++){
        float ir = (r==0?i0:r==1?i1:r==2?i2:i3);
        int tok = qs0 + wv_*16 + quad*4 + r;
        #pragma unroll
        for (int nb = 0; nb < 4; nb++){
            int hd = nb*16 + lc;
            ctxh[((size_t)(b*Sc + tok))*Ec + h*HDc + hd] = f2b(oacc[nb][r]*ir);
        }
    }
}

// ---------------------------------------------------------------------------
// 9b. merge the two half stats -> combine weights + attnw constant.
// ---------------------------------------------------------------------------
__global__ __launch_bounds__(256) void k_merge(
    const float* __restrict__ pm, const float* __restrict__ pl,
    float* __restrict__ lstc, float* __restrict__ w0, float* __restrict__ w1)
{
    int r = blockIdx.x*256 + threadIdx.x;
    float m0 = pm[r],        m1 = pm[65536 + r];
    float l0 = pl[r],        l1 = pl[65536 + r];
    float M  = fmaxf(m0, m1);
    float e0 = ex2(m0 - M)*l0;
    float e1 = ex2(m1 - M)*l1;
    float L  = e0 + e1;
    float iL = 1.f/L;
    lstc[r] = M + log2f(L);
    w0[r] = e0*iL;
    w1[r] = e1*iL;
}

// ---------------------------------------------------------------------------
// 9c. weighted combine of the two ctx halves: c0 = w0*c0 + w1*c1
// ---------------------------------------------------------------------------
__global__ __launch_bounds__(256) void k_addc(u16* __restrict__ c0,
                                              const u16* __restrict__ c1,
                                              const float* __restrict__ w0,
                                              const float* __restrict__ w1)
{
    int i = (blockIdx.x*256 + threadIdx.x)*8;
    int hh = (i >> 6) & 15, s = (i >> 10) & 2047, bb = i >> 21;
    int wi = ((bb*Hc + hh) << 11) + s;
    float wa = w0[wi], wb = w1[wi];
    ushort4 a0 = *(ushort4*)&c0[i],   a1 = *(ushort4*)&c0[i+4];
    ushort4 b0 = *(const ushort4*)&c1[i], b1 = *(const ushort4*)&c1[i+4];
    ushort4 o0, o1;
    o0.x = f2b(b2f(a0.x)*wa + b2f(b0.x)*wb); o0.y = f2b(b2f(a0.y)*wa + b2f(b0.y)*wb);
    o0.z = f2b(b2f(a0.z)*wa + b2f(b0.z)*wb); o0.w = f2b(b2f(a0.w)*wa + b2f(b0.w)*wb);
    o1.x = f2b(b2f(a1.x)*wa + b2f(b1.x)*wb); o1.y = f2b(b2f(a1.y)*wa + b2f(b1.y)*wb);
    o1.z = f2b(b2f(a1.z)*wa + b2f(b1.z)*wb); o1.w = f2b(b2f(a1.w)*wa + b2f(b1.w)*wb);
    *(ushort4*)&c0[i]   = o0;
    *(ushort4*)&c0[i+4] = o1;
}

// ---------------------------------------------------------------------------
// 8. attn_weights: q-tile 64, k-tile 64, loop all 16 h, NO atomics.
//    grid (32, 32, 2) = (q, k, b). Folded cc = M + log2(L); Q pre-scaled by
//    C2. Native v_exp_f32. Mask bf16 (pre-scaled) in the epilogue.
// ---------------------------------------------------------------------------
__global__ __launch_bounds__(256) void k_attnw(
    const u16* __restrict__ qb, const u16* __restrict__ kb,
    const u16* __restrict__ maskb, const float* __restrict__ lstc,
    float* __restrict__ awout)
{
    int qs0 = blockIdx.x*64, ks0 = blockIdx.y*64, b = blockIdx.z;
    int t = threadIdx.x, lane = t & 63, wv_ = t >> 6;
    int quad = lane >> 4, lc = lane & 15;
    __shared__ u16 kt[64*64];
    __shared__ float scc[64];
    f32x4 T[4];
    #pragma unroll
    for (int j=0;j<4;j++) T[j] = (f32x4){0.f,0.f,0.f,0.f};

    for (int h = 0; h < Hc; h++){
        __syncthreads();
        const u16* qp = qb + ((size_t)(b*Hc+h))*Sc*HDc;
        const u16* kp = kb + ((size_t)(b*Hc+h))*Sc*HDc;
        bf8 aq[2];
        #pragma unroll
        for (int ks = 0; ks < 2; ks++)
            aq[ks] = *(const bf8*)(qp + (size_t)(qs0 + wv_*16 + lc)*HDc + ks*32 + quad*8);
        {
            int rr = t >> 2, c8 = (t & 3)*2;
            const u16* s2 = kp + (size_t)(ks0+rr)*HDc + c8*8;
            *(uint4*)swz(kt, rr, c8)   = *(const uint4*)(s2);
            *(uint4*)swz(kt, rr, c8+1) = *(const uint4*)(s2+8);
        }
        if (t < 64)
            scc[t] = lstc[((size_t)(b*Hc+h))*Sc + qs0 + t];
        __syncthreads();
        f32x4 acc[4];
        #pragma unroll
        for (int j=0;j<4;j++) acc[j] = (f32x4){0.f,0.f,0.f,0.f};
        #pragma unroll
        for (int ks = 0; ks < 2; ks++){
            #pragma unroll
            for (int nb = 0; nb < 4; nb++){
                bf8 bb = *(const bf8*)swzc(kt, nb*16 + lc, ks*4 + quad);
                acc[nb] = MFMA(aq[ks], bb, acc[nb]);
            }
        }
        #pragma unroll
        for (int r = 0; r < 4; r++){
            int row = wv_*16 + quad*4 + r;
            float cv = scc[row];
            #pragma unroll
            for (int nb = 0; nb < 4; nb++)
                T[nb][r] += ex2(acc[nb][r] - cv);
        }
    }
    #pragma unroll
    for (int r = 0; r < 4; r++){
        int gq = qs0 + wv_*16 + quad*4 + r;
        #pragma unroll
        for (int nb = 0; nb < 4; nb++){
            int gk = ks0 + nb*16 + lc;
            float mk = b2f(maskb[(size_t)gq*Sc + gk]);   // mask*log2e
            awout[(size_t)b*Sc*Sc + (size_t)gq*Sc + gk]
                = T[nb][r]*ex2(mk)*(1.f/16.f);
        }
    }
}

// ---------------------------------------------------------------------------
// 10. output projection, MFMA. grid (8, NTILES). XOR-swizzled tiles staged
//     via global_load_lds (same mapping as k_qkv).
// ---------------------------------------------------------------------------
__global__ __launch_bounds__(256) void k_oproj(
    const u16* __restrict__ ctxb, const u16* __restrict__ woT,
    const int* __restrict__ perm, const int* __restrict__ tmeta,
    const u16* __restrict__ zbuf, float* __restrict__ opre)
{
    int meta = tmeta[blockIdx.y];
    if (meta < 0) return;
    int b = meta >> 1, m = meta & 1;
    const u16* W = woT + (size_t)m*Ec*Dc;
    int c0 = blockIdx.x*128;
    int t = threadIdx.x, lane = t & 63, wv_ = t >> 6;
    int quad = lane >> 4, lc = lane & 15;
    __shared__ u16 at[128*64];
    __shared__ u16 bt[128*64];
    __shared__ int sperm[128];
    if (t < 128) sperm[t] = perm[blockIdx.y*128 + t];
    f32x4 acc[2][8];
    #pragma unroll
    for (int i=0;i<2;i++)
        #pragma unroll
        for (int j=0;j<8;j++) acc[i][j] = (f32x4){0.f,0.f,0.f,0.f};
    __syncthreads();

    int colsw = ((lane & 7) ^ (lane >> 3)) << 3;
    const u16* ab[4]; const u16* bb[4];
    #pragma unroll
    for (int i = 0; i < 4; i++){
        int row = wv_*32 + i*8 + (lane >> 3);
        int s_ = sperm[row];
        ab[i] = (s_ >= 0) ? (ctxb + ((size_t)(b*Sc + s_))*Ec + colsw) : zbuf;
        bb[i] = W + (size_t)(c0 + row)*Ec + colsw;
    }

    for (int d0 = 0; d0 < Ec; d0 += 64){
        #pragma unroll
        for (int i = 0; i < 4; i++){
            gl16(ab[i] + d0, &at[(wv_*4 + i)*512]);
            gl16(bb[i] + d0, &bt[(wv_*4 + i)*512]);
        }
        __syncthreads();
        #pragma unroll
        for (int ks = 0; ks < 2; ks++){
            bf8 a0 = *(const bf8*)swzc(at, wv_*32 + lc,      ks*4 + quad);
            bf8 a1 = *(const bf8*)swzc(at, wv_*32 + 16 + lc, ks*4 + quad);
            #pragma unroll
            for (int nb = 0; nb < 8; nb++){
                bf8 bb2 = *(const bf8*)swzc(bt, nb*16 + lc, ks*4 + quad);
                acc[0][nb] = MFMA(a0, bb2, acc[0][nb]);
                acc[1][nb] = MFMA(a1, bb2, acc[1][nb]);
            }
        }
        __syncthreads();
    }
    #pragma unroll
    for (int mb = 0; mb < 2; mb++){
        #pragma unroll
        for (int r = 0; r < 4; r++){
            int row = wv_*32 + mb*16 + quad*4 + r;
            int s_ = sperm[row];
            if (s_ < 0) continue;
            #pragma unroll
            for (int nb = 0; nb < 8; nb++){
                int col = c0 + nb*16 + lc;
                opre[((size_t)(b*Sc + s_))*Dc + col] = acc[mb][nb][r];
            }
        }
    }
}

// ---------------------------------------------------------------------------
// 11. final RMSNorm over D -> out
// ---------------------------------------------------------------------------
__global__ __launch_bounds__(256) void k_onorm(
    const float* __restrict__ opre, const float* __restrict__ anw,
    const int* __restrict__ mod, float* __restrict__ out)
{
    int row = blockIdx.x;
    int m = mod[row];
    int t = threadIdx.x;
    float val[4];
    float ss = 0.f;
    #pragma unroll
    for (int j=0;j<4;j++){
        val[j] = opre[(size_t)row*Dc + t + 256*j];
        ss += val[j]*val[j];
    }
    #pragma unroll
    for (int o=32;o>0;o>>=1) ss += __shfl_xor(ss, o, 64);
    __shared__ float red[4];
    int wid = t>>6, lane = t&63;
    if (lane==0) red[wid]=ss;
    __syncthreads();
    float tot = red[0]+red[1]+red[2]+red[3];
    float rms = rsqrtf(tot*(1.f/1024.f) + EPSc);
    #pragma unroll
    for (int j=0;j<4;j++)
        out[(size_t)row*Dc + t + 256*j] = val[j]*rms*anw[m*Dc + t + 256*j];
}

// ---------------------------------------------------------------------------
extern "C" void kernel_launch(void* const* d_in, const int* in_sizes, int n_in,
                              void* d_out, int out_size, void* d_ws, size_t ws_size,
                              hipStream_t stream)
{
    const float* x    = (const float*)d_in[0];
    const float* mask = (const float*)d_in[1];
    const int*   mod  = (const int*)  d_in[2];
    const float* Wq   = (const float*)d_in[3];
    const float* Wk   = (const float*)d_in[4];
    const float* Wv   = (const float*)d_in[5];
    const float* Wo   = (const float*)d_in[6];
    const float* qnw  = (const float*)d_in[7];
    const float* knw  = (const float*)d_in[8];
    const float* anw  = (const float*)d_in[9];

    float* out   = (float*)d_out;                 // [B,S,D]
    float* awout = out + (size_t)Bc*Sc*Dc;        // [B,S,S]

    float* ws = (float*)d_ws;
    u16* qb    = (u16*)(ws + 0);
    u16* kb    = (u16*)(ws + 2097152);
    u16* vb    = (u16*)(ws + 4194304);   // dead after k_vt -> ctx partial 1
    u16* xb    = (u16*)(ws + 6291456);   // dead after k_qkv -> ctx partial 0
    u16* ctx0  = xb;
    u16* ctx1  = vb;
    u16* vtb   = (u16*)(ws + 8388608);
    u16* wqT   = (u16*)(ws + 10485760);
    u16* wkT   = (u16*)(ws + 11534336);
    u16* wvT   = (u16*)(ws + 12582912);
    u16* woT   = (u16*)(ws + 13631488);
    float* lstc= ws + 14680064;          // M + log2(L), 65536
    float* pm  = ws + 14811136;          // per-half m, 2*65536
    float* pl  = pm + 131072;            // per-half l, 2*65536
    float* w0  = ws + 15073280;          // combine weights, 65536 each
    float* w1  = w0 + 65536;
    u16* maskb = (u16*)(ws + 15335424);  // mask*log2e, bf16
    int* perm  = (int*)(ws + 17432576);
    int* tmeta = perm + NTILES*TILE_R;
    u16* zbuf  = (u16*)(tmeta + NTILES + 28);   // 4KB zero scratch (aligned)
    float* opre = ws;                    // aliases qb+kb (dead by then)

    k_perm  <<<dim3(1),            256, 0, stream>>>(mod, perm, tmeta, zbuf);
    k_f2b   <<<dim3(4096),         256, 0, stream>>>(x, xb, Bc*Sc*Dc);
    k_f2bs  <<<dim3(4096),         256, 0, stream>>>(mask, maskb, Sc*Sc, LOG2E);
    k_tcvt  <<<dim3(32,32,8),      256, 0, stream>>>(Wq, Wk, Wv, Wo, wqT, wkT, wvT, woT);
    k_qkv   <<<dim3(8,NTILES,3),   256, 0, stream>>>(xb, wqT, wkT, wvT, perm, tmeta,
                                                     qnw, knw, zbuf, qb, kb, vb);
    k_vt    <<<dim3(32,32),        256, 0, stream>>>(vb, vtb);
    k_flash <<<dim3(32,16,4),      256, 0, stream>>>(qb, kb, vtb, maskb, pm, pl, ctx0, ctx1);
    k_merge <<<dim3(256),          256, 0, stream>>>(pm, pl, lstc, w0, w1);
    k_attnw <<<dim3(32,32,2),      256, 0, stream>>>(qb, kb, maskb, lstc, awout);
    k_addc  <<<dim3(2048),         256, 0, stream>>>(ctx0, ctx1, w0, w1);
    k_oproj <<<dim3(8,NTILES),     256, 0, stream>>>(ctx0, woT, perm, tmeta, zbuf, opre);
    k_onorm <<<dim3(4096),         256, 0, stream>>>(opre, anw, mod, out);
}